// Round 1
// baseline (789.782 us; speedup 1.0000x reference)
//
#include <hip/hip_runtime.h>

using bf16   = __bf16;
using bf16x4 = __attribute__((ext_vector_type(4))) __bf16;
using bf16x8 = __attribute__((ext_vector_type(8))) __bf16;
using f32x4  = __attribute__((ext_vector_type(4))) float;
using u32x4  = __attribute__((ext_vector_type(4))) unsigned int;

#define MFMA16(a,b,c) __builtin_amdgcn_mfma_f32_16x16x32_bf16((a),(b),(c),0,0,0)

__device__ inline void glds16(const void* g, void* l) {
    __builtin_amdgcn_global_load_lds(
        (__attribute__((address_space(1))) void*)(const_cast<void*>(g)),
        (__attribute__((address_space(3))) void*)(l), 16, 0, 0);
}

// ---------------- constants (problem-instance fixed) ----------------
constexpr int CB   = 8;                 // batch
constexpr int NH   = 12;                // heads
constexpr int CC   = 768;               // channels
constexpr int HD   = 64;                // head dim
constexpr int TT   = 8, HH = 28, WW = 28;
constexpr int NTOK = TT*HH*WW + 1;      // 6273
constexpr int MX   = CB*NTOK;           // 50184
constexpr int MXP  = 50304;             // 393*128 (padded M)
constexpr int NQ   = 1569, NQP = 1600;  // q tokens (pad to 25*64)
constexpr int NK   = 393,  NKP = 416;   // k/v tokens (pad to 13*32)
constexpr int MO   = CB*NQ;             // 12552
constexpr int MOP  = 12672;             // 99*128

// ---------------- f32 -> bf16 cast (with zero tail pad) ----------------
__global__ __launch_bounds__(256) void cast_f32_bf16(const float* __restrict__ src,
                                                     bf16* __restrict__ dst,
                                                     int nvalid, int ntotal) {
    int i = (blockIdx.x * 256 + threadIdx.x) * 4;
    int stride = gridDim.x * 256 * 4;
    for (; i < ntotal; i += stride) {
        bf16x4 o;
        if (i + 3 < nvalid) {
            f32x4 v = *(const f32x4*)(src + i);
            #pragma unroll
            for (int e = 0; e < 4; ++e) o[e] = (bf16)v[e];
        } else {
            #pragma unroll
            for (int e = 0; e < 4; ++e) {
                int k = i + e;
                o[e] = (bf16)((k < nvalid) ? src[k] : 0.f);
            }
        }
        *(bf16x4*)(dst + i) = o;
    }
}

// ---------------- 128x128 bf16 MFMA GEMM (m97 structure) ----------------
// A: [Mpad][768] bf16 row-major.  Bw: [Ncols][768] bf16 (i.e. W[out][in], "B^T" layout).
// C = A @ Bw^T.  FINAL: f32 out + bias, row-predicated; else bf16 out.
template<bool FINAL>
__global__ __launch_bounds__(256) void gemm_kernel(const bf16* __restrict__ A,
                                                   const bf16* __restrict__ Bw,
                                                   void* __restrict__ Cptr,
                                                   const float* __restrict__ bias,
                                                   int ntiles, int Mvalid) {
    __shared__ bf16 Al[128 * 32];
    __shared__ bf16 Bl[128 * 32];
    const int bm = blockIdx.x / ntiles, bn = blockIdx.x % ntiles;
    const int tid = threadIdx.x, l = tid & 63, w = tid >> 6;
    const int li = l & 15, lg = l >> 4;
    const int wr = w >> 1, wc = w & 1;
    // staging: wave w covers chunks (2w, 2w+1); chunk k = rows 16k..16k+15 of the tile
    const int srow = w * 32 + (l >> 2);      // chunk 2w row for this lane
    const int scol = (l & 3) * 8;
    const bf16* Ab = A  + ((size_t)bm * 128 + srow) * 768 + scol;
    const bf16* Bb = Bw + ((size_t)bn * 128 + srow) * 768 + scol;
    char* AlB = (char*)Al + w * 2048;
    char* BlB = (char*)Bl + w * 2048;

    f32x4 acc[4][4] = {};
    for (int ks = 0; ks < 24; ++ks) {
        glds16(Ab + ks * 32,            AlB);
        glds16(Ab + 16 * 768 + ks * 32, AlB + 1024);
        glds16(Bb + ks * 32,            BlB);
        glds16(Bb + 16 * 768 + ks * 32, BlB + 1024);
        __syncthreads();
        bf16x8 af[4], bfr[4];
        #pragma unroll
        for (int m = 0; m < 4; ++m) af[m]  = *(const bf16x8*)&Al[(wr * 64 + m * 16 + li) * 32 + lg * 8];
        #pragma unroll
        for (int n = 0; n < 4; ++n) bfr[n] = *(const bf16x8*)&Bl[(wc * 64 + n * 16 + li) * 32 + lg * 8];
        #pragma unroll
        for (int m = 0; m < 4; ++m)
            #pragma unroll
            for (int n = 0; n < 4; ++n)
                acc[m][n] = MFMA16(af[m], bfr[n], acc[m][n]);
        __syncthreads();
    }
    #pragma unroll
    for (int m = 0; m < 4; ++m) {
        const int row0 = bm * 128 + wr * 64 + m * 16 + lg * 4;
        #pragma unroll
        for (int n = 0; n < 4; ++n) {
            const int col = bn * 128 + wc * 64 + n * 16 + li;
            #pragma unroll
            for (int r = 0; r < 4; ++r) {
                const int row = row0 + r;
                if constexpr (FINAL) {
                    if (row < Mvalid)
                        ((float*)Cptr)[(size_t)row * 768 + col] = acc[m][n][r] + bias[col];
                } else {
                    ((bf16*)Cptr)[(size_t)row * 768 + col] = (bf16)acc[m][n][r];
                }
            }
        }
    }
}

// ---------------- depthwise 3x3x3 pool + LayerNorm(hd) ----------------
// P: [Mpad][768] bf16 (projection output). out: [(b*12+head)*NPpad + p][64] bf16.
// wave-per-token; 64 lanes = 64 channels. p==0 is cls (passthrough). p>=NP -> zero pad.
__global__ __launch_bounds__(256) void pool_norm_kernel(const bf16* __restrict__ P,
                                                        const float* __restrict__ pw,
                                                        const float* __restrict__ gamma,
                                                        const float* __restrict__ beta,
                                                        bf16* __restrict__ outp,
                                                        int OH, int OW, int sHW,
                                                        int NP, int NPpad, float outScale) {
    __shared__ float wl[27 * 64];   // [tap][c]
    for (int idx = threadIdx.x; idx < 27 * 64; idx += 256) {
        int c = idx / 27, tap = idx % 27;
        wl[tap * 64 + c] = pw[idx];
    }
    __syncthreads();
    const int w = threadIdx.x >> 6, c = threadIdx.x & 63;
    const int gt = blockIdx.x * 4 + w;
    const int p = gt % NPpad;
    const int bh = gt / NPpad;
    const int b = bh / NH, head = bh % NH;

    float val = 0.f;
    if (p == 0) {
        val = (float)P[((size_t)b * NTOK) * CC + head * HD + c];
    } else if (p < NP) {
        const int op = p - 1;
        const int ohw = OH * OW;
        const int t = op / ohw, rr = op % ohw;
        const int oh = rr / OW, ow = rr % OW;
        #pragma unroll
        for (int dt = 0; dt < 3; ++dt) {
            const int it = t + dt - 1;
            if (it < 0 || it >= TT) continue;
            #pragma unroll
            for (int dh = 0; dh < 3; ++dh) {
                const int ih = oh * sHW + dh - 1;
                if (ih < 0 || ih >= HH) continue;
                #pragma unroll
                for (int dw = 0; dw < 3; ++dw) {
                    const int iw = ow * sHW + dw - 1;
                    if (iw < 0 || iw >= WW) continue;
                    const int tok = 1 + (it * HH + ih) * WW + iw;
                    val += wl[((dt * 3 + dh) * 3 + dw) * 64 + c] *
                           (float)P[((size_t)(b * NTOK + tok)) * CC + head * HD + c];
                }
            }
        }
    }
    // LayerNorm across the 64 lanes (hd dim)
    float s = val;
    #pragma unroll
    for (int m = 1; m < 64; m <<= 1) s += __shfl_xor(s, m);
    const float mu = s * (1.f / 64.f);
    const float d = val - mu;
    float v2 = d * d;
    #pragma unroll
    for (int m = 1; m < 64; m <<= 1) v2 += __shfl_xor(v2, m);
    const float rs = rsqrtf(v2 * (1.f / 64.f) + 1e-5f);
    const float o = (p < NP) ? (d * rs * gamma[c] + beta[c]) * outScale : 0.f;
    outp[((size_t)bh * NPpad + p) * HD + c] = (bf16)o;
}

// ---------------- flash attention: q(1569x64) x k/v(393x64) per (b,head) ----------------
// qn: [bh][1600][64] bf16 (pre-scaled by 0.125, zero-padded rows)
// kn/vn: [bh][416][64] bf16 (zero-padded rows).  ob: [b*1569+q][768] bf16.
__global__ __launch_bounds__(256) void attn_kernel(const bf16* __restrict__ qn,
                                                   const bf16* __restrict__ kn,
                                                   const bf16* __restrict__ vn,
                                                   bf16* __restrict__ ob) {
    __shared__ bf16 Kl[32][72];      // padded: 144B rows to avoid bank-aligned columns
    __shared__ bf16 Vt[64][40];      // transposed V, padded: 80B rows
    __shared__ float Pl[4][16][36];  // per-wave P tile, padded: 144B rows

    const int tid = threadIdx.x, l = tid & 63, w = tid >> 6;
    const int li = l & 15, lg = l >> 4;
    const int bh = blockIdx.y;
    const int b = bh / NH, head = bh % NH;
    const int qbase = blockIdx.x * 64 + w * 16;

    // q fragments (held for the whole kernel), rows zero-padded in qn
    const bf16* qp = qn + ((size_t)bh * NQP + qbase + li) * HD + lg * 8;
    const bf16x8 aq0 = *(const bf16x8*)qp;
    const bf16x8 aq1 = *(const bf16x8*)(qp + 32);

    f32x4 oacc[4] = {};
    float mrun[4], lrun[4];
    #pragma unroll
    for (int r = 0; r < 4; ++r) { mrun[r] = -1e30f; lrun[r] = 0.f; }

    for (int kt = 0; kt < NKP / 32; ++kt) {
        const int j0 = kt * 32;
        {   // stage K tile [32][64] -> Kl
            const int row = tid >> 3, g8 = (tid & 7) * 8;
            u32x4 kv = *(const u32x4*)(kn + ((size_t)bh * NKP + j0 + row) * HD + g8);
            *(u32x4*)&Kl[row][g8] = kv;
        }
        {   // stage V tile transposed -> Vt[d][j]
            const int j = tid & 31, d8 = tid >> 5;
            u32x4 vv4 = *(const u32x4*)(vn + ((size_t)bh * NKP + j0 + j) * HD + d8 * 8);
            bf16x8 vv = __builtin_bit_cast(bf16x8, vv4);
            #pragma unroll
            for (int e = 0; e < 8; ++e) Vt[d8 * 8 + e][j] = vv[e];
        }
        __syncthreads();

        // S = q k^T : two 16x16 C-tiles (j halves), contracting d=64 via 2 MFMAs each
        f32x4 c0 = {}, c1 = {};
        const bf16x8 b00 = *(const bf16x8*)&Kl[li][lg * 8];
        const bf16x8 b01 = *(const bf16x8*)&Kl[li][32 + lg * 8];
        const bf16x8 b10 = *(const bf16x8*)&Kl[16 + li][lg * 8];
        const bf16x8 b11 = *(const bf16x8*)&Kl[16 + li][32 + lg * 8];
        c0 = MFMA16(aq0, b00, c0); c0 = MFMA16(aq1, b01, c0);
        c1 = MFMA16(aq0, b10, c1); c1 = MFMA16(aq1, b11, c1);

        const bool msk0 = (j0 + li) >= NK, msk1 = (j0 + 16 + li) >= NK;
        float p0[4], p1[4];
        #pragma unroll
        for (int r = 0; r < 4; ++r) {
            const float s0 = msk0 ? -1e30f : c0[r];
            const float s1 = msk1 ? -1e30f : c1[r];
            float t = fmaxf(s0, s1);
            t = fmaxf(t, __shfl_xor(t, 1));
            t = fmaxf(t, __shfl_xor(t, 2));
            t = fmaxf(t, __shfl_xor(t, 4));
            t = fmaxf(t, __shfl_xor(t, 8));
            const float mn = fmaxf(mrun[r], t);
            const float sc = __expf(mrun[r] - mn);
            const float e0 = __expf(s0 - mn);
            const float e1 = __expf(s1 - mn);
            float rsum = e0 + e1;
            rsum += __shfl_xor(rsum, 1);
            rsum += __shfl_xor(rsum, 2);
            rsum += __shfl_xor(rsum, 4);
            rsum += __shfl_xor(rsum, 8);
            lrun[r] = lrun[r] * sc + rsum;
            mrun[r] = mn;
            p0[r] = e0; p1[r] = e1;
            #pragma unroll
            for (int dg = 0; dg < 4; ++dg) oacc[dg][r] *= sc;
        }
        // P -> per-wave LDS (C-layout) then reload as A-fragment
        #pragma unroll
        for (int r = 0; r < 4; ++r) {
            Pl[w][lg * 4 + r][li]      = p0[r];
            Pl[w][lg * 4 + r][16 + li] = p1[r];
        }
        const f32x4 pa = *(const f32x4*)&Pl[w][li][lg * 8];
        const f32x4 pb = *(const f32x4*)&Pl[w][li][lg * 8 + 4];
        bf16x8 ap;
        #pragma unroll
        for (int e = 0; e < 4; ++e) { ap[e] = (bf16)pa[e]; ap[4 + e] = (bf16)pb[e]; }
        #pragma unroll
        for (int dg = 0; dg < 4; ++dg) {
            const bf16x8 bv = *(const bf16x8*)&Vt[dg * 16 + li][lg * 8];
            oacc[dg] = MFMA16(ap, bv, oacc[dg]);
        }
        __syncthreads();
    }
    // epilogue: o / l, write to (B, Nq, C) layout
    #pragma unroll
    for (int r = 0; r < 4; ++r) {
        const int q = qbase + lg * 4 + r;
        if (q < NQ) {
            const float inv = 1.f / lrun[r];
            const size_t off = ((size_t)(b * NQ + q)) * CC + head * HD;
            #pragma unroll
            for (int dg = 0; dg < 4; ++dg)
                ob[off + dg * 16 + li] = (bf16)(oacc[dg][r] * inv);
        }
    }
}

// ---------------- launcher ----------------
extern "C" void kernel_launch(void* const* d_in, const int* in_sizes, int n_in,
                              void* d_out, int out_size, void* d_ws, size_t ws_size,
                              hipStream_t stream) {
    const float* x     = (const float*)d_in[0];
    const float* Wq    = (const float*)d_in[1];
    const float* Wk    = (const float*)d_in[2];
    const float* Wv    = (const float*)d_in[3];
    const float* Wproj = (const float*)d_in[4];
    const float* bproj = (const float*)d_in[5];
    const float* pqw   = (const float*)d_in[6];
    const float* pkw   = (const float*)d_in[7];
    const float* pvw   = (const float*)d_in[8];
    const float* gq    = (const float*)d_in[9];
    const float* bq    = (const float*)d_in[10];
    const float* gk    = (const float*)d_in[11];
    const float* bk    = (const float*)d_in[12];
    const float* gv    = (const float*)d_in[13];
    const float* bv    = (const float*)d_in[14];

    // workspace layout (bytes)
    if (ws_size < 208601088ULL) return;   // need ~209 MB
    char* ws = (char*)d_ws;
    bf16* xb   = (bf16*)(ws);               // [50304][768]
    bf16* wqkv = (bf16*)(ws + 77266944);    // [2304][768]  (q,k,v stacked)
    bf16* wpb  = (bf16*)(ws + 80805888);    // [768][768]
    bf16* tmp  = (bf16*)(ws + 81985536);    // [50304][768] per-projection GEMM out
    bf16* qn   = (bf16*)(ws + 159252480);   // [96][1600][64]
    bf16* kn   = (bf16*)(ws + 178913280);   // [96][416][64]
    bf16* vnb  = (bf16*)(ws + 184025088);   // [96][416][64]
    bf16* ob   = (bf16*)(ws + 189136896);   // [12672][768]

    const int WSZ = 589824;  // 768*768

    cast_f32_bf16<<<4096, 256, 0, stream>>>(x, xb, MX * CC, MXP * CC);
    cast_f32_bf16<<<576, 256, 0, stream>>>(Wq, wqkv,            WSZ, WSZ);
    cast_f32_bf16<<<576, 256, 0, stream>>>(Wk, wqkv + WSZ,      WSZ, WSZ);
    cast_f32_bf16<<<576, 256, 0, stream>>>(Wv, wqkv + 2 * WSZ,  WSZ, WSZ);
    cast_f32_bf16<<<576, 256, 0, stream>>>(Wproj, wpb,          WSZ, WSZ);

    // Q
    gemm_kernel<false><<<393 * 6, 256, 0, stream>>>(xb, wqkv, tmp, nullptr, 6, 0);
    pool_norm_kernel<<<96 * NQP / 4, 256, 0, stream>>>(tmp, pqw, gq, bq, qn, 14, 14, 2, NQ, NQP, 0.125f);
    // K
    gemm_kernel<false><<<393 * 6, 256, 0, stream>>>(xb, wqkv + WSZ, tmp, nullptr, 6, 0);
    pool_norm_kernel<<<96 * NKP / 4, 256, 0, stream>>>(tmp, pkw, gk, bk, kn, 7, 7, 4, NK, NKP, 1.0f);
    // V
    gemm_kernel<false><<<393 * 6, 256, 0, stream>>>(xb, wqkv + 2 * WSZ, tmp, nullptr, 6, 0);
    pool_norm_kernel<<<96 * NKP / 4, 256, 0, stream>>>(tmp, pvw, gv, bv, vnb, 7, 7, 4, NK, NKP, 1.0f);

    attn_kernel<<<dim3(25, 96), 256, 0, stream>>>(qn, kn, vnb, ob);

    gemm_kernel<true><<<99 * 6, 256, 0, stream>>>(ob, wpb, d_out, bproj, 6, MO);
}

// Round 2
// 547.966 us; speedup vs baseline: 1.4413x; 1.4413x over previous
//
#include <hip/hip_runtime.h>

using bf16   = __bf16;
using bf16x4 = __attribute__((ext_vector_type(4))) __bf16;
using bf16x8 = __attribute__((ext_vector_type(8))) __bf16;
using f32x4  = __attribute__((ext_vector_type(4))) float;
using u32x4  = __attribute__((ext_vector_type(4))) unsigned int;

#define MFMA16(a,b,c) __builtin_amdgcn_mfma_f32_16x16x32_bf16((a),(b),(c),0,0,0)

__device__ inline void glds16(const void* g, void* l) {
    __builtin_amdgcn_global_load_lds(
        (__attribute__((address_space(1))) void*)(const_cast<void*>(g)),
        (__attribute__((address_space(3))) void*)(l), 16, 0, 0);
}

// ---------------- constants (problem-instance fixed) ----------------
constexpr int CB   = 8;                 // batch
constexpr int NH   = 12;                // heads
constexpr int CC   = 768;               // channels
constexpr int HD   = 64;                // head dim
constexpr int TT   = 8, HH = 28, WW = 28;
constexpr int NTOK = TT*HH*WW + 1;      // 6273
constexpr int MX   = CB*NTOK;           // 50184
constexpr int MXP  = 50304;             // 393*128 (padded M)
constexpr int NQ   = 1569, NQP = 1600;  // q tokens (pad to 25*64)
constexpr int NK   = 393,  NKP = 416;   // k/v tokens (pad to 13*32)
constexpr int MO   = CB*NQ;             // 12552
constexpr int MOP  = 12672;             // 99*128

// ---------------- f32 -> bf16 cast (with zero tail pad) ----------------
__global__ __launch_bounds__(256) void cast_f32_bf16(const float* __restrict__ src,
                                                     bf16* __restrict__ dst,
                                                     int nvalid, int ntotal) {
    int i = (blockIdx.x * 256 + threadIdx.x) * 4;
    int stride = gridDim.x * 256 * 4;
    for (; i < ntotal; i += stride) {
        bf16x4 o;
        if (i + 3 < nvalid) {
            f32x4 v = *(const f32x4*)(src + i);
            #pragma unroll
            for (int e = 0; e < 4; ++e) o[e] = (bf16)v[e];
        } else {
            #pragma unroll
            for (int e = 0; e < 4; ++e) {
                int k = i + e;
                o[e] = (bf16)((k < nvalid) ? src[k] : 0.f);
            }
        }
        *(bf16x4*)(dst + i) = o;
    }
}

// ---------------- weight transpose: (64,27) -> [27][64], 3 sets ----------------
__global__ __launch_bounds__(256) void transpose_w3(const float* __restrict__ w0,
                                                    const float* __restrict__ w1,
                                                    const float* __restrict__ w2,
                                                    float* __restrict__ wt) {
    int i = blockIdx.x * 256 + threadIdx.x;
    if (i >= 3 * 1728) return;
    int setn = i / 1728, j = i % 1728;
    const float* src = (setn == 0) ? w0 : (setn == 1) ? w1 : w2;
    int tap = j / 64, c = j % 64;
    wt[i] = src[c * 27 + tap];
}

// ---------------- 128x128 bf16 MFMA GEMM (m97 structure) ----------------
// A: [Mpad][768] bf16 row-major.  Bw: [Ncols][768] bf16 (i.e. W[out][in], "B^T" layout).
// C = A @ Bw^T.  FINAL: f32 out + bias, row-predicated; else bf16 out.
template<bool FINAL>
__global__ __launch_bounds__(256) void gemm_kernel(const bf16* __restrict__ A,
                                                   const bf16* __restrict__ Bw,
                                                   void* __restrict__ Cptr,
                                                   const float* __restrict__ bias,
                                                   int ntiles, int Mvalid) {
    __shared__ bf16 Al[128 * 32];
    __shared__ bf16 Bl[128 * 32];
    const int bm = blockIdx.x / ntiles, bn = blockIdx.x % ntiles;
    const int tid = threadIdx.x, l = tid & 63, w = tid >> 6;
    const int li = l & 15, lg = l >> 4;
    const int wr = w >> 1, wc = w & 1;
    const int srow = w * 32 + (l >> 2);
    const int scol = (l & 3) * 8;
    const bf16* Ab = A  + ((size_t)bm * 128 + srow) * 768 + scol;
    const bf16* Bb = Bw + ((size_t)bn * 128 + srow) * 768 + scol;
    char* AlB = (char*)Al + w * 2048;
    char* BlB = (char*)Bl + w * 2048;

    f32x4 acc[4][4] = {};
    for (int ks = 0; ks < 24; ++ks) {
        glds16(Ab + ks * 32,            AlB);
        glds16(Ab + 16 * 768 + ks * 32, AlB + 1024);
        glds16(Bb + ks * 32,            BlB);
        glds16(Bb + 16 * 768 + ks * 32, BlB + 1024);
        __syncthreads();
        bf16x8 af[4], bfr[4];
        #pragma unroll
        for (int m = 0; m < 4; ++m) af[m]  = *(const bf16x8*)&Al[(wr * 64 + m * 16 + li) * 32 + lg * 8];
        #pragma unroll
        for (int n = 0; n < 4; ++n) bfr[n] = *(const bf16x8*)&Bl[(wc * 64 + n * 16 + li) * 32 + lg * 8];
        #pragma unroll
        for (int m = 0; m < 4; ++m)
            #pragma unroll
            for (int n = 0; n < 4; ++n)
                acc[m][n] = MFMA16(af[m], bfr[n], acc[m][n]);
        __syncthreads();
    }
    #pragma unroll
    for (int m = 0; m < 4; ++m) {
        const int row0 = bm * 128 + wr * 64 + m * 16 + lg * 4;
        #pragma unroll
        for (int n = 0; n < 4; ++n) {
            const int col = bn * 128 + wc * 64 + n * 16 + li;
            #pragma unroll
            for (int r = 0; r < 4; ++r) {
                const int row = row0 + r;
                if constexpr (FINAL) {
                    if (row < Mvalid)
                        ((float*)Cptr)[(size_t)row * 768 + col] = acc[m][n][r] + bias[col];
                } else {
                    ((bf16*)Cptr)[(size_t)row * 768 + col] = (bf16)acc[m][n][r];
                }
            }
        }
    }
}

// ---------------- depthwise 3x3x3 pool + LayerNorm(hd), vectorized ----------------
// Wave task layout: lane = owg(3b)*8 + cg(3b). Lane owns 8 consecutive channels of
// one output position. Wave covers 8 ow positions x 64 ch. wt: [27][64] f32.
// Last task per bh: cls token (owg 0) + zero-fill pad rows (owg 1..7).
template<int S, int OH, int OW, int CH, int NP, int NPpad>
__global__ __launch_bounds__(256) void pool_norm2(const bf16* __restrict__ P,
                                                  const float* __restrict__ wt,
                                                  const float* __restrict__ gamma,
                                                  const float* __restrict__ beta,
                                                  bf16* __restrict__ outp,
                                                  float outScale) {
    constexpr int TASKS = TT * OH * CH + 1;
    const int w = threadIdx.x >> 6, lane = threadIdx.x & 63;
    const int gw = blockIdx.x * 4 + w;
    const int bh = gw / TASKS, task = gw % TASKS;
    const int b = bh / NH, head = bh % NH;
    const int owg = lane >> 3, cg = lane & 7, c = cg * 8;
    const size_t pbase = (size_t)b * NTOK * CC + head * HD + c;

    if (task == TASKS - 1) {
        if (owg == 0) {
            // cls token passthrough + LN
            bf16x8 v = *(const bf16x8*)(P + pbase);
            float a[8];
            #pragma unroll
            for (int e = 0; e < 8; ++e) a[e] = (float)v[e];
            float s = 0;
            #pragma unroll
            for (int e = 0; e < 8; ++e) s += a[e];
            s += __shfl_xor(s, 1); s += __shfl_xor(s, 2); s += __shfl_xor(s, 4);
            const float mu = s * 0.015625f;
            float v2 = 0;
            #pragma unroll
            for (int e = 0; e < 8; ++e) { float d = a[e] - mu; v2 += d * d; }
            v2 += __shfl_xor(v2, 1); v2 += __shfl_xor(v2, 2); v2 += __shfl_xor(v2, 4);
            const float rs = rsqrtf(v2 * 0.015625f + 1e-5f);
            f32x4 g0 = *(const f32x4*)(gamma + c), g1 = *(const f32x4*)(gamma + c + 4);
            f32x4 b0 = *(const f32x4*)(beta + c),  b1 = *(const f32x4*)(beta + c + 4);
            bf16x8 o;
            #pragma unroll
            for (int e = 0; e < 4; ++e) {
                o[e]     = (bf16)(((a[e]     - mu) * rs * g0[e] + b0[e]) * outScale);
                o[4 + e] = (bf16)(((a[4 + e] - mu) * rs * g1[e] + b1[e]) * outScale);
            }
            *(bf16x8*)(outp + ((size_t)bh * NPpad) * HD + c) = o;
        } else {
            bf16x8 z = {};
            for (int p = NP + owg - 1; p < NPpad; p += 7)
                *(bf16x8*)(outp + ((size_t)bh * NPpad + p) * HD + c) = z;
        }
        return;
    }

    const int t  = task / (OH * CH);
    const int r2 = task % (OH * CH);
    const int oh = r2 / CH;
    const int ow = (r2 % CH) * 8 + owg;
    const bool active = (ow < OW);

    float acc[8] = {0, 0, 0, 0, 0, 0, 0, 0};
    #pragma unroll
    for (int dt = 0; dt < 3; ++dt) {
        const int it = t + dt - 1;
        if (it < 0 || it >= TT) continue;
        #pragma unroll
        for (int dh = 0; dh < 3; ++dh) {
            const int ih = oh * S + dh - 1;
            if (ih < 0 || ih >= HH) continue;
            const int tokrow = 1 + (it * HH + ih) * WW;
            #pragma unroll
            for (int dw = 0; dw < 3; ++dw) {
                const int iw = ow * S + dw - 1;
                if (active && iw >= 0) {
                    bf16x8 v = *(const bf16x8*)(P + pbase + (size_t)(tokrow + iw) * CC);
                    const float* wp = wt + ((dt * 3 + dh) * 3 + dw) * 64 + c;
                    f32x4 w0 = *(const f32x4*)wp, w1 = *(const f32x4*)(wp + 4);
                    #pragma unroll
                    for (int e = 0; e < 4; ++e) {
                        acc[e]     += w0[e] * (float)v[e];
                        acc[4 + e] += w1[e] * (float)v[4 + e];
                    }
                }
            }
        }
    }
    // LayerNorm over 64 ch: 8 in-lane + 3 shfl steps (within the 8-lane cg group)
    float s = 0;
    #pragma unroll
    for (int e = 0; e < 8; ++e) s += acc[e];
    s += __shfl_xor(s, 1); s += __shfl_xor(s, 2); s += __shfl_xor(s, 4);
    const float mu = s * 0.015625f;
    float v2 = 0;
    #pragma unroll
    for (int e = 0; e < 8; ++e) { float d = acc[e] - mu; v2 += d * d; }
    v2 += __shfl_xor(v2, 1); v2 += __shfl_xor(v2, 2); v2 += __shfl_xor(v2, 4);
    const float rs = rsqrtf(v2 * 0.015625f + 1e-5f);
    if (active) {
        f32x4 g0 = *(const f32x4*)(gamma + c), g1 = *(const f32x4*)(gamma + c + 4);
        f32x4 b0 = *(const f32x4*)(beta + c),  b1 = *(const f32x4*)(beta + c + 4);
        bf16x8 o;
        #pragma unroll
        for (int e = 0; e < 4; ++e) {
            o[e]     = (bf16)(((acc[e]     - mu) * rs * g0[e] + b0[e]) * outScale);
            o[4 + e] = (bf16)(((acc[4 + e] - mu) * rs * g1[e] + b1[e]) * outScale);
        }
        const int p = 1 + (t * OH + oh) * OW + ow;
        *(bf16x8*)(outp + ((size_t)bh * NPpad + p) * HD + c) = o;
    }
}

// ---------------- flash attention: q(1569x64) x k/v(393x64) per (b,head) ----------------
__global__ __launch_bounds__(256) void attn_kernel(const bf16* __restrict__ qn,
                                                   const bf16* __restrict__ kn,
                                                   const bf16* __restrict__ vn,
                                                   bf16* __restrict__ ob) {
    __shared__ bf16 Kl[32][72];
    __shared__ bf16 Vt[64][40];
    __shared__ float Pl[4][16][36];

    const int tid = threadIdx.x, l = tid & 63, w = tid >> 6;
    const int li = l & 15, lg = l >> 4;
    const int bh = blockIdx.y;
    const int b = bh / NH, head = bh % NH;
    const int qbase = blockIdx.x * 64 + w * 16;

    const bf16* qp = qn + ((size_t)bh * NQP + qbase + li) * HD + lg * 8;
    const bf16x8 aq0 = *(const bf16x8*)qp;
    const bf16x8 aq1 = *(const bf16x8*)(qp + 32);

    f32x4 oacc[4] = {};
    float mrun[4], lrun[4];
    #pragma unroll
    for (int r = 0; r < 4; ++r) { mrun[r] = -1e30f; lrun[r] = 0.f; }

    for (int kt = 0; kt < NKP / 32; ++kt) {
        const int j0 = kt * 32;
        {
            const int row = tid >> 3, g8 = (tid & 7) * 8;
            u32x4 kv = *(const u32x4*)(kn + ((size_t)bh * NKP + j0 + row) * HD + g8);
            *(u32x4*)&Kl[row][g8] = kv;
        }
        {
            const int j = tid & 31, d8 = tid >> 5;
            u32x4 vv4 = *(const u32x4*)(vn + ((size_t)bh * NKP + j0 + j) * HD + d8 * 8);
            bf16x8 vv = __builtin_bit_cast(bf16x8, vv4);
            #pragma unroll
            for (int e = 0; e < 8; ++e) Vt[d8 * 8 + e][j] = vv[e];
        }
        __syncthreads();

        f32x4 c0 = {}, c1 = {};
        const bf16x8 b00 = *(const bf16x8*)&Kl[li][lg * 8];
        const bf16x8 b01 = *(const bf16x8*)&Kl[li][32 + lg * 8];
        const bf16x8 b10 = *(const bf16x8*)&Kl[16 + li][lg * 8];
        const bf16x8 b11 = *(const bf16x8*)&Kl[16 + li][32 + lg * 8];
        c0 = MFMA16(aq0, b00, c0); c0 = MFMA16(aq1, b01, c0);
        c1 = MFMA16(aq0, b10, c1); c1 = MFMA16(aq1, b11, c1);

        const bool msk0 = (j0 + li) >= NK, msk1 = (j0 + 16 + li) >= NK;
        float p0[4], p1[4];
        #pragma unroll
        for (int r = 0; r < 4; ++r) {
            const float s0 = msk0 ? -1e30f : c0[r];
            const float s1 = msk1 ? -1e30f : c1[r];
            float t = fmaxf(s0, s1);
            t = fmaxf(t, __shfl_xor(t, 1));
            t = fmaxf(t, __shfl_xor(t, 2));
            t = fmaxf(t, __shfl_xor(t, 4));
            t = fmaxf(t, __shfl_xor(t, 8));
            const float mn = fmaxf(mrun[r], t);
            const float sc = __expf(mrun[r] - mn);
            const float e0 = __expf(s0 - mn);
            const float e1 = __expf(s1 - mn);
            float rsum = e0 + e1;
            rsum += __shfl_xor(rsum, 1);
            rsum += __shfl_xor(rsum, 2);
            rsum += __shfl_xor(rsum, 4);
            rsum += __shfl_xor(rsum, 8);
            lrun[r] = lrun[r] * sc + rsum;
            mrun[r] = mn;
            p0[r] = e0; p1[r] = e1;
            #pragma unroll
            for (int dg = 0; dg < 4; ++dg) oacc[dg][r] *= sc;
        }
        #pragma unroll
        for (int r = 0; r < 4; ++r) {
            Pl[w][lg * 4 + r][li]      = p0[r];
            Pl[w][lg * 4 + r][16 + li] = p1[r];
        }
        const f32x4 pa = *(const f32x4*)&Pl[w][li][lg * 8];
        const f32x4 pb = *(const f32x4*)&Pl[w][li][lg * 8 + 4];
        bf16x8 ap;
        #pragma unroll
        for (int e = 0; e < 4; ++e) { ap[e] = (bf16)pa[e]; ap[4 + e] = (bf16)pb[e]; }
        #pragma unroll
        for (int dg = 0; dg < 4; ++dg) {
            const bf16x8 bv = *(const bf16x8*)&Vt[dg * 16 + li][lg * 8];
            oacc[dg] = MFMA16(ap, bv, oacc[dg]);
        }
        __syncthreads();
    }
    #pragma unroll
    for (int r = 0; r < 4; ++r) {
        const int q = qbase + lg * 4 + r;
        if (q < NQ) {
            const float inv = 1.f / lrun[r];
            const size_t off = ((size_t)(b * NQ + q)) * CC + head * HD;
            #pragma unroll
            for (int dg = 0; dg < 4; ++dg)
                ob[off + dg * 16 + li] = (bf16)(oacc[dg][r] * inv);
        }
    }
}

// ---------------- launcher ----------------
extern "C" void kernel_launch(void* const* d_in, const int* in_sizes, int n_in,
                              void* d_out, int out_size, void* d_ws, size_t ws_size,
                              hipStream_t stream) {
    const float* x     = (const float*)d_in[0];
    const float* Wq    = (const float*)d_in[1];
    const float* Wk    = (const float*)d_in[2];
    const float* Wv    = (const float*)d_in[3];
    const float* Wproj = (const float*)d_in[4];
    const float* bproj = (const float*)d_in[5];
    const float* pqw   = (const float*)d_in[6];
    const float* pkw   = (const float*)d_in[7];
    const float* pvw   = (const float*)d_in[8];
    const float* gq    = (const float*)d_in[9];
    const float* bq    = (const float*)d_in[10];
    const float* gk    = (const float*)d_in[11];
    const float* bk    = (const float*)d_in[12];
    const float* gv    = (const float*)d_in[13];
    const float* bv    = (const float*)d_in[14];

    if (ws_size < 208601088ULL) return;
    char* ws = (char*)d_ws;
    bf16* xb   = (bf16*)(ws);               // [50304][768]
    bf16* wqkv = (bf16*)(ws + 77266944);    // [2304][768]
    bf16* wpb  = (bf16*)(ws + 80805888);    // [768][768]
    bf16* tmp  = (bf16*)(ws + 81985536);    // [50304][768]
    bf16* qn   = (bf16*)(ws + 159252480);   // [96][1600][64]
    bf16* kn   = (bf16*)(ws + 178913280);   // [96][416][64]
    bf16* vnb  = (bf16*)(ws + 184025088);   // [96][416][64]
    bf16* ob   = (bf16*)(ws + 189136896);   // [12672][768]
    // wt overlays the first 20736 B of ob: alive only before attn rewrites ob.
    float* wt  = (float*)(ws + 189136896);  // [3][27][64] f32

    const int WSZ = 589824;  // 768*768

    transpose_w3<<<21, 256, 0, stream>>>(pqw, pkw, pvw, wt);
    cast_f32_bf16<<<4096, 256, 0, stream>>>(x, xb, MX * CC, MXP * CC);
    cast_f32_bf16<<<576, 256, 0, stream>>>(Wq, wqkv,            WSZ, WSZ);
    cast_f32_bf16<<<576, 256, 0, stream>>>(Wk, wqkv + WSZ,      WSZ, WSZ);
    cast_f32_bf16<<<576, 256, 0, stream>>>(Wv, wqkv + 2 * WSZ,  WSZ, WSZ);
    cast_f32_bf16<<<576, 256, 0, stream>>>(Wproj, wpb,          WSZ, WSZ);

    // Q: proj + pool(stride 1,2,2) + LN  (scale 0.125 baked in)
    gemm_kernel<false><<<393 * 6, 256, 0, stream>>>(xb, wqkv, tmp, nullptr, 6, 0);
    pool_norm2<2, 14, 14, 2, NQ, NQP><<<5400, 256, 0, stream>>>(tmp, wt, gq, bq, qn, 0.125f);
    // K: proj + pool(stride 1,4,4) + LN
    gemm_kernel<false><<<393 * 6, 256, 0, stream>>>(xb, wqkv + WSZ, tmp, nullptr, 6, 0);
    pool_norm2<4, 7, 7, 1, NK, NKP><<<1368, 256, 0, stream>>>(tmp, wt + 1728, gk, bk, kn, 1.0f);
    // V: proj + pool(stride 1,4,4) + LN
    gemm_kernel<false><<<393 * 6, 256, 0, stream>>>(xb, wqkv + 2 * WSZ, tmp, nullptr, 6, 0);
    pool_norm2<4, 7, 7, 1, NK, NKP><<<1368, 256, 0, stream>>>(tmp, wt + 3456, gv, bv, vnb, 1.0f);

    attn_kernel<<<dim3(25, 96), 256, 0, stream>>>(qn, kn, vnb, ob);

    gemm_kernel<true><<<99 * 6, 256, 0, stream>>>(ob, wpb, d_out, bproj, 6, MO);
}

// Round 3
// 507.106 us; speedup vs baseline: 1.5574x; 1.0806x over previous
//
#include <hip/hip_runtime.h>

using bf16   = __bf16;
using bf16x4 = __attribute__((ext_vector_type(4))) __bf16;
using bf16x8 = __attribute__((ext_vector_type(8))) __bf16;
using f32x4  = __attribute__((ext_vector_type(4))) float;
using u32x4  = __attribute__((ext_vector_type(4))) unsigned int;

#define MFMA16(a,b,c) __builtin_amdgcn_mfma_f32_16x16x32_bf16((a),(b),(c),0,0,0)

__device__ inline void glds16(const void* g, void* l) {
    __builtin_amdgcn_global_load_lds(
        (__attribute__((address_space(1))) void*)(const_cast<void*>(g)),
        (__attribute__((address_space(3))) void*)(l), 16, 0, 0);
}

// ---------------- constants (problem-instance fixed) ----------------
constexpr int CB   = 8;
constexpr int NH   = 12;
constexpr int CC   = 768;
constexpr int HD   = 64;
constexpr int TT   = 8, HH = 28, WW = 28;
constexpr int NTOK = TT*HH*WW + 1;      // 6273
constexpr int MX   = CB*NTOK;           // 50184
constexpr int MXP  = 50304;             // padded M rows in xb/tmp
constexpr int NQ   = 1569, NQP = 1600;
constexpr int NK   = 393,  NKP = 416;
constexpr int MO   = CB*NQ;             // 12552
constexpr int MOP  = 12672;

// ---------------- f32 -> bf16 cast (with zero tail pad) ----------------
__global__ __launch_bounds__(256) void cast_f32_bf16(const float* __restrict__ src,
                                                     bf16* __restrict__ dst,
                                                     int nvalid, int ntotal) {
    int i = (blockIdx.x * 256 + threadIdx.x) * 4;
    int stride = gridDim.x * 256 * 4;
    for (; i < ntotal; i += stride) {
        bf16x4 o;
        if (i + 3 < nvalid) {
            f32x4 v = *(const f32x4*)(src + i);
            #pragma unroll
            for (int e = 0; e < 4; ++e) o[e] = (bf16)v[e];
        } else {
            #pragma unroll
            for (int e = 0; e < 4; ++e) {
                int k = i + e;
                o[e] = (bf16)((k < nvalid) ? src[k] : 0.f);
            }
        }
        *(bf16x4*)(dst + i) = o;
    }
}

// ---------------- weight transpose: (64,27) -> [27][64], 3 sets ----------------
__global__ __launch_bounds__(256) void transpose_w3(const float* __restrict__ w0,
                                                    const float* __restrict__ w1,
                                                    const float* __restrict__ w2,
                                                    float* __restrict__ wt) {
    int i = blockIdx.x * 256 + threadIdx.x;
    if (i >= 3 * 1728) return;
    int setn = i / 1728, j = i % 1728;
    const float* src = (setn == 0) ? w0 : (setn == 1) ? w1 : w2;
    int tap = j / 64, c = j % 64;
    wt[i] = src[c * 27 + tap];
}

// ---------------- 256x256 8-phase bf16 GEMM (HK/m201-style, plain HIP) ----------------
// A: [*][768] bf16 row-major.  Bw: [768][768] bf16 (W[out][in], B^T layout).
// C = A @ Bw^T.  K = 768 fixed (12 K-tiles of 64).
// 512 thr = 8 waves (2M x 4N), per-wave out 128x64, acc 8x4 f32x4.
// LDS: 2 buffers x (A 256x64 | B 256x64) bf16 = 131072 B (dynamic).
// st-swizzle: within-row byte ^= (row&7)<<4, applied on ds_read and inverse-applied
// on the per-lane GLOBAL source of global_load_lds (LDS dest stays linear).
template<bool FINAL>
__global__ __launch_bounds__(512, 2) void gemm256(const bf16* __restrict__ A,
                                                  const bf16* __restrict__ Bw,
                                                  void* __restrict__ Cptr,
                                                  const float* __restrict__ bias,
                                                  int nbn, int Mvalid, int Aclamp) {
    extern __shared__ char lds[];
    // T1: bijective XCD-chunked remap (m204)
    const int nwg = gridDim.x;
    const int xcd = blockIdx.x & 7, loc = blockIdx.x >> 3;
    const int q8 = nwg >> 3, r8 = nwg & 7;
    const int wgid = (xcd < r8 ? xcd * (q8 + 1) : r8 * (q8 + 1) + (xcd - r8) * q8) + loc;
    const int bm = wgid / nbn, bn = wgid % nbn;

    const int tid = threadIdx.x, lane = tid & 63, w = tid >> 6;
    const int li = lane & 15, lg = lane >> 4;
    const int wr = w >> 2, wc = w & 3;

    // staging: per-lane source offset; lr = row-in-8-group, lsw = swizzled col (elements)
    const int lr  = lane >> 3;
    const int lsw = ((lane & 7) ^ lr) << 3;
    const bf16* Agp = A  + (size_t)bm * 256 * 768;
    const bf16* Bgp = Bw + (size_t)bn * 256 * 768;
    const int clampA = Aclamp - bm * 256;

    // ds_read swizzled column bytes for k-slice 0/1
    const int sw_  = (li & 7) << 4;
    const int swc0 = (lg * 16) ^ sw_;
    const int swc1 = (64 | (lg * 16)) ^ sw_;

#define STAGE_A(Tt, h, j) do {                                                       \
        const int r0_ = (h) * 128 + w * 16 + (j) * 8;                                \
        int gr_ = r0_ + lr; if (gr_ >= clampA) gr_ = clampA - 1;                     \
        glds16(Agp + (size_t)gr_ * 768 + (Tt) * 64 + lsw,                            \
               lds + ((Tt) & 1) * 65536 + r0_ * 128); } while (0)
#define STAGE_B(Tt, h, j) do {                                                       \
        const int r0_ = (h) * 128 + w * 16 + (j) * 8;                                \
        glds16(Bgp + (size_t)(r0_ + lr) * 768 + (Tt) * 64 + lsw,                     \
               lds + ((Tt) & 1) * 65536 + 32768 + r0_ * 128); } while (0)

    f32x4 acc[8][4] = {};
    bf16x8 aF[4][2], bF0[2][2], bF1[2][2];

#define READ_A(mh)                                                                   \
    _Pragma("unroll") for (int mf = 0; mf < 4; ++mf) {                               \
        const char* p_ = ldsA + (size_t)(wr * 128 + (mh) * 64 + mf * 16 + li) * 128; \
        aF[mf][0] = *(const bf16x8*)(p_ + swc0);                                     \
        aF[mf][1] = *(const bf16x8*)(p_ + swc1); }
#define READ_B(nh, BF)                                                               \
    _Pragma("unroll") for (int nf = 0; nf < 2; ++nf) {                               \
        const char* p_ = ldsB + (size_t)(wc * 64 + (nh) * 32 + nf * 16 + li) * 128;  \
        BF[nf][0] = *(const bf16x8*)(p_ + swc0);                                     \
        BF[nf][1] = *(const bf16x8*)(p_ + swc1); }
#define MFMA_PHASE(mh, nh, BF)                                                       \
    _Pragma("unroll") for (int mf = 0; mf < 4; ++mf)                                 \
    _Pragma("unroll") for (int nf = 0; nf < 2; ++nf) {                               \
        acc[(mh)*4+mf][(nh)*2+nf] = MFMA16(aF[mf][0], BF[nf][0], acc[(mh)*4+mf][(nh)*2+nf]); \
        acc[(mh)*4+mf][(nh)*2+nf] = MFMA16(aF[mf][1], BF[nf][1], acc[(mh)*4+mf][(nh)*2+nf]); }

    // prologue: stage K-tiles 0 (buf0) then 1 (buf1); allow tile-1's 8 in flight
    STAGE_B(0,0,0); STAGE_B(0,0,1); STAGE_B(0,1,0); STAGE_B(0,1,1);
    STAGE_A(0,0,0); STAGE_A(0,0,1); STAGE_A(0,1,0); STAGE_A(0,1,1);
    STAGE_B(1,0,0); STAGE_B(1,0,1); STAGE_B(1,1,0); STAGE_B(1,1,1);
    STAGE_A(1,0,0); STAGE_A(1,0,1); STAGE_A(1,1,0); STAGE_A(1,1,1);
    asm volatile("s_waitcnt vmcnt(8)" ::: "memory");
    __builtin_amdgcn_s_barrier();

    #pragma unroll 2
    for (int T = 0; T < 12; ++T) {
        const char* ldsA = lds + (T & 1) * 65536;
        const char* ldsB = ldsA + 32768;
        const bool st = (T < 10);
        // ---- ph0: quadrant (m0,n0); reads A-mh0 (8) + B-nh0 (4)
        READ_A(0); READ_B(0, bF0);
        __builtin_amdgcn_s_barrier();
        asm volatile("s_waitcnt lgkmcnt(0)" ::: "memory");
        __builtin_amdgcn_sched_barrier(0);
        __builtin_amdgcn_s_setprio(1);
        MFMA_PHASE(0, 0, bF0);
        __builtin_amdgcn_s_setprio(0);
        __builtin_amdgcn_s_barrier();
        // ---- ph1: quadrant (m0,n1); reads B-nh1 (4)
        READ_B(1, bF1);
        __builtin_amdgcn_s_barrier();
        asm volatile("s_waitcnt lgkmcnt(0)" ::: "memory");
        __builtin_amdgcn_sched_barrier(0);
        __builtin_amdgcn_s_setprio(1);
        MFMA_PHASE(0, 1, bF1);
        __builtin_amdgcn_s_setprio(0);
        __builtin_amdgcn_s_barrier();
        // ---- ph2: quadrant (m1,n0); reads A-mh1 (8); stage B of T+2 (B last read ph1)
        READ_A(1);
        if (st) { STAGE_B(T+2,0,0); STAGE_B(T+2,0,1); STAGE_B(T+2,1,0); STAGE_B(T+2,1,1); }
        __builtin_amdgcn_s_barrier();
        asm volatile("s_waitcnt lgkmcnt(0)" ::: "memory");
        __builtin_amdgcn_sched_barrier(0);
        __builtin_amdgcn_s_setprio(1);
        MFMA_PHASE(1, 0, bF0);
        __builtin_amdgcn_s_setprio(0);
        __builtin_amdgcn_s_barrier();
        // ---- ph3: quadrant (m1,n1); stage A of T+2 (A last read ph2); counted wait
        if (st) { STAGE_A(T+2,0,0); STAGE_A(T+2,0,1); STAGE_A(T+2,1,0); STAGE_A(T+2,1,1); }
        __builtin_amdgcn_s_barrier();
        __builtin_amdgcn_sched_barrier(0);
        __builtin_amdgcn_s_setprio(1);
        MFMA_PHASE(1, 1, bF1);
        __builtin_amdgcn_s_setprio(0);
        if (T < 10)       asm volatile("s_waitcnt vmcnt(8)" ::: "memory");
        else if (T == 10) asm volatile("s_waitcnt vmcnt(0)" ::: "memory");
        __builtin_amdgcn_s_barrier();
    }
#undef STAGE_A
#undef STAGE_B
#undef READ_A
#undef READ_B
#undef MFMA_PHASE

    // epilogue
    #pragma unroll
    for (int m = 0; m < 8; ++m) {
        const int row0 = bm * 256 + wr * 128 + m * 16 + lg * 4;
        #pragma unroll
        for (int n = 0; n < 4; ++n) {
            const int col = bn * 256 + wc * 64 + n * 16 + li;
            #pragma unroll
            for (int r = 0; r < 4; ++r) {
                const int row = row0 + r;
                if (row < Mvalid) {
                    if constexpr (FINAL)
                        ((float*)Cptr)[(size_t)row * 768 + col] = acc[m][n][r] + bias[col];
                    else
                        ((bf16*)Cptr)[(size_t)row * 768 + col] = (bf16)acc[m][n][r];
                }
            }
        }
    }
}

// ---------------- depthwise 3x3x3 pool + LayerNorm(hd), vectorized ----------------
template<int S, int OH, int OW, int CH, int NP, int NPpad>
__global__ __launch_bounds__(256) void pool_norm2(const bf16* __restrict__ P,
                                                  const float* __restrict__ wt,
                                                  const float* __restrict__ gamma,
                                                  const float* __restrict__ beta,
                                                  bf16* __restrict__ outp,
                                                  float outScale) {
    constexpr int TASKS = TT * OH * CH + 1;
    const int w = threadIdx.x >> 6, lane = threadIdx.x & 63;
    const int gw = blockIdx.x * 4 + w;
    const int bh = gw / TASKS, task = gw % TASKS;
    const int b = bh / NH, head = bh % NH;
    const int owg = lane >> 3, cg = lane & 7, c = cg * 8;
    const size_t pbase = (size_t)b * NTOK * CC + head * HD + c;

    if (task == TASKS - 1) {
        if (owg == 0) {
            bf16x8 v = *(const bf16x8*)(P + pbase);
            float a[8];
            #pragma unroll
            for (int e = 0; e < 8; ++e) a[e] = (float)v[e];
            float s = 0;
            #pragma unroll
            for (int e = 0; e < 8; ++e) s += a[e];
            s += __shfl_xor(s, 1); s += __shfl_xor(s, 2); s += __shfl_xor(s, 4);
            const float mu = s * 0.015625f;
            float v2 = 0;
            #pragma unroll
            for (int e = 0; e < 8; ++e) { float d = a[e] - mu; v2 += d * d; }
            v2 += __shfl_xor(v2, 1); v2 += __shfl_xor(v2, 2); v2 += __shfl_xor(v2, 4);
            const float rs = rsqrtf(v2 * 0.015625f + 1e-5f);
            f32x4 g0 = *(const f32x4*)(gamma + c), g1 = *(const f32x4*)(gamma + c + 4);
            f32x4 b0 = *(const f32x4*)(beta + c),  b1 = *(const f32x4*)(beta + c + 4);
            bf16x8 o;
            #pragma unroll
            for (int e = 0; e < 4; ++e) {
                o[e]     = (bf16)(((a[e]     - mu) * rs * g0[e] + b0[e]) * outScale);
                o[4 + e] = (bf16)(((a[4 + e] - mu) * rs * g1[e] + b1[e]) * outScale);
            }
            *(bf16x8*)(outp + ((size_t)bh * NPpad) * HD + c) = o;
        } else {
            bf16x8 z = {};
            for (int p = NP + owg - 1; p < NPpad; p += 7)
                *(bf16x8*)(outp + ((size_t)bh * NPpad + p) * HD + c) = z;
        }
        return;
    }

    const int t  = task / (OH * CH);
    const int r2 = task % (OH * CH);
    const int oh = r2 / CH;
    const int ow = (r2 % CH) * 8 + owg;
    const bool active = (ow < OW);

    float acc[8] = {0, 0, 0, 0, 0, 0, 0, 0};
    #pragma unroll
    for (int dt = 0; dt < 3; ++dt) {
        const int it = t + dt - 1;
        if (it < 0 || it >= TT) continue;
        #pragma unroll
        for (int dh = 0; dh < 3; ++dh) {
            const int ih = oh * S + dh - 1;
            if (ih < 0 || ih >= HH) continue;
            const int tokrow = 1 + (it * HH + ih) * WW;
            #pragma unroll
            for (int dw = 0; dw < 3; ++dw) {
                const int iw = ow * S + dw - 1;
                if (active && iw >= 0) {
                    bf16x8 v = *(const bf16x8*)(P + pbase + (size_t)(tokrow + iw) * CC);
                    const float* wp = wt + ((dt * 3 + dh) * 3 + dw) * 64 + c;
                    f32x4 w0 = *(const f32x4*)wp, w1 = *(const f32x4*)(wp + 4);
                    #pragma unroll
                    for (int e = 0; e < 4; ++e) {
                        acc[e]     += w0[e] * (float)v[e];
                        acc[4 + e] += w1[e] * (float)v[4 + e];
                    }
                }
            }
        }
    }
    float s = 0;
    #pragma unroll
    for (int e = 0; e < 8; ++e) s += acc[e];
    s += __shfl_xor(s, 1); s += __shfl_xor(s, 2); s += __shfl_xor(s, 4);
    const float mu = s * 0.015625f;
    float v2 = 0;
    #pragma unroll
    for (int e = 0; e < 8; ++e) { float d = acc[e] - mu; v2 += d * d; }
    v2 += __shfl_xor(v2, 1); v2 += __shfl_xor(v2, 2); v2 += __shfl_xor(v2, 4);
    const float rs = rsqrtf(v2 * 0.015625f + 1e-5f);
    if (active) {
        f32x4 g0 = *(const f32x4*)(gamma + c), g1 = *(const f32x4*)(gamma + c + 4);
        f32x4 b0 = *(const f32x4*)(beta + c),  b1 = *(const f32x4*)(beta + c + 4);
        bf16x8 o;
        #pragma unroll
        for (int e = 0; e < 4; ++e) {
            o[e]     = (bf16)(((acc[e]     - mu) * rs * g0[e] + b0[e]) * outScale);
            o[4 + e] = (bf16)(((acc[4 + e] - mu) * rs * g1[e] + b1[e]) * outScale);
        }
        const int p = 1 + (t * OH + oh) * OW + ow;
        *(bf16x8*)(outp + ((size_t)bh * NPpad + p) * HD + c) = o;
    }
}

// ---------------- flash attention: q(1569x64) x k/v(393x64) per (b,head) ----------------
__global__ __launch_bounds__(256) void attn_kernel(const bf16* __restrict__ qn,
                                                   const bf16* __restrict__ kn,
                                                   const bf16* __restrict__ vn,
                                                   bf16* __restrict__ ob) {
    __shared__ bf16 Kl[32][72];
    __shared__ bf16 Vt[64][40];
    __shared__ float Pl[4][16][36];

    const int tid = threadIdx.x, l = tid & 63, w = tid >> 6;
    const int li = l & 15, lg = l >> 4;
    const int bh = blockIdx.y;
    const int b = bh / NH, head = bh % NH;
    const int qbase = blockIdx.x * 64 + w * 16;

    const bf16* qp = qn + ((size_t)bh * NQP + qbase + li) * HD + lg * 8;
    const bf16x8 aq0 = *(const bf16x8*)qp;
    const bf16x8 aq1 = *(const bf16x8*)(qp + 32);

    f32x4 oacc[4] = {};
    float mrun[4], lrun[4];
    #pragma unroll
    for (int r = 0; r < 4; ++r) { mrun[r] = -1e30f; lrun[r] = 0.f; }

    for (int kt = 0; kt < NKP / 32; ++kt) {
        const int j0 = kt * 32;
        {
            const int row = tid >> 3, g8 = (tid & 7) * 8;
            u32x4 kv = *(const u32x4*)(kn + ((size_t)bh * NKP + j0 + row) * HD + g8);
            *(u32x4*)&Kl[row][g8] = kv;
        }
        {
            const int j = tid & 31, d8 = tid >> 5;
            u32x4 vv4 = *(const u32x4*)(vn + ((size_t)bh * NKP + j0 + j) * HD + d8 * 8);
            bf16x8 vv = __builtin_bit_cast(bf16x8, vv4);
            #pragma unroll
            for (int e = 0; e < 8; ++e) Vt[d8 * 8 + e][j] = vv[e];
        }
        __syncthreads();

        f32x4 c0 = {}, c1 = {};
        const bf16x8 b00 = *(const bf16x8*)&Kl[li][lg * 8];
        const bf16x8 b01 = *(const bf16x8*)&Kl[li][32 + lg * 8];
        const bf16x8 b10 = *(const bf16x8*)&Kl[16 + li][lg * 8];
        const bf16x8 b11 = *(const bf16x8*)&Kl[16 + li][32 + lg * 8];
        c0 = MFMA16(aq0, b00, c0); c0 = MFMA16(aq1, b01, c0);
        c1 = MFMA16(aq0, b10, c1); c1 = MFMA16(aq1, b11, c1);

        const bool msk0 = (j0 + li) >= NK, msk1 = (j0 + 16 + li) >= NK;
        float p0[4], p1[4];
        #pragma unroll
        for (int r = 0; r < 4; ++r) {
            const float s0 = msk0 ? -1e30f : c0[r];
            const float s1 = msk1 ? -1e30f : c1[r];
            float t = fmaxf(s0, s1);
            t = fmaxf(t, __shfl_xor(t, 1));
            t = fmaxf(t, __shfl_xor(t, 2));
            t = fmaxf(t, __shfl_xor(t, 4));
            t = fmaxf(t, __shfl_xor(t, 8));
            const float mn = fmaxf(mrun[r], t);
            const float sc = __expf(mrun[r] - mn);
            const float e0 = __expf(s0 - mn);
            const float e1 = __expf(s1 - mn);
            float rsum = e0 + e1;
            rsum += __shfl_xor(rsum, 1);
            rsum += __shfl_xor(rsum, 2);
            rsum += __shfl_xor(rsum, 4);
            rsum += __shfl_xor(rsum, 8);
            lrun[r] = lrun[r] * sc + rsum;
            mrun[r] = mn;
            p0[r] = e0; p1[r] = e1;
            #pragma unroll
            for (int dg = 0; dg < 4; ++dg) oacc[dg][r] *= sc;
        }
        #pragma unroll
        for (int r = 0; r < 4; ++r) {
            Pl[w][lg * 4 + r][li]      = p0[r];
            Pl[w][lg * 4 + r][16 + li] = p1[r];
        }
        const f32x4 pa = *(const f32x4*)&Pl[w][li][lg * 8];
        const f32x4 pb = *(const f32x4*)&Pl[w][li][lg * 8 + 4];
        bf16x8 ap;
        #pragma unroll
        for (int e = 0; e < 4; ++e) { ap[e] = (bf16)pa[e]; ap[4 + e] = (bf16)pb[e]; }
        #pragma unroll
        for (int dg = 0; dg < 4; ++dg) {
            const bf16x8 bv = *(const bf16x8*)&Vt[dg * 16 + li][lg * 8];
            oacc[dg] = MFMA16(ap, bv, oacc[dg]);
        }
        __syncthreads();
    }
    #pragma unroll
    for (int r = 0; r < 4; ++r) {
        const int q = qbase + lg * 4 + r;
        if (q < NQ) {
            const float inv = 1.f / lrun[r];
            const size_t off = ((size_t)(b * NQ + q)) * CC + head * HD;
            #pragma unroll
            for (int dg = 0; dg < 4; ++dg)
                ob[off + dg * 16 + li] = (bf16)(oacc[dg][r] * inv);
        }
    }
}

// ---------------- launcher ----------------
extern "C" void kernel_launch(void* const* d_in, const int* in_sizes, int n_in,
                              void* d_out, int out_size, void* d_ws, size_t ws_size,
                              hipStream_t stream) {
    const float* x     = (const float*)d_in[0];
    const float* Wq    = (const float*)d_in[1];
    const float* Wk    = (const float*)d_in[2];
    const float* Wv    = (const float*)d_in[3];
    const float* Wproj = (const float*)d_in[4];
    const float* bproj = (const float*)d_in[5];
    const float* pqw   = (const float*)d_in[6];
    const float* pkw   = (const float*)d_in[7];
    const float* pvw   = (const float*)d_in[8];
    const float* gq    = (const float*)d_in[9];
    const float* bq    = (const float*)d_in[10];
    const float* gk    = (const float*)d_in[11];
    const float* bk    = (const float*)d_in[12];
    const float* gv    = (const float*)d_in[13];
    const float* bv    = (const float*)d_in[14];

    if (ws_size < 208601088ULL) return;
    char* ws = (char*)d_ws;
    bf16* xb   = (bf16*)(ws);               // [50304][768]
    bf16* wqkv = (bf16*)(ws + 77266944);    // [2304][768]
    bf16* wpb  = (bf16*)(ws + 80805888);    // [768][768]
    bf16* tmp  = (bf16*)(ws + 81985536);    // [50304][768]
    bf16* qn   = (bf16*)(ws + 159252480);   // [96][1600][64]
    bf16* kn   = (bf16*)(ws + 178913280);   // [96][416][64]
    bf16* vnb  = (bf16*)(ws + 184025088);   // [96][416][64]
    bf16* ob   = (bf16*)(ws + 189136896);   // [12672][768]
    float* wt  = (float*)(ws + 189136896);  // [3][27][64] f32 (overlay, dead before attn)

    const int WSZ = 589824;  // 768*768

    (void)hipFuncSetAttribute((const void*)gemm256<false>,
                              hipFuncAttributeMaxDynamicSharedMemorySize, 131072);
    (void)hipFuncSetAttribute((const void*)gemm256<true>,
                              hipFuncAttributeMaxDynamicSharedMemorySize, 131072);

    transpose_w3<<<21, 256, 0, stream>>>(pqw, pkw, pvw, wt);
    cast_f32_bf16<<<4096, 256, 0, stream>>>(x, xb, MX * CC, MXP * CC);
    cast_f32_bf16<<<576, 256, 0, stream>>>(Wq, wqkv,            WSZ, WSZ);
    cast_f32_bf16<<<576, 256, 0, stream>>>(Wk, wqkv + WSZ,      WSZ, WSZ);
    cast_f32_bf16<<<576, 256, 0, stream>>>(Wv, wqkv + 2 * WSZ,  WSZ, WSZ);
    cast_f32_bf16<<<576, 256, 0, stream>>>(Wproj, wpb,          WSZ, WSZ);

    // Q: proj + pool(stride 1,2,2) + LN  (scale 0.125 baked in)
    gemm256<false><<<197 * 3, 512, 131072, stream>>>(xb, wqkv, tmp, nullptr, 3, MXP, MXP);
    pool_norm2<2, 14, 14, 2, NQ, NQP><<<5400, 256, 0, stream>>>(tmp, wt, gq, bq, qn, 0.125f);
    // K: proj + pool(stride 1,4,4) + LN
    gemm256<false><<<197 * 3, 512, 131072, stream>>>(xb, wqkv + WSZ, tmp, nullptr, 3, MXP, MXP);
    pool_norm2<4, 7, 7, 1, NK, NKP><<<1368, 256, 0, stream>>>(tmp, wt + 1728, gk, bk, kn, 1.0f);
    // V: proj + pool(stride 1,4,4) + LN
    gemm256<false><<<197 * 3, 512, 131072, stream>>>(xb, wqkv + 2 * WSZ, tmp, nullptr, 3, MXP, MXP);
    pool_norm2<4, 7, 7, 1, NK, NKP><<<1368, 256, 0, stream>>>(tmp, wt + 3456, gv, bv, vnb, 1.0f);

    attn_kernel<<<dim3(25, 96), 256, 0, stream>>>(qn, kn, vnb, ob);

    gemm256<true><<<50 * 3, 512, 131072, stream>>>(ob, wpb, d_out, bproj, 3, MO, MOP);
}

// Round 4
// 464.683 us; speedup vs baseline: 1.6996x; 1.0913x over previous
//
#include <hip/hip_runtime.h>

using bf16   = __bf16;
using bf16x4 = __attribute__((ext_vector_type(4))) __bf16;
using bf16x8 = __attribute__((ext_vector_type(8))) __bf16;
using f32x4  = __attribute__((ext_vector_type(4))) float;
using u32x4  = __attribute__((ext_vector_type(4))) unsigned int;

#define MFMA16(a,b,c) __builtin_amdgcn_mfma_f32_16x16x32_bf16((a),(b),(c),0,0,0)

__device__ inline void glds16(const void* g, void* l) {
    __builtin_amdgcn_global_load_lds(
        (__attribute__((address_space(1))) void*)(const_cast<void*>(g)),
        (__attribute__((address_space(3))) void*)(l), 16, 0, 0);
}

// ---------------- constants (problem-instance fixed) ----------------
constexpr int CB   = 8;
constexpr int NH   = 12;
constexpr int CC   = 768;
constexpr int HD   = 64;
constexpr int TT   = 8, HH = 28, WW = 28;
constexpr int NTOK = TT*HH*WW + 1;      // 6273
constexpr int MX   = CB*NTOK;           // 50184
constexpr int MXP  = 50304;             // padded M rows in xb/tmp
constexpr int NQ   = 1569, NQP = 1600;
constexpr int NK   = 393,  NKP = 416;
constexpr int MO   = CB*NQ;             // 12552
constexpr int MOP  = 12672;

// ---------------- f32 -> bf16 cast (with zero tail pad) ----------------
__global__ __launch_bounds__(256) void cast_f32_bf16(const float* __restrict__ src,
                                                     bf16* __restrict__ dst,
                                                     int nvalid, int ntotal) {
    int i = (blockIdx.x * 256 + threadIdx.x) * 4;
    int stride = gridDim.x * 256 * 4;
    for (; i < ntotal; i += stride) {
        bf16x4 o;
        if (i + 3 < nvalid) {
            f32x4 v = *(const f32x4*)(src + i);
            #pragma unroll
            for (int e = 0; e < 4; ++e) o[e] = (bf16)v[e];
        } else {
            #pragma unroll
            for (int e = 0; e < 4; ++e) {
                int k = i + e;
                o[e] = (bf16)((k < nvalid) ? src[k] : 0.f);
            }
        }
        *(bf16x4*)(dst + i) = o;
    }
}

// ---------------- weight transpose: (64,27) -> [27][64], 3 sets ----------------
__global__ __launch_bounds__(256) void transpose_w3(const float* __restrict__ w0,
                                                    const float* __restrict__ w1,
                                                    const float* __restrict__ w2,
                                                    float* __restrict__ wt) {
    int i = blockIdx.x * 256 + threadIdx.x;
    if (i >= 3 * 1728) return;
    int setn = i / 1728, j = i % 1728;
    const float* src = (setn == 0) ? w0 : (setn == 1) ? w1 : w2;
    int tap = j / 64, c = j % 64;
    wt[i] = src[c * 27 + tap];
}

// ---------------- score-bound kernel: M = 0.125 * Bq * Bk ----------------
// LN output norm <= 8 exactly; ||q|| <= 8*max|g| + ||b|| (hard Cauchy-Schwarz bound).
__global__ void bound_kernel(const float* __restrict__ gq, const float* __restrict__ bq,
                             const float* __restrict__ gk, const float* __restrict__ bk,
                             float* __restrict__ out) {
    const int c = threadIdx.x;   // 64 threads
    float mgq = fabsf(gq[c]), sbq = bq[c] * bq[c];
    float mgk = fabsf(gk[c]), sbk = bk[c] * bk[c];
    #pragma unroll
    for (int m = 1; m < 64; m <<= 1) {
        mgq = fmaxf(mgq, __shfl_xor(mgq, m)); sbq += __shfl_xor(sbq, m);
        mgk = fmaxf(mgk, __shfl_xor(mgk, m)); sbk += __shfl_xor(sbk, m);
    }
    if (c == 0) {
        const float Bq = 8.f * mgq + sqrtf(sbq);
        const float Bk = 8.f * mgk + sqrtf(sbk);
        out[0] = 0.125f * Bq * Bk;
    }
}

// ---------------- 256x256 8-phase bf16 GEMM (HK/m201-style, plain HIP) ----------------
template<bool FINAL>
__global__ __launch_bounds__(512, 2) void gemm256(const bf16* __restrict__ A,
                                                  const bf16* __restrict__ Bw,
                                                  void* __restrict__ Cptr,
                                                  const float* __restrict__ bias,
                                                  int nbn, int Mvalid, int Aclamp) {
    extern __shared__ char lds[];
    const int nwg = gridDim.x;
    const int xcd = blockIdx.x & 7, loc = blockIdx.x >> 3;
    const int q8 = nwg >> 3, r8 = nwg & 7;
    const int wgid = (xcd < r8 ? xcd * (q8 + 1) : r8 * (q8 + 1) + (xcd - r8) * q8) + loc;
    const int bm = wgid / nbn, bn = wgid % nbn;

    const int tid = threadIdx.x, lane = tid & 63, w = tid >> 6;
    const int li = lane & 15, lg = lane >> 4;
    const int wr = w >> 2, wc = w & 3;

    const int lr  = lane >> 3;
    const int lsw = ((lane & 7) ^ lr) << 3;
    const bf16* Agp = A  + (size_t)bm * 256 * 768;
    const bf16* Bgp = Bw + (size_t)bn * 256 * 768;
    const int clampA = Aclamp - bm * 256;

    const int sw_  = (li & 7) << 4;
    const int swc0 = (lg * 16) ^ sw_;
    const int swc1 = (64 | (lg * 16)) ^ sw_;

#define STAGE_A(Tt, h, j) do {                                                       \
        const int r0_ = (h) * 128 + w * 16 + (j) * 8;                                \
        int gr_ = r0_ + lr; if (gr_ >= clampA) gr_ = clampA - 1;                     \
        glds16(Agp + (size_t)gr_ * 768 + (Tt) * 64 + lsw,                            \
               lds + ((Tt) & 1) * 65536 + r0_ * 128); } while (0)
#define STAGE_B(Tt, h, j) do {                                                       \
        const int r0_ = (h) * 128 + w * 16 + (j) * 8;                                \
        glds16(Bgp + (size_t)(r0_ + lr) * 768 + (Tt) * 64 + lsw,                     \
               lds + ((Tt) & 1) * 65536 + 32768 + r0_ * 128); } while (0)

    f32x4 acc[8][4] = {};
    bf16x8 aF[4][2], bF0[2][2], bF1[2][2];

#define READ_A(mh)                                                                   \
    _Pragma("unroll") for (int mf = 0; mf < 4; ++mf) {                               \
        const char* p_ = ldsA + (size_t)(wr * 128 + (mh) * 64 + mf * 16 + li) * 128; \
        aF[mf][0] = *(const bf16x8*)(p_ + swc0);                                     \
        aF[mf][1] = *(const bf16x8*)(p_ + swc1); }
#define READ_B(nh, BF)                                                               \
    _Pragma("unroll") for (int nf = 0; nf < 2; ++nf) {                               \
        const char* p_ = ldsB + (size_t)(wc * 64 + (nh) * 32 + nf * 16 + li) * 128;  \
        BF[nf][0] = *(const bf16x8*)(p_ + swc0);                                     \
        BF[nf][1] = *(const bf16x8*)(p_ + swc1); }
#define MFMA_PHASE(mh, nh, BF)                                                       \
    _Pragma("unroll") for (int mf = 0; mf < 4; ++mf)                                 \
    _Pragma("unroll") for (int nf = 0; nf < 2; ++nf) {                               \
        acc[(mh)*4+mf][(nh)*2+nf] = MFMA16(aF[mf][0], BF[nf][0], acc[(mh)*4+mf][(nh)*2+nf]); \
        acc[(mh)*4+mf][(nh)*2+nf] = MFMA16(aF[mf][1], BF[nf][1], acc[(mh)*4+mf][(nh)*2+nf]); }

    STAGE_B(0,0,0); STAGE_B(0,0,1); STAGE_B(0,1,0); STAGE_B(0,1,1);
    STAGE_A(0,0,0); STAGE_A(0,0,1); STAGE_A(0,1,0); STAGE_A(0,1,1);
    STAGE_B(1,0,0); STAGE_B(1,0,1); STAGE_B(1,1,0); STAGE_B(1,1,1);
    STAGE_A(1,0,0); STAGE_A(1,0,1); STAGE_A(1,1,0); STAGE_A(1,1,1);
    asm volatile("s_waitcnt vmcnt(8)" ::: "memory");
    __builtin_amdgcn_s_barrier();

    #pragma unroll 2
    for (int T = 0; T < 12; ++T) {
        const char* ldsA = lds + (T & 1) * 65536;
        const char* ldsB = ldsA + 32768;
        const bool st = (T < 10);
        READ_A(0); READ_B(0, bF0);
        __builtin_amdgcn_s_barrier();
        asm volatile("s_waitcnt lgkmcnt(0)" ::: "memory");
        __builtin_amdgcn_sched_barrier(0);
        __builtin_amdgcn_s_setprio(1);
        MFMA_PHASE(0, 0, bF0);
        __builtin_amdgcn_s_setprio(0);
        __builtin_amdgcn_s_barrier();
        READ_B(1, bF1);
        __builtin_amdgcn_s_barrier();
        asm volatile("s_waitcnt lgkmcnt(0)" ::: "memory");
        __builtin_amdgcn_sched_barrier(0);
        __builtin_amdgcn_s_setprio(1);
        MFMA_PHASE(0, 1, bF1);
        __builtin_amdgcn_s_setprio(0);
        __builtin_amdgcn_s_barrier();
        READ_A(1);
        if (st) { STAGE_B(T+2,0,0); STAGE_B(T+2,0,1); STAGE_B(T+2,1,0); STAGE_B(T+2,1,1); }
        __builtin_amdgcn_s_barrier();
        asm volatile("s_waitcnt lgkmcnt(0)" ::: "memory");
        __builtin_amdgcn_sched_barrier(0);
        __builtin_amdgcn_s_setprio(1);
        MFMA_PHASE(1, 0, bF0);
        __builtin_amdgcn_s_setprio(0);
        __builtin_amdgcn_s_barrier();
        if (st) { STAGE_A(T+2,0,0); STAGE_A(T+2,0,1); STAGE_A(T+2,1,0); STAGE_A(T+2,1,1); }
        __builtin_amdgcn_s_barrier();
        __builtin_amdgcn_sched_barrier(0);
        __builtin_amdgcn_s_setprio(1);
        MFMA_PHASE(1, 1, bF1);
        __builtin_amdgcn_s_setprio(0);
        if (T < 10)       asm volatile("s_waitcnt vmcnt(8)" ::: "memory");
        else if (T == 10) asm volatile("s_waitcnt vmcnt(0)" ::: "memory");
        __builtin_amdgcn_s_barrier();
    }
#undef STAGE_A
#undef STAGE_B
#undef READ_A
#undef READ_B
#undef MFMA_PHASE

    #pragma unroll
    for (int m = 0; m < 8; ++m) {
        const int row0 = bm * 256 + wr * 128 + m * 16 + lg * 4;
        #pragma unroll
        for (int n = 0; n < 4; ++n) {
            const int col = bn * 256 + wc * 64 + n * 16 + li;
            #pragma unroll
            for (int r = 0; r < 4; ++r) {
                const int row = row0 + r;
                if (row < Mvalid) {
                    if constexpr (FINAL)
                        ((float*)Cptr)[(size_t)row * 768 + col] = acc[m][n][r] + bias[col];
                    else
                        ((bf16*)Cptr)[(size_t)row * 768 + col] = (bf16)acc[m][n][r];
                }
            }
        }
    }
}

// ---------------- depthwise 3x3x3 pool + LayerNorm(hd), vectorized ----------------
template<int S, int OH, int OW, int CH, int NP, int NPpad>
__global__ __launch_bounds__(256) void pool_norm2(const bf16* __restrict__ P,
                                                  const float* __restrict__ wt,
                                                  const float* __restrict__ gamma,
                                                  const float* __restrict__ beta,
                                                  bf16* __restrict__ outp,
                                                  float outScale) {
    constexpr int TASKS = TT * OH * CH + 1;
    const int w = threadIdx.x >> 6, lane = threadIdx.x & 63;
    const int gw = blockIdx.x * 4 + w;
    const int bh = gw / TASKS, task = gw % TASKS;
    const int b = bh / NH, head = bh % NH;
    const int owg = lane >> 3, cg = lane & 7, c = cg * 8;
    const size_t pbase = (size_t)b * NTOK * CC + head * HD + c;

    if (task == TASKS - 1) {
        if (owg == 0) {
            bf16x8 v = *(const bf16x8*)(P + pbase);
            float a[8];
            #pragma unroll
            for (int e = 0; e < 8; ++e) a[e] = (float)v[e];
            float s = 0;
            #pragma unroll
            for (int e = 0; e < 8; ++e) s += a[e];
            s += __shfl_xor(s, 1); s += __shfl_xor(s, 2); s += __shfl_xor(s, 4);
            const float mu = s * 0.015625f;
            float v2 = 0;
            #pragma unroll
            for (int e = 0; e < 8; ++e) { float d = a[e] - mu; v2 += d * d; }
            v2 += __shfl_xor(v2, 1); v2 += __shfl_xor(v2, 2); v2 += __shfl_xor(v2, 4);
            const float rs = rsqrtf(v2 * 0.015625f + 1e-5f);
            f32x4 g0 = *(const f32x4*)(gamma + c), g1 = *(const f32x4*)(gamma + c + 4);
            f32x4 b0 = *(const f32x4*)(beta + c),  b1 = *(const f32x4*)(beta + c + 4);
            bf16x8 o;
            #pragma unroll
            for (int e = 0; e < 4; ++e) {
                o[e]     = (bf16)(((a[e]     - mu) * rs * g0[e] + b0[e]) * outScale);
                o[4 + e] = (bf16)(((a[4 + e] - mu) * rs * g1[e] + b1[e]) * outScale);
            }
            *(bf16x8*)(outp + ((size_t)bh * NPpad) * HD + c) = o;
        } else {
            bf16x8 z = {};
            for (int p = NP + owg - 1; p < NPpad; p += 7)
                *(bf16x8*)(outp + ((size_t)bh * NPpad + p) * HD + c) = z;
        }
        return;
    }

    const int t  = task / (OH * CH);
    const int r2 = task % (OH * CH);
    const int oh = r2 / CH;
    const int ow = (r2 % CH) * 8 + owg;
    const bool active = (ow < OW);

    float acc[8] = {0, 0, 0, 0, 0, 0, 0, 0};
    #pragma unroll
    for (int dt = 0; dt < 3; ++dt) {
        const int it = t + dt - 1;
        if (it < 0 || it >= TT) continue;
        #pragma unroll
        for (int dh = 0; dh < 3; ++dh) {
            const int ih = oh * S + dh - 1;
            if (ih < 0 || ih >= HH) continue;
            const int tokrow = 1 + (it * HH + ih) * WW;
            #pragma unroll
            for (int dw = 0; dw < 3; ++dw) {
                const int iw = ow * S + dw - 1;
                if (active && iw >= 0) {
                    bf16x8 v = *(const bf16x8*)(P + pbase + (size_t)(tokrow + iw) * CC);
                    const float* wp = wt + ((dt * 3 + dh) * 3 + dw) * 64 + c;
                    f32x4 w0 = *(const f32x4*)wp, w1 = *(const f32x4*)(wp + 4);
                    #pragma unroll
                    for (int e = 0; e < 4; ++e) {
                        acc[e]     += w0[e] * (float)v[e];
                        acc[4 + e] += w1[e] * (float)v[4 + e];
                    }
                }
            }
        }
    }
    float s = 0;
    #pragma unroll
    for (int e = 0; e < 8; ++e) s += acc[e];
    s += __shfl_xor(s, 1); s += __shfl_xor(s, 2); s += __shfl_xor(s, 4);
    const float mu = s * 0.015625f;
    float v2 = 0;
    #pragma unroll
    for (int e = 0; e < 8; ++e) { float d = acc[e] - mu; v2 += d * d; }
    v2 += __shfl_xor(v2, 1); v2 += __shfl_xor(v2, 2); v2 += __shfl_xor(v2, 4);
    const float rs = rsqrtf(v2 * 0.015625f + 1e-5f);
    if (active) {
        f32x4 g0 = *(const f32x4*)(gamma + c), g1 = *(const f32x4*)(gamma + c + 4);
        f32x4 b0 = *(const f32x4*)(beta + c),  b1 = *(const f32x4*)(beta + c + 4);
        bf16x8 o;
        #pragma unroll
        for (int e = 0; e < 4; ++e) {
            o[e]     = (bf16)(((acc[e]     - mu) * rs * g0[e] + b0[e]) * outScale);
            o[4 + e] = (bf16)(((acc[4 + e] - mu) * rs * g1[e] + b1[e]) * outScale);
        }
        const int p = 1 + (t * OH + oh) * OW + ow;
        *(bf16x8*)(outp + ((size_t)bh * NPpad + p) * HD + c) = o;
    }
}

// ---------------- flash attention, fixed-max softmax ----------------
// Scores s <= M (hard bound). P = exp(s - M): no running max, no rescale; the
// softmax denominator is a plain deferred sum reduced once in the epilogue.
// K/V tiles double-buffered: global->reg issued before compute, LDS write after.
__global__ __launch_bounds__(256) void attn_kernel(const bf16* __restrict__ qn,
                                                   const bf16* __restrict__ kn,
                                                   const bf16* __restrict__ vn,
                                                   bf16* __restrict__ ob,
                                                   const float* __restrict__ Mptr) {
    __shared__ bf16 Kl[2][32][72];
    __shared__ bf16 Vt[2][64][40];
    __shared__ bf16 Pl[4][16][40];

    const int tid = threadIdx.x, l = tid & 63, w = tid >> 6;
    const int li = l & 15, lg = l >> 4;
    const int bh = blockIdx.y;
    const int b = bh / NH, head = bh % NH;
    const int qbase = blockIdx.x * 64 + w * 16;
    const float M = Mptr[0];

    const bf16* qp = qn + ((size_t)bh * NQP + qbase + li) * HD + lg * 8;
    const bf16x8 aq0 = *(const bf16x8*)qp;
    const bf16x8 aq1 = *(const bf16x8*)(qp + 32);

    const int srow = tid >> 3, scol = (tid & 7) * 8;   // K staging: [32][64]
    const int sj = tid & 31, sd8 = tid >> 5;           // V staging (transpose)
    const bf16* kbase = kn + (size_t)bh * NKP * HD;
    const bf16* vbase = vn + (size_t)bh * NKP * HD;

    // tile 0 -> LDS buf0
    u32x4 kv = *(const u32x4*)(kbase + srow * HD + scol);
    u32x4 vv = *(const u32x4*)(vbase + sj * HD + sd8 * 8);
    *(u32x4*)&Kl[0][srow][scol] = kv;
    {
        bf16x8 t = __builtin_bit_cast(bf16x8, vv);
        #pragma unroll
        for (int e = 0; e < 8; ++e) Vt[0][sd8 * 8 + e][sj] = t[e];
    }

    f32x4 oacc[4] = {};
    float lpart[4] = {0.f, 0.f, 0.f, 0.f};

    for (int kt = 0; kt < 13; ++kt) {
        const int cur = kt & 1;
        if (kt < 12) {   // prefetch next tile into regs (latency hidden under compute)
            kv = *(const u32x4*)(kbase + (kt + 1) * 32 * HD + srow * HD + scol);
            vv = *(const u32x4*)(vbase + (kt + 1) * 32 * HD + sj * HD + sd8 * 8);
        }
        __syncthreads();

        f32x4 c0 = {}, c1 = {};
        const bf16x8 b00 = *(const bf16x8*)&Kl[cur][li][lg * 8];
        const bf16x8 b01 = *(const bf16x8*)&Kl[cur][li][32 + lg * 8];
        const bf16x8 b10 = *(const bf16x8*)&Kl[cur][16 + li][lg * 8];
        const bf16x8 b11 = *(const bf16x8*)&Kl[cur][16 + li][32 + lg * 8];
        __builtin_amdgcn_s_setprio(1);
        c0 = MFMA16(aq0, b00, c0); c0 = MFMA16(aq1, b01, c0);
        c1 = MFMA16(aq0, b10, c1); c1 = MFMA16(aq1, b11, c1);
        __builtin_amdgcn_s_setprio(0);

        float p0[4], p1[4];
        #pragma unroll
        for (int r = 0; r < 4; ++r) {
            p0[r] = __expf(c0[r] - M);
            p1[r] = __expf(c1[r] - M);
        }
        if (kt == 12) {   // only the last tile has invalid columns (384..415 vs NK=393)
            const bool m0 = (384 + li) >= NK;
            #pragma unroll
            for (int r = 0; r < 4; ++r) { if (m0) p0[r] = 0.f; p1[r] = 0.f; }
        }
        #pragma unroll
        for (int r = 0; r < 4; ++r) {
            lpart[r] += p0[r] + p1[r];
            Pl[w][lg * 4 + r][li]      = (bf16)p0[r];
            Pl[w][lg * 4 + r][16 + li] = (bf16)p1[r];
        }
        const bf16x8 ap = *(const bf16x8*)&Pl[w][li][lg * 8];
        __builtin_amdgcn_s_setprio(1);
        #pragma unroll
        for (int dg = 0; dg < 4; ++dg) {
            const bf16x8 bv = *(const bf16x8*)&Vt[cur][dg * 16 + li][lg * 8];
            oacc[dg] = MFMA16(ap, bv, oacc[dg]);
        }
        __builtin_amdgcn_s_setprio(0);

        if (kt < 12) {   // write prefetched tile to the other buffer (WAR-safe: see barrier)
            const int nxt = cur ^ 1;
            *(u32x4*)&Kl[nxt][srow][scol] = kv;
            bf16x8 t = __builtin_bit_cast(bf16x8, vv);
            #pragma unroll
            for (int e = 0; e < 8; ++e) Vt[nxt][sd8 * 8 + e][sj] = t[e];
        }
    }
    // epilogue: reduce l across the 16 li lanes, normalize, store
    #pragma unroll
    for (int r = 0; r < 4; ++r) {
        float lsum = lpart[r];
        lsum += __shfl_xor(lsum, 1);
        lsum += __shfl_xor(lsum, 2);
        lsum += __shfl_xor(lsum, 4);
        lsum += __shfl_xor(lsum, 8);
        const int q = qbase + lg * 4 + r;
        if (q < NQ) {
            const float inv = 1.f / lsum;
            const size_t off = ((size_t)(b * NQ + q)) * CC + head * HD;
            #pragma unroll
            for (int dg = 0; dg < 4; ++dg)
                ob[off + dg * 16 + li] = (bf16)(oacc[dg][r] * inv);
        }
    }
}

// ---------------- launcher ----------------
extern "C" void kernel_launch(void* const* d_in, const int* in_sizes, int n_in,
                              void* d_out, int out_size, void* d_ws, size_t ws_size,
                              hipStream_t stream) {
    const float* x     = (const float*)d_in[0];
    const float* Wq    = (const float*)d_in[1];
    const float* Wk    = (const float*)d_in[2];
    const float* Wv    = (const float*)d_in[3];
    const float* Wproj = (const float*)d_in[4];
    const float* bproj = (const float*)d_in[5];
    const float* pqw   = (const float*)d_in[6];
    const float* pkw   = (const float*)d_in[7];
    const float* pvw   = (const float*)d_in[8];
    const float* gq    = (const float*)d_in[9];
    const float* bq    = (const float*)d_in[10];
    const float* gk    = (const float*)d_in[11];
    const float* bk    = (const float*)d_in[12];
    const float* gv    = (const float*)d_in[13];
    const float* bv    = (const float*)d_in[14];

    if (ws_size < 208601088ULL) return;
    char* ws = (char*)d_ws;
    bf16* xb   = (bf16*)(ws);               // [50304][768]
    bf16* wqkv = (bf16*)(ws + 77266944);    // [2304][768]
    bf16* wpb  = (bf16*)(ws + 80805888);    // [768][768]
    bf16* tmp  = (bf16*)(ws + 81985536);    // [50304][768]
    bf16* qn   = (bf16*)(ws + 159252480);   // [96][1600][64]
    bf16* kn   = (bf16*)(ws + 178913280);   // [96][416][64]
    bf16* vnb  = (bf16*)(ws + 184025088);   // [96][416][64]
    bf16* ob   = (bf16*)(ws + 189136896);   // [12672][768]
    float* wt  = (float*)(ws + 189136896);  // [3][27][64] f32 (overlay, dead before attn)
    float* Mb  = (float*)(ws + 81985536);   // overlays tmp[0]: written after pool_v, read by attn

    const int WSZ = 589824;  // 768*768

    (void)hipFuncSetAttribute((const void*)gemm256<false>,
                              hipFuncAttributeMaxDynamicSharedMemorySize, 131072);
    (void)hipFuncSetAttribute((const void*)gemm256<true>,
                              hipFuncAttributeMaxDynamicSharedMemorySize, 131072);

    transpose_w3<<<21, 256, 0, stream>>>(pqw, pkw, pvw, wt);
    cast_f32_bf16<<<4096, 256, 0, stream>>>(x, xb, MX * CC, MXP * CC);
    cast_f32_bf16<<<576, 256, 0, stream>>>(Wq, wqkv,            WSZ, WSZ);
    cast_f32_bf16<<<576, 256, 0, stream>>>(Wk, wqkv + WSZ,      WSZ, WSZ);
    cast_f32_bf16<<<576, 256, 0, stream>>>(Wv, wqkv + 2 * WSZ,  WSZ, WSZ);
    cast_f32_bf16<<<576, 256, 0, stream>>>(Wproj, wpb,          WSZ, WSZ);

    // Q: proj + pool(stride 1,2,2) + LN  (scale 0.125 baked in)
    gemm256<false><<<197 * 3, 512, 131072, stream>>>(xb, wqkv, tmp, nullptr, 3, MXP, MXP);
    pool_norm2<2, 14, 14, 2, NQ, NQP><<<5400, 256, 0, stream>>>(tmp, wt, gq, bq, qn, 0.125f);
    // K: proj + pool(stride 1,4,4) + LN
    gemm256<false><<<197 * 3, 512, 131072, stream>>>(xb, wqkv + WSZ, tmp, nullptr, 3, MXP, MXP);
    pool_norm2<4, 7, 7, 1, NK, NKP><<<1368, 256, 0, stream>>>(tmp, wt + 1728, gk, bk, kn, 1.0f);
    // V: proj + pool(stride 1,4,4) + LN
    gemm256<false><<<197 * 3, 512, 131072, stream>>>(xb, wqkv + 2 * WSZ, tmp, nullptr, 3, MXP, MXP);
    pool_norm2<4, 7, 7, 1, NK, NKP><<<1368, 256, 0, stream>>>(tmp, wt + 3456, gv, bv, vnb, 1.0f);

    // score bound (tmp is dead after pool_v; stash M in its first 4 bytes)
    bound_kernel<<<1, 64, 0, stream>>>(gq, bq, gk, bk, Mb);

    attn_kernel<<<dim3(25, 96), 256, 0, stream>>>(qn, kn, vnb, ob, Mb);

    gemm256<true><<<50 * 3, 512, 131072, stream>>>(ob, wpb, d_out, bproj, 3, MO, MOP);
}

// Round 5
// 463.328 us; speedup vs baseline: 1.7046x; 1.0029x over previous
//
#include <hip/hip_runtime.h>

using bf16   = __bf16;
using bf16x4 = __attribute__((ext_vector_type(4))) __bf16;
using bf16x8 = __attribute__((ext_vector_type(8))) __bf16;
using f32x4  = __attribute__((ext_vector_type(4))) float;
using u32x4  = __attribute__((ext_vector_type(4))) unsigned int;

#define MFMA16(a,b,c) __builtin_amdgcn_mfma_f32_16x16x32_bf16((a),(b),(c),0,0,0)

__device__ inline void glds16(const void* g, void* l) {
    __builtin_amdgcn_global_load_lds(
        (__attribute__((address_space(1))) void*)(const_cast<void*>(g)),
        (__attribute__((address_space(3))) void*)(l), 16, 0, 0);
}

// ---------------- constants (problem-instance fixed) ----------------
constexpr int CB   = 8;
constexpr int NH   = 12;
constexpr int CC   = 768;
constexpr int HD   = 64;
constexpr int TT   = 8, HH = 28, WW = 28;
constexpr int NTOK = TT*HH*WW + 1;      // 6273
constexpr int MX   = CB*NTOK;           // 50184
constexpr int MXP  = 50304;             // padded M rows in xb/tmp
constexpr int NQ   = 1569, NQP = 1600;
constexpr int NK   = 393,  NKP = 416;
constexpr int MO   = CB*NQ;             // 12552
constexpr int MOP  = 12672;

// ---------------- f32 -> bf16 cast (with zero tail pad) ----------------
__global__ __launch_bounds__(256) void cast_f32_bf16(const float* __restrict__ src,
                                                     bf16* __restrict__ dst,
                                                     int nvalid, int ntotal) {
    int i = (blockIdx.x * 256 + threadIdx.x) * 4;
    int stride = gridDim.x * 256 * 4;
    for (; i < ntotal; i += stride) {
        bf16x4 o;
        if (i + 3 < nvalid) {
            f32x4 v = *(const f32x4*)(src + i);
            #pragma unroll
            for (int e = 0; e < 4; ++e) o[e] = (bf16)v[e];
        } else {
            #pragma unroll
            for (int e = 0; e < 4; ++e) {
                int k = i + e;
                o[e] = (bf16)((k < nvalid) ? src[k] : 0.f);
            }
        }
        *(bf16x4*)(dst + i) = o;
    }
}

// ---------------- weight transpose: (64,27) -> [27][64], 3 sets ----------------
__global__ __launch_bounds__(256) void transpose_w3(const float* __restrict__ w0,
                                                    const float* __restrict__ w1,
                                                    const float* __restrict__ w2,
                                                    float* __restrict__ wt) {
    int i = blockIdx.x * 256 + threadIdx.x;
    if (i >= 3 * 1728) return;
    int setn = i / 1728, j = i % 1728;
    const float* src = (setn == 0) ? w0 : (setn == 1) ? w1 : w2;
    int tap = j / 64, c = j % 64;
    wt[i] = src[c * 27 + tap];
}

// ---------------- score-bound kernel: M = 0.125 * Bq * Bk ----------------
__global__ void bound_kernel(const float* __restrict__ gq, const float* __restrict__ bq,
                             const float* __restrict__ gk, const float* __restrict__ bk,
                             float* __restrict__ out) {
    const int c = threadIdx.x;   // 64 threads
    float mgq = fabsf(gq[c]), sbq = bq[c] * bq[c];
    float mgk = fabsf(gk[c]), sbk = bk[c] * bk[c];
    #pragma unroll
    for (int m = 1; m < 64; m <<= 1) {
        mgq = fmaxf(mgq, __shfl_xor(mgq, m)); sbq += __shfl_xor(sbq, m);
        mgk = fmaxf(mgk, __shfl_xor(mgk, m)); sbk += __shfl_xor(sbk, m);
    }
    if (c == 0) {
        const float Bq = 8.f * mgq + sqrtf(sbq);
        const float Bk = 8.f * mgk + sqrtf(sbk);
        out[0] = 0.125f * Bq * Bk;
    }
}

// ---------------- 256x128 bf16 GEMM, 3-deep pipelined (BK=64) ----------------
// A: [*][768] bf16 row-major.  Bw: [Ncols][768] bf16 (W[out][in], B^T layout).
// C = A @ Bw^T.  K = 768 (12 K-tiles of 64).
// 512 thr = 8 waves (4M x 2N); per-wave out 64x64; acc 4x4 f32x4.
// LDS: 3 buffers x (A 256x64 | B 128x64) bf16 = 3 x 49152 = 147456 B.
// 3-deep: tile T+2 staged at tile-T top into a buffer disjoint from T's -> all
// 6 global_load_lds issue early (2-tile latency lead), vmcnt(6) once per tile.
template<bool FINAL>
__global__ __launch_bounds__(512, 2) void gemmK(const bf16* __restrict__ A,
                                                const bf16* __restrict__ Bw,
                                                void* __restrict__ Cptr,
                                                const float* __restrict__ bias,
                                                int nbn, int Mvalid, int Aclamp) {
    extern __shared__ char lds[];
    // T1: bijective XCD-chunked remap (m204)
    const int nwg = gridDim.x;
    const int xcd = blockIdx.x & 7, loc = blockIdx.x >> 3;
    const int q8 = nwg >> 3, r8 = nwg & 7;
    const int wgid = (xcd < r8 ? xcd * (q8 + 1) : r8 * (q8 + 1) + (xcd - r8) * q8) + loc;
    const int bm = wgid / nbn, bn = wgid % nbn;

    const int tid = threadIdx.x, lane = tid & 63, w = tid >> 6;
    const int li = lane & 15, lg = lane >> 4;
    const int wr = w >> 1, wc = w & 1;

    // staging source swizzle (inverse of read-side st-swizzle; LDS dest linear)
    const int lr  = lane >> 3;
    const int lsw = ((lane & 7) ^ lr) << 3;
    const bf16* Agp = A  + (size_t)bm * 256 * 768;
    const bf16* Bgp = Bw + (size_t)bn * 128 * 768;
    const int clampA = Aclamp - bm * 256;

    // read-side swizzled column bytes for k-slice 0/1 (rows == li mod 8)
    const int sw_  = (li & 7) << 4;
    const int swc0 = (lg * 16) ^ sw_;
    const int swc1 = (64 | (lg * 16)) ^ sw_;

#define STAGE_T(Tt, buf) do {                                                        \
        char* d_ = lds + (buf) * 49152;                                              \
        _Pragma("unroll")                                                            \
        for (int h_ = 0; h_ < 4; ++h_) {                                             \
            const int r0_ = h_ * 64 + w * 8;                                         \
            int gr_ = r0_ + lr; if (gr_ >= clampA) gr_ = clampA - 1;                 \
            glds16(Agp + (size_t)gr_ * 768 + (Tt) * 64 + lsw, d_ + r0_ * 128);       \
        }                                                                            \
        _Pragma("unroll")                                                            \
        for (int h_ = 0; h_ < 2; ++h_) {                                             \
            const int r0_ = h_ * 64 + w * 8;                                         \
            glds16(Bgp + (size_t)(r0_ + lr) * 768 + (Tt) * 64 + lsw,                 \
                   d_ + 32768 + r0_ * 128);                                          \
        } } while (0)

    f32x4 acc[4][4] = {};
    bf16x8 aF[4][2], bFa[2][2], bFb[2][2];

#define READ_A()                                                                     \
    _Pragma("unroll") for (int mf = 0; mf < 4; ++mf) {                               \
        const char* p_ = bufA + (size_t)(wr * 64 + mf * 16 + li) * 128;              \
        aF[mf][0] = *(const bf16x8*)(p_ + swc0);                                     \
        aF[mf][1] = *(const bf16x8*)(p_ + swc1); }
#define READ_B(ph, BF)                                                               \
    _Pragma("unroll") for (int nf = 0; nf < 2; ++nf) {                               \
        const char* p_ = bufB + (size_t)(wc * 64 + (ph) * 32 + nf * 16 + li) * 128;  \
        BF[nf][0] = *(const bf16x8*)(p_ + swc0);                                     \
        BF[nf][1] = *(const bf16x8*)(p_ + swc1); }
#define MFMA_PH(ph, BF)                                                              \
    _Pragma("unroll") for (int mf = 0; mf < 4; ++mf)                                 \
    _Pragma("unroll") for (int nf = 0; nf < 2; ++nf) {                               \
        acc[mf][(ph)*2+nf] = MFMA16(aF[mf][0], BF[nf][0], acc[mf][(ph)*2+nf]);       \
        acc[mf][(ph)*2+nf] = MFMA16(aF[mf][1], BF[nf][1], acc[mf][(ph)*2+nf]); }

    // prologue: stage tiles 0,1; wait tile 0 (6 of 12 outstanding), publish
    STAGE_T(0, 0);
    STAGE_T(1, 1);
    asm volatile("s_waitcnt vmcnt(6)" ::: "memory");
    __builtin_amdgcn_s_barrier();

    #pragma unroll
    for (int T = 0; T < 12; ++T) {
        const int bt = T % 3;                 // compile-time (full unroll)
        const int bs = (T + 2) % 3;
        const char* bufA = lds + bt * 49152;
        const char* bufB = bufA + 32768;
        if (T < 10) STAGE_T(T + 2, bs);       // issue-early: 2-tile latency lead
        // ---- phase 0: (all m, n-half 0)
        READ_A(); READ_B(0, bFa);
        __builtin_amdgcn_s_barrier();
        asm volatile("s_waitcnt lgkmcnt(0)" ::: "memory");
        __builtin_amdgcn_sched_barrier(0);
        __builtin_amdgcn_s_setprio(1);
        MFMA_PH(0, bFa);
        __builtin_amdgcn_s_setprio(0);
        __builtin_amdgcn_s_barrier();
        // ---- phase 1: (all m, n-half 1)
        READ_B(1, bFb);
        __builtin_amdgcn_s_barrier();
        asm volatile("s_waitcnt lgkmcnt(0)" ::: "memory");
        __builtin_amdgcn_sched_barrier(0);
        __builtin_amdgcn_s_setprio(1);
        MFMA_PH(1, bFb);
        __builtin_amdgcn_s_setprio(0);
        if (T < 10)       asm volatile("s_waitcnt vmcnt(6)" ::: "memory");
        else if (T == 10) asm volatile("s_waitcnt vmcnt(0)" ::: "memory");
        __builtin_amdgcn_s_barrier();         // publish buf[T+1]
    }
#undef STAGE_T
#undef READ_A
#undef READ_B
#undef MFMA_PH

    // epilogue
    #pragma unroll
    for (int mf = 0; mf < 4; ++mf) {
        const int row0 = bm * 256 + wr * 64 + mf * 16 + lg * 4;
        #pragma unroll
        for (int nf = 0; nf < 4; ++nf) {
            const int col = bn * 128 + wc * 64 + nf * 16 + li;
            #pragma unroll
            for (int r = 0; r < 4; ++r) {
                const int row = row0 + r;
                if (row < Mvalid) {
                    if constexpr (FINAL)
                        ((float*)Cptr)[(size_t)row * 768 + col] = acc[mf][nf][r] + bias[col];
                    else
                        ((bf16*)Cptr)[(size_t)row * 768 + col] = (bf16)acc[mf][nf][r];
                }
            }
        }
    }
}

// ---------------- depthwise 3x3x3 pool + LayerNorm(hd), vectorized ----------------
template<int S, int OH, int OW, int CH, int NP, int NPpad>
__global__ __launch_bounds__(256) void pool_norm2(const bf16* __restrict__ P,
                                                  const float* __restrict__ wt,
                                                  const float* __restrict__ gamma,
                                                  const float* __restrict__ beta,
                                                  bf16* __restrict__ outp,
                                                  float outScale) {
    constexpr int TASKS = TT * OH * CH + 1;
    const int w = threadIdx.x >> 6, lane = threadIdx.x & 63;
    const int gw = blockIdx.x * 4 + w;
    const int bh = gw / TASKS, task = gw % TASKS;
    const int b = bh / NH, head = bh % NH;
    const int owg = lane >> 3, cg = lane & 7, c = cg * 8;
    const size_t pbase = (size_t)b * NTOK * CC + head * HD + c;

    if (task == TASKS - 1) {
        if (owg == 0) {
            bf16x8 v = *(const bf16x8*)(P + pbase);
            float a[8];
            #pragma unroll
            for (int e = 0; e < 8; ++e) a[e] = (float)v[e];
            float s = 0;
            #pragma unroll
            for (int e = 0; e < 8; ++e) s += a[e];
            s += __shfl_xor(s, 1); s += __shfl_xor(s, 2); s += __shfl_xor(s, 4);
            const float mu = s * 0.015625f;
            float v2 = 0;
            #pragma unroll
            for (int e = 0; e < 8; ++e) { float d = a[e] - mu; v2 += d * d; }
            v2 += __shfl_xor(v2, 1); v2 += __shfl_xor(v2, 2); v2 += __shfl_xor(v2, 4);
            const float rs = rsqrtf(v2 * 0.015625f + 1e-5f);
            f32x4 g0 = *(const f32x4*)(gamma + c), g1 = *(const f32x4*)(gamma + c + 4);
            f32x4 b0 = *(const f32x4*)(beta + c),  b1 = *(const f32x4*)(beta + c + 4);
            bf16x8 o;
            #pragma unroll
            for (int e = 0; e < 4; ++e) {
                o[e]     = (bf16)(((a[e]     - mu) * rs * g0[e] + b0[e]) * outScale);
                o[4 + e] = (bf16)(((a[4 + e] - mu) * rs * g1[e] + b1[e]) * outScale);
            }
            *(bf16x8*)(outp + ((size_t)bh * NPpad) * HD + c) = o;
        } else {
            bf16x8 z = {};
            for (int p = NP + owg - 1; p < NPpad; p += 7)
                *(bf16x8*)(outp + ((size_t)bh * NPpad + p) * HD + c) = z;
        }
        return;
    }

    const int t  = task / (OH * CH);
    const int r2 = task % (OH * CH);
    const int oh = r2 / CH;
    const int ow = (r2 % CH) * 8 + owg;
    const bool active = (ow < OW);

    float acc[8] = {0, 0, 0, 0, 0, 0, 0, 0};
    #pragma unroll
    for (int dt = 0; dt < 3; ++dt) {
        const int it = t + dt - 1;
        if (it < 0 || it >= TT) continue;
        #pragma unroll
        for (int dh = 0; dh < 3; ++dh) {
            const int ih = oh * S + dh - 1;
            if (ih < 0 || ih >= HH) continue;
            const int tokrow = 1 + (it * HH + ih) * WW;
            #pragma unroll
            for (int dw = 0; dw < 3; ++dw) {
                const int iw = ow * S + dw - 1;
                if (active && iw >= 0) {
                    bf16x8 v = *(const bf16x8*)(P + pbase + (size_t)(tokrow + iw) * CC);
                    const float* wp = wt + ((dt * 3 + dh) * 3 + dw) * 64 + c;
                    f32x4 w0 = *(const f32x4*)wp, w1 = *(const f32x4*)(wp + 4);
                    #pragma unroll
                    for (int e = 0; e < 4; ++e) {
                        acc[e]     += w0[e] * (float)v[e];
                        acc[4 + e] += w1[e] * (float)v[4 + e];
                    }
                }
            }
        }
    }
    float s = 0;
    #pragma unroll
    for (int e = 0; e < 8; ++e) s += acc[e];
    s += __shfl_xor(s, 1); s += __shfl_xor(s, 2); s += __shfl_xor(s, 4);
    const float mu = s * 0.015625f;
    float v2 = 0;
    #pragma unroll
    for (int e = 0; e < 8; ++e) { float d = acc[e] - mu; v2 += d * d; }
    v2 += __shfl_xor(v2, 1); v2 += __shfl_xor(v2, 2); v2 += __shfl_xor(v2, 4);
    const float rs = rsqrtf(v2 * 0.015625f + 1e-5f);
    if (active) {
        f32x4 g0 = *(const f32x4*)(gamma + c), g1 = *(const f32x4*)(gamma + c + 4);
        f32x4 b0 = *(const f32x4*)(beta + c),  b1 = *(const f32x4*)(beta + c + 4);
        bf16x8 o;
        #pragma unroll
        for (int e = 0; e < 4; ++e) {
            o[e]     = (bf16)(((acc[e]     - mu) * rs * g0[e] + b0[e]) * outScale);
            o[4 + e] = (bf16)(((acc[4 + e] - mu) * rs * g1[e] + b1[e]) * outScale);
        }
        const int p = 1 + (t * OH + oh) * OW + ow;
        *(bf16x8*)(outp + ((size_t)bh * NPpad + p) * HD + c) = o;
    }
}

// ---------------- flash attention, fixed-max softmax ----------------
__global__ __launch_bounds__(256) void attn_kernel(const bf16* __restrict__ qn,
                                                   const bf16* __restrict__ kn,
                                                   const bf16* __restrict__ vn,
                                                   bf16* __restrict__ ob,
                                                   const float* __restrict__ Mptr) {
    __shared__ bf16 Kl[2][32][72];
    __shared__ bf16 Vt[2][64][40];
    __shared__ bf16 Pl[4][16][40];

    const int tid = threadIdx.x, l = tid & 63, w = tid >> 6;
    const int li = l & 15, lg = l >> 4;
    const int bh = blockIdx.y;
    const int b = bh / NH, head = bh % NH;
    const int qbase = blockIdx.x * 64 + w * 16;
    const float M = Mptr[0];

    const bf16* qp = qn + ((size_t)bh * NQP + qbase + li) * HD + lg * 8;
    const bf16x8 aq0 = *(const bf16x8*)qp;
    const bf16x8 aq1 = *(const bf16x8*)(qp + 32);

    const int srow = tid >> 3, scol = (tid & 7) * 8;
    const int sj = tid & 31, sd8 = tid >> 5;
    const bf16* kbase = kn + (size_t)bh * NKP * HD;
    const bf16* vbase = vn + (size_t)bh * NKP * HD;

    u32x4 kv = *(const u32x4*)(kbase + srow * HD + scol);
    u32x4 vv = *(const u32x4*)(vbase + sj * HD + sd8 * 8);
    *(u32x4*)&Kl[0][srow][scol] = kv;
    {
        bf16x8 t = __builtin_bit_cast(bf16x8, vv);
        #pragma unroll
        for (int e = 0; e < 8; ++e) Vt[0][sd8 * 8 + e][sj] = t[e];
    }

    f32x4 oacc[4] = {};
    float lpart[4] = {0.f, 0.f, 0.f, 0.f};

    for (int kt = 0; kt < 13; ++kt) {
        const int cur = kt & 1;
        if (kt < 12) {
            kv = *(const u32x4*)(kbase + (kt + 1) * 32 * HD + srow * HD + scol);
            vv = *(const u32x4*)(vbase + (kt + 1) * 32 * HD + sj * HD + sd8 * 8);
        }
        __syncthreads();

        f32x4 c0 = {}, c1 = {};
        const bf16x8 b00 = *(const bf16x8*)&Kl[cur][li][lg * 8];
        const bf16x8 b01 = *(const bf16x8*)&Kl[cur][li][32 + lg * 8];
        const bf16x8 b10 = *(const bf16x8*)&Kl[cur][16 + li][lg * 8];
        const bf16x8 b11 = *(const bf16x8*)&Kl[cur][16 + li][32 + lg * 8];
        __builtin_amdgcn_s_setprio(1);
        c0 = MFMA16(aq0, b00, c0); c0 = MFMA16(aq1, b01, c0);
        c1 = MFMA16(aq0, b10, c1); c1 = MFMA16(aq1, b11, c1);
        __builtin_amdgcn_s_setprio(0);

        float p0[4], p1[4];
        #pragma unroll
        for (int r = 0; r < 4; ++r) {
            p0[r] = __expf(c0[r] - M);
            p1[r] = __expf(c1[r] - M);
        }
        if (kt == 12) {
            const bool m0 = (384 + li) >= NK;
            #pragma unroll
            for (int r = 0; r < 4; ++r) { if (m0) p0[r] = 0.f; p1[r] = 0.f; }
        }
        #pragma unroll
        for (int r = 0; r < 4; ++r) {
            lpart[r] += p0[r] + p1[r];
            Pl[w][lg * 4 + r][li]      = (bf16)p0[r];
            Pl[w][lg * 4 + r][16 + li] = (bf16)p1[r];
        }
        const bf16x8 ap = *(const bf16x8*)&Pl[w][li][lg * 8];
        __builtin_amdgcn_s_setprio(1);
        #pragma unroll
        for (int dg = 0; dg < 4; ++dg) {
            const bf16x8 bv = *(const bf16x8*)&Vt[cur][dg * 16 + li][lg * 8];
            oacc[dg] = MFMA16(ap, bv, oacc[dg]);
        }
        __builtin_amdgcn_s_setprio(0);

        if (kt < 12) {
            const int nxt = cur ^ 1;
            *(u32x4*)&Kl[nxt][srow][scol] = kv;
            bf16x8 t = __builtin_bit_cast(bf16x8, vv);
            #pragma unroll
            for (int e = 0; e < 8; ++e) Vt[nxt][sd8 * 8 + e][sj] = t[e];
        }
    }
    #pragma unroll
    for (int r = 0; r < 4; ++r) {
        float lsum = lpart[r];
        lsum += __shfl_xor(lsum, 1);
        lsum += __shfl_xor(lsum, 2);
        lsum += __shfl_xor(lsum, 4);
        lsum += __shfl_xor(lsum, 8);
        const int q = qbase + lg * 4 + r;
        if (q < NQ) {
            const float inv = 1.f / lsum;
            const size_t off = ((size_t)(b * NQ + q)) * CC + head * HD;
            #pragma unroll
            for (int dg = 0; dg < 4; ++dg)
                ob[off + dg * 16 + li] = (bf16)(oacc[dg][r] * inv);
        }
    }
}

// ---------------- launcher ----------------
extern "C" void kernel_launch(void* const* d_in, const int* in_sizes, int n_in,
                              void* d_out, int out_size, void* d_ws, size_t ws_size,
                              hipStream_t stream) {
    const float* x     = (const float*)d_in[0];
    const float* Wq    = (const float*)d_in[1];
    const float* Wk    = (const float*)d_in[2];
    const float* Wv    = (const float*)d_in[3];
    const float* Wproj = (const float*)d_in[4];
    const float* bproj = (const float*)d_in[5];
    const float* pqw   = (const float*)d_in[6];
    const float* pkw   = (const float*)d_in[7];
    const float* pvw   = (const float*)d_in[8];
    const float* gq    = (const float*)d_in[9];
    const float* bq    = (const float*)d_in[10];
    const float* gk    = (const float*)d_in[11];
    const float* bk    = (const float*)d_in[12];
    const float* gv    = (const float*)d_in[13];
    const float* bv    = (const float*)d_in[14];

    if (ws_size < 208601088ULL) return;
    char* ws = (char*)d_ws;
    bf16* xb   = (bf16*)(ws);               // [50304][768]
    bf16* wqkv = (bf16*)(ws + 77266944);    // [2304][768]
    bf16* wpb  = (bf16*)(ws + 80805888);    // [768][768]
    bf16* tmp  = (bf16*)(ws + 81985536);    // [50304][768]
    bf16* qn   = (bf16*)(ws + 159252480);   // [96][1600][64]
    bf16* kn   = (bf16*)(ws + 178913280);   // [96][416][64]
    bf16* vnb  = (bf16*)(ws + 184025088);   // [96][416][64]
    bf16* ob   = (bf16*)(ws + 189136896);   // [12672][768]
    float* wt  = (float*)(ws + 189136896);  // [3][27][64] f32 (overlay, dead before attn)
    float* Mb  = (float*)(ws + 81985536);   // overlays tmp[0]: written after pool_v

    const int WSZ = 589824;  // 768*768

    (void)hipFuncSetAttribute((const void*)gemmK<false>,
                              hipFuncAttributeMaxDynamicSharedMemorySize, 147456);
    (void)hipFuncSetAttribute((const void*)gemmK<true>,
                              hipFuncAttributeMaxDynamicSharedMemorySize, 147456);

    transpose_w3<<<21, 256, 0, stream>>>(pqw, pkw, pvw, wt);
    cast_f32_bf16<<<4096, 256, 0, stream>>>(x, xb, MX * CC, MXP * CC);
    cast_f32_bf16<<<576, 256, 0, stream>>>(Wq, wqkv,            WSZ, WSZ);
    cast_f32_bf16<<<576, 256, 0, stream>>>(Wk, wqkv + WSZ,      WSZ, WSZ);
    cast_f32_bf16<<<576, 256, 0, stream>>>(Wv, wqkv + 2 * WSZ,  WSZ, WSZ);
    cast_f32_bf16<<<576, 256, 0, stream>>>(Wproj, wpb,          WSZ, WSZ);

    // Q: proj + pool(stride 1,2,2) + LN  (scale 0.125 baked in)
    gemmK<false><<<197 * 6, 512, 147456, stream>>>(xb, wqkv, tmp, nullptr, 6, MXP, MXP);
    pool_norm2<2, 14, 14, 2, NQ, NQP><<<5400, 256, 0, stream>>>(tmp, wt, gq, bq, qn, 0.125f);
    // K: proj + pool(stride 1,4,4) + LN
    gemmK<false><<<197 * 6, 512, 147456, stream>>>(xb, wqkv + WSZ, tmp, nullptr, 6, MXP, MXP);
    pool_norm2<4, 7, 7, 1, NK, NKP><<<1368, 256, 0, stream>>>(tmp, wt + 1728, gk, bk, kn, 1.0f);
    // V: proj + pool(stride 1,4,4) + LN
    gemmK<false><<<197 * 6, 512, 147456, stream>>>(xb, wqkv + 2 * WSZ, tmp, nullptr, 6, MXP, MXP);
    pool_norm2<4, 7, 7, 1, NK, NKP><<<1368, 256, 0, stream>>>(tmp, wt + 3456, gv, bv, vnb, 1.0f);

    // score bound (tmp dead after pool_v; stash M in its first 4 bytes)
    bound_kernel<<<1, 64, 0, stream>>>(gq, bq, gk, bk, Mb);

    attn_kernel<<<dim3(25, 96), 256, 0, stream>>>(qn, kn, vnb, ob, Mb);

    gemmK<true><<<50 * 6, 512, 147456, stream>>>(ob, wpb, d_out, bproj, 6, MO, MOP);
}

// Round 6
// 457.740 us; speedup vs baseline: 1.7254x; 1.0122x over previous
//
#include <hip/hip_runtime.h>

using bf16   = __bf16;
using bf16x4 = __attribute__((ext_vector_type(4))) __bf16;
using bf16x8 = __attribute__((ext_vector_type(8))) __bf16;
using f32x4  = __attribute__((ext_vector_type(4))) float;
using u32x4  = __attribute__((ext_vector_type(4))) unsigned int;

#define MFMA16(a,b,c) __builtin_amdgcn_mfma_f32_16x16x32_bf16((a),(b),(c),0,0,0)

__device__ inline void glds16(const void* g, void* l) {
    __builtin_amdgcn_global_load_lds(
        (__attribute__((address_space(1))) void*)(const_cast<void*>(g)),
        (__attribute__((address_space(3))) void*)(l), 16, 0, 0);
}

// ---------------- constants (problem-instance fixed) ----------------
constexpr int CB   = 8;
constexpr int NH   = 12;
constexpr int CC   = 768;
constexpr int HD   = 64;
constexpr int TT   = 8, HH = 28, WW = 28;
constexpr int NTOK = TT*HH*WW + 1;      // 6273
constexpr int MX   = CB*NTOK;           // 50184
constexpr int MXP  = 50304;             // padded M rows in xb/tmp3
constexpr int NQ   = 1569, NQP = 1600;
constexpr int NK   = 393,  NKP = 416;
constexpr int MO   = CB*NQ;             // 12552
constexpr int MOP  = 12672;

// ---------------- f32 -> bf16 cast (with zero tail pad) ----------------
__global__ __launch_bounds__(256) void cast_f32_bf16(const float* __restrict__ src,
                                                     bf16* __restrict__ dst,
                                                     int nvalid, int ntotal) {
    int i = (blockIdx.x * 256 + threadIdx.x) * 4;
    int stride = gridDim.x * 256 * 4;
    for (; i < ntotal; i += stride) {
        bf16x4 o;
        if (i + 3 < nvalid) {
            f32x4 v = *(const f32x4*)(src + i);
            #pragma unroll
            for (int e = 0; e < 4; ++e) o[e] = (bf16)v[e];
        } else {
            #pragma unroll
            for (int e = 0; e < 4; ++e) {
                int k = i + e;
                o[e] = (bf16)((k < nvalid) ? src[k] : 0.f);
            }
        }
        *(bf16x4*)(dst + i) = o;
    }
}

// ---------------- weight transpose: (64,27) -> [27][64], 3 sets ----------------
__global__ __launch_bounds__(256) void transpose_w3(const float* __restrict__ w0,
                                                    const float* __restrict__ w1,
                                                    const float* __restrict__ w2,
                                                    float* __restrict__ wt) {
    int i = blockIdx.x * 256 + threadIdx.x;
    if (i >= 3 * 1728) return;
    int setn = i / 1728, j = i % 1728;
    const float* src = (setn == 0) ? w0 : (setn == 1) ? w1 : w2;
    int tap = j / 64, c = j % 64;
    wt[i] = src[c * 27 + tap];
}

// ---------------- score-bound kernel: M = 0.125 * Bq * Bk ----------------
__global__ void bound_kernel(const float* __restrict__ gq, const float* __restrict__ bq,
                             const float* __restrict__ gk, const float* __restrict__ bk,
                             float* __restrict__ out) {
    const int c = threadIdx.x;   // 64 threads
    float mgq = fabsf(gq[c]), sbq = bq[c] * bq[c];
    float mgk = fabsf(gk[c]), sbk = bk[c] * bk[c];
    #pragma unroll
    for (int m = 1; m < 64; m <<= 1) {
        mgq = fmaxf(mgq, __shfl_xor(mgq, m)); sbq += __shfl_xor(sbq, m);
        mgk = fmaxf(mgk, __shfl_xor(mgk, m)); sbk += __shfl_xor(sbk, m);
    }
    if (c == 0) {
        const float Bq = 8.f * mgq + sqrtf(sbq);
        const float Bk = 8.f * mgk + sqrtf(sbk);
        out[0] = 0.125f * Bq * Bk;
    }
}

// ---------------- 256x128 bf16 GEMM, 3-deep, ONE barrier per K-tile ----------------
// A: [*][768] bf16 row-major.  Bw: [Ncols][768] bf16 (W[out][in], B^T layout).
// C = A @ Bw^T, C row stride = ldc.  K = 768 (12 K-tiles of 64).
// 512 thr = 8 waves (4M x 2N); per-wave out 64x64; acc 4x4 f32x4.
// LDS: 3 x (A 256x64 | B 128x64) bf16 = 147456 B. Tile T stages T+2 (disjoint
// buffer), so loads lead by 2 full tiles; vmcnt(6) counted wait once per tile;
// NO per-phase lgkm drains -- compiler interleaves ds_reads under MFMAs (m97
// behavior) and the single end-of-tile barrier publishes/protects buffers.
template<bool FINAL>
__global__ __launch_bounds__(512, 2) void gemmF(const bf16* __restrict__ A,
                                                const bf16* __restrict__ Bw,
                                                void* __restrict__ Cptr,
                                                const float* __restrict__ bias,
                                                int nbn, int Mvalid, int Aclamp, int ldc) {
    extern __shared__ char lds[];
    // T1: bijective XCD-chunked remap (m204)
    const int nwg = gridDim.x;
    const int xcd = blockIdx.x & 7, loc = blockIdx.x >> 3;
    const int q8 = nwg >> 3, r8 = nwg & 7;
    const int wgid = (xcd < r8 ? xcd * (q8 + 1) : r8 * (q8 + 1) + (xcd - r8) * q8) + loc;
    const int bm = wgid / nbn, bn = wgid % nbn;

    const int tid = threadIdx.x, lane = tid & 63, w = tid >> 6;
    const int li = lane & 15, lg = lane >> 4;
    const int wr = w >> 1, wc = w & 1;

    // staging source swizzle (inverse of read-side st-swizzle; LDS dest linear)
    const int lr  = lane >> 3;
    const int lsw = ((lane & 7) ^ lr) << 3;
    const bf16* Agp = A  + (size_t)bm * 256 * 768;
    const bf16* Bgp = Bw + (size_t)bn * 128 * 768;
    const int clampA = Aclamp - bm * 256;

    // read-side swizzled column bytes for k-slice 0/1 (row mod 8 == li mod 8)
    const int sw_  = (li & 7) << 4;
    const int swc0 = (lg * 16) ^ sw_;
    const int swc1 = (64 | (lg * 16)) ^ sw_;

#define STAGE_T(Tt, buf) do {                                                        \
        char* d_ = lds + (buf) * 49152;                                              \
        _Pragma("unroll")                                                            \
        for (int h_ = 0; h_ < 4; ++h_) {                                             \
            const int r0_ = h_ * 64 + w * 8;                                         \
            int gr_ = r0_ + lr; if (gr_ >= clampA) gr_ = clampA - 1;                 \
            glds16(Agp + (size_t)gr_ * 768 + (Tt) * 64 + lsw, d_ + r0_ * 128);       \
        }                                                                            \
        _Pragma("unroll")                                                            \
        for (int h_ = 0; h_ < 2; ++h_) {                                             \
            const int r0_ = h_ * 64 + w * 8;                                         \
            glds16(Bgp + (size_t)(r0_ + lr) * 768 + (Tt) * 64 + lsw,                 \
                   d_ + 32768 + r0_ * 128);                                          \
        } } while (0)

    f32x4 acc[4][4] = {};
    bf16x8 aF[4][2], bFa[2][2], bFb[2][2];

#define READ_ALL()                                                                   \
    _Pragma("unroll") for (int mf = 0; mf < 4; ++mf) {                               \
        const char* p_ = bufA + (size_t)(wr * 64 + mf * 16 + li) * 128;              \
        aF[mf][0] = *(const bf16x8*)(p_ + swc0);                                     \
        aF[mf][1] = *(const bf16x8*)(p_ + swc1); }                                   \
    _Pragma("unroll") for (int nf = 0; nf < 2; ++nf) {                               \
        const char* p_ = bufB + (size_t)(wc * 64 + nf * 16 + li) * 128;              \
        bFa[nf][0] = *(const bf16x8*)(p_ + swc0);                                    \
        bFa[nf][1] = *(const bf16x8*)(p_ + swc1); }                                  \
    _Pragma("unroll") for (int nf = 0; nf < 2; ++nf) {                               \
        const char* p_ = bufB + (size_t)(wc * 64 + 32 + nf * 16 + li) * 128;         \
        bFb[nf][0] = *(const bf16x8*)(p_ + swc0);                                    \
        bFb[nf][1] = *(const bf16x8*)(p_ + swc1); }

#define MFMA_ALL()                                                                   \
    _Pragma("unroll") for (int mf = 0; mf < 4; ++mf)                                 \
    _Pragma("unroll") for (int nf = 0; nf < 2; ++nf) {                               \
        acc[mf][nf] = MFMA16(aF[mf][0], bFa[nf][0], acc[mf][nf]);                    \
        acc[mf][nf] = MFMA16(aF[mf][1], bFa[nf][1], acc[mf][nf]);                    \
        acc[mf][2+nf] = MFMA16(aF[mf][0], bFb[nf][0], acc[mf][2+nf]);                \
        acc[mf][2+nf] = MFMA16(aF[mf][1], bFb[nf][1], acc[mf][2+nf]); }

    // prologue: stage tiles 0,1; wait tile 0 (6 of 12 outstanding), publish
    STAGE_T(0, 0);
    STAGE_T(1, 1);
    asm volatile("s_waitcnt vmcnt(6)" ::: "memory");
    __builtin_amdgcn_s_barrier();
    __builtin_amdgcn_sched_barrier(0);

    #pragma unroll
    for (int T = 0; T < 12; ++T) {
        const char* bufA = lds + (T % 3) * 49152;
        const char* bufB = bufA + 32768;
        if (T < 10) STAGE_T(T + 2, (T + 2) % 3);   // 2-tile latency lead
        READ_ALL();
        __builtin_amdgcn_s_setprio(1);
        MFMA_ALL();                                 // compiler-scheduled lgkm waits
        __builtin_amdgcn_s_setprio(0);
        asm volatile("s_waitcnt lgkmcnt(0)" ::: "memory");  // free: reads consumed
        if (T < 10)       asm volatile("s_waitcnt vmcnt(6)" ::: "memory");
        else if (T == 10) asm volatile("s_waitcnt vmcnt(0)" ::: "memory");
        __builtin_amdgcn_s_barrier();               // publish buf[T+1]; protect buf[(T+2)%3]
        __builtin_amdgcn_sched_barrier(0);
    }
#undef STAGE_T
#undef READ_ALL
#undef MFMA_ALL

    // epilogue
    #pragma unroll
    for (int mf = 0; mf < 4; ++mf) {
        const int row0 = bm * 256 + wr * 64 + mf * 16 + lg * 4;
        #pragma unroll
        for (int nf = 0; nf < 4; ++nf) {
            const int col = bn * 128 + wc * 64 + nf * 16 + li;
            #pragma unroll
            for (int r = 0; r < 4; ++r) {
                const int row = row0 + r;
                if (row < Mvalid) {
                    if constexpr (FINAL)
                        ((float*)Cptr)[(size_t)row * ldc + col] = acc[mf][nf][r] + bias[col];
                    else
                        ((bf16*)Cptr)[(size_t)row * ldc + col] = (bf16)acc[mf][nf][r];
                }
            }
        }
    }
}

// ---------------- depthwise 3x3x3 pool + LayerNorm(hd), vectorized ----------------
// SRCSTRIDE: row stride (elements) of P (fused QKV output = 2304).
template<int S, int OH, int OW, int CH, int NP, int NPpad, int SRCSTRIDE>
__global__ __launch_bounds__(256) void pool_norm2(const bf16* __restrict__ P,
                                                  const float* __restrict__ wt,
                                                  const float* __restrict__ gamma,
                                                  const float* __restrict__ beta,
                                                  bf16* __restrict__ outp,
                                                  float outScale) {
    constexpr int TASKS = TT * OH * CH + 1;
    const int w = threadIdx.x >> 6, lane = threadIdx.x & 63;
    const int gw = blockIdx.x * 4 + w;
    const int bh = gw / TASKS, task = gw % TASKS;
    const int b = bh / NH, head = bh % NH;
    const int owg = lane >> 3, cg = lane & 7, c = cg * 8;
    const size_t pbase = (size_t)b * NTOK * SRCSTRIDE + head * HD + c;

    if (task == TASKS - 1) {
        if (owg == 0) {
            bf16x8 v = *(const bf16x8*)(P + pbase);
            float a[8];
            #pragma unroll
            for (int e = 0; e < 8; ++e) a[e] = (float)v[e];
            float s = 0;
            #pragma unroll
            for (int e = 0; e < 8; ++e) s += a[e];
            s += __shfl_xor(s, 1); s += __shfl_xor(s, 2); s += __shfl_xor(s, 4);
            const float mu = s * 0.015625f;
            float v2 = 0;
            #pragma unroll
            for (int e = 0; e < 8; ++e) { float d = a[e] - mu; v2 += d * d; }
            v2 += __shfl_xor(v2, 1); v2 += __shfl_xor(v2, 2); v2 += __shfl_xor(v2, 4);
            const float rs = rsqrtf(v2 * 0.015625f + 1e-5f);
            f32x4 g0 = *(const f32x4*)(gamma + c), g1 = *(const f32x4*)(gamma + c + 4);
            f32x4 b0 = *(const f32x4*)(beta + c),  b1 = *(const f32x4*)(beta + c + 4);
            bf16x8 o;
            #pragma unroll
            for (int e = 0; e < 4; ++e) {
                o[e]     = (bf16)(((a[e]     - mu) * rs * g0[e] + b0[e]) * outScale);
                o[4 + e] = (bf16)(((a[4 + e] - mu) * rs * g1[e] + b1[e]) * outScale);
            }
            *(bf16x8*)(outp + ((size_t)bh * NPpad) * HD + c) = o;
        } else {
            bf16x8 z = {};
            for (int p = NP + owg - 1; p < NPpad; p += 7)
                *(bf16x8*)(outp + ((size_t)bh * NPpad + p) * HD + c) = z;
        }
        return;
    }

    const int t  = task / (OH * CH);
    const int r2 = task % (OH * CH);
    const int oh = r2 / CH;
    const int ow = (r2 % CH) * 8 + owg;
    const bool active = (ow < OW);

    float acc[8] = {0, 0, 0, 0, 0, 0, 0, 0};
    #pragma unroll
    for (int dt = 0; dt < 3; ++dt) {
        const int it = t + dt - 1;
        if (it < 0 || it >= TT) continue;
        #pragma unroll
        for (int dh = 0; dh < 3; ++dh) {
            const int ih = oh * S + dh - 1;
            if (ih < 0 || ih >= HH) continue;
            const int tokrow = 1 + (it * HH + ih) * WW;
            #pragma unroll
            for (int dw = 0; dw < 3; ++dw) {
                const int iw = ow * S + dw - 1;
                if (active && iw >= 0) {
                    bf16x8 v = *(const bf16x8*)(P + pbase + (size_t)(tokrow + iw) * SRCSTRIDE);
                    const float* wp = wt + ((dt * 3 + dh) * 3 + dw) * 64 + c;
                    f32x4 w0 = *(const f32x4*)wp, w1 = *(const f32x4*)(wp + 4);
                    #pragma unroll
                    for (int e = 0; e < 4; ++e) {
                        acc[e]     += w0[e] * (float)v[e];
                        acc[4 + e] += w1[e] * (float)v[4 + e];
                    }
                }
            }
        }
    }
    float s = 0;
    #pragma unroll
    for (int e = 0; e < 8; ++e) s += acc[e];
    s += __shfl_xor(s, 1); s += __shfl_xor(s, 2); s += __shfl_xor(s, 4);
    const float mu = s * 0.015625f;
    float v2 = 0;
    #pragma unroll
    for (int e = 0; e < 8; ++e) { float d = acc[e] - mu; v2 += d * d; }
    v2 += __shfl_xor(v2, 1); v2 += __shfl_xor(v2, 2); v2 += __shfl_xor(v2, 4);
    const float rs = rsqrtf(v2 * 0.015625f + 1e-5f);
    if (active) {
        f32x4 g0 = *(const f32x4*)(gamma + c), g1 = *(const f32x4*)(gamma + c + 4);
        f32x4 b0 = *(const f32x4*)(beta + c),  b1 = *(const f32x4*)(beta + c + 4);
        bf16x8 o;
        #pragma unroll
        for (int e = 0; e < 4; ++e) {
            o[e]     = (bf16)(((acc[e]     - mu) * rs * g0[e] + b0[e]) * outScale);
            o[4 + e] = (bf16)(((acc[4 + e] - mu) * rs * g1[e] + b1[e]) * outScale);
        }
        const int p = 1 + (t * OH + oh) * OW + ow;
        *(bf16x8*)(outp + ((size_t)bh * NPpad + p) * HD + c) = o;
    }
}

// ---------------- flash attention, fixed-max softmax ----------------
__global__ __launch_bounds__(256) void attn_kernel(const bf16* __restrict__ qn,
                                                   const bf16* __restrict__ kn,
                                                   const bf16* __restrict__ vn,
                                                   bf16* __restrict__ ob,
                                                   const float* __restrict__ Mptr) {
    __shared__ bf16 Kl[2][32][72];
    __shared__ bf16 Vt[2][64][40];
    __shared__ bf16 Pl[4][16][40];

    const int tid = threadIdx.x, l = tid & 63, w = tid >> 6;
    const int li = l & 15, lg = l >> 4;
    const int bh = blockIdx.y;
    const int b = bh / NH, head = bh % NH;
    const int qbase = blockIdx.x * 64 + w * 16;
    const float M = Mptr[0];

    const bf16* qp = qn + ((size_t)bh * NQP + qbase + li) * HD + lg * 8;
    const bf16x8 aq0 = *(const bf16x8*)qp;
    const bf16x8 aq1 = *(const bf16x8*)(qp + 32);

    const int srow = tid >> 3, scol = (tid & 7) * 8;
    const int sj = tid & 31, sd8 = tid >> 5;
    const bf16* kbase = kn + (size_t)bh * NKP * HD;
    const bf16* vbase = vn + (size_t)bh * NKP * HD;

    u32x4 kv = *(const u32x4*)(kbase + srow * HD + scol);
    u32x4 vv = *(const u32x4*)(vbase + sj * HD + sd8 * 8);
    *(u32x4*)&Kl[0][srow][scol] = kv;
    {
        bf16x8 t = __builtin_bit_cast(bf16x8, vv);
        #pragma unroll
        for (int e = 0; e < 8; ++e) Vt[0][sd8 * 8 + e][sj] = t[e];
    }

    f32x4 oacc[4] = {};
    float lpart[4] = {0.f, 0.f, 0.f, 0.f};

    for (int kt = 0; kt < 13; ++kt) {
        const int cur = kt & 1;
        if (kt < 12) {
            kv = *(const u32x4*)(kbase + (kt + 1) * 32 * HD + srow * HD + scol);
            vv = *(const u32x4*)(vbase + (kt + 1) * 32 * HD + sj * HD + sd8 * 8);
        }
        __syncthreads();

        f32x4 c0 = {}, c1 = {};
        const bf16x8 b00 = *(const bf16x8*)&Kl[cur][li][lg * 8];
        const bf16x8 b01 = *(const bf16x8*)&Kl[cur][li][32 + lg * 8];
        const bf16x8 b10 = *(const bf16x8*)&Kl[cur][16 + li][lg * 8];
        const bf16x8 b11 = *(const bf16x8*)&Kl[cur][16 + li][32 + lg * 8];
        __builtin_amdgcn_s_setprio(1);
        c0 = MFMA16(aq0, b00, c0); c0 = MFMA16(aq1, b01, c0);
        c1 = MFMA16(aq0, b10, c1); c1 = MFMA16(aq1, b11, c1);
        __builtin_amdgcn_s_setprio(0);

        float p0[4], p1[4];
        #pragma unroll
        for (int r = 0; r < 4; ++r) {
            p0[r] = __expf(c0[r] - M);
            p1[r] = __expf(c1[r] - M);
        }
        if (kt == 12) {
            const bool m0 = (384 + li) >= NK;
            #pragma unroll
            for (int r = 0; r < 4; ++r) { if (m0) p0[r] = 0.f; p1[r] = 0.f; }
        }
        #pragma unroll
        for (int r = 0; r < 4; ++r) {
            lpart[r] += p0[r] + p1[r];
            Pl[w][lg * 4 + r][li]      = (bf16)p0[r];
            Pl[w][lg * 4 + r][16 + li] = (bf16)p1[r];
        }
        const bf16x8 ap = *(const bf16x8*)&Pl[w][li][lg * 8];
        __builtin_amdgcn_s_setprio(1);
        #pragma unroll
        for (int dg = 0; dg < 4; ++dg) {
            const bf16x8 bv = *(const bf16x8*)&Vt[cur][dg * 16 + li][lg * 8];
            oacc[dg] = MFMA16(ap, bv, oacc[dg]);
        }
        __builtin_amdgcn_s_setprio(0);

        if (kt < 12) {
            const int nxt = cur ^ 1;
            *(u32x4*)&Kl[nxt][srow][scol] = kv;
            bf16x8 t = __builtin_bit_cast(bf16x8, vv);
            #pragma unroll
            for (int e = 0; e < 8; ++e) Vt[nxt][sd8 * 8 + e][sj] = t[e];
        }
    }
    #pragma unroll
    for (int r = 0; r < 4; ++r) {
        float lsum = lpart[r];
        lsum += __shfl_xor(lsum, 1);
        lsum += __shfl_xor(lsum, 2);
        lsum += __shfl_xor(lsum, 4);
        lsum += __shfl_xor(lsum, 8);
        const int q = qbase + lg * 4 + r;
        if (q < NQ) {
            const float inv = 1.f / lsum;
            const size_t off = ((size_t)(b * NQ + q)) * CC + head * HD;
            #pragma unroll
            for (int dg = 0; dg < 4; ++dg)
                ob[off + dg * 16 + li] = (bf16)(oacc[dg][r] * inv);
        }
    }
}

// ---------------- launcher ----------------
extern "C" void kernel_launch(void* const* d_in, const int* in_sizes, int n_in,
                              void* d_out, int out_size, void* d_ws, size_t ws_size,
                              hipStream_t stream) {
    const float* x     = (const float*)d_in[0];
    const float* Wq    = (const float*)d_in[1];
    const float* Wk    = (const float*)d_in[2];
    const float* Wv    = (const float*)d_in[3];
    const float* Wproj = (const float*)d_in[4];
    const float* bproj = (const float*)d_in[5];
    const float* pqw   = (const float*)d_in[6];
    const float* pkw   = (const float*)d_in[7];
    const float* pvw   = (const float*)d_in[8];
    const float* gq    = (const float*)d_in[9];
    const float* bq    = (const float*)d_in[10];
    const float* gk    = (const float*)d_in[11];
    const float* bk    = (const float*)d_in[12];
    const float* gv    = (const float*)d_in[13];
    const float* bv    = (const float*)d_in[14];

    // ws layout (observed ws_size ~578 MB; we need ~364 MB)
    if (ws_size < 364000000ULL) return;
    char* ws = (char*)d_ws;
    bf16* xb   = (bf16*)(ws);               // [50304][768]   77,266,944
    bf16* wqkv = (bf16*)(ws + 77266944);    // [2304][768]     3,538,944
    bf16* wpb  = (bf16*)(ws + 80805888);    // [768][768]      1,179,648
    bf16* tmp3 = (bf16*)(ws + 81985536);    // [50304][2304] 231,800,832
    bf16* qn   = (bf16*)(ws + 313786368);   // [96][1600][64] 19,660,800
    bf16* kn   = (bf16*)(ws + 333447168);   // [96][416][64]   5,111,808
    bf16* vnb  = (bf16*)(ws + 338558976);   // [96][416][64]   5,111,808
    bf16* ob   = (bf16*)(ws + 343670784);   // [12672][768]   19,464,192
    float* wt  = (float*)(ws + 363134976);  // [3][27][64] f32    20,736
    float* Mb  = (float*)(ws + 363155712);  // [1]

    const int WSZ = 589824;  // 768*768

    (void)hipFuncSetAttribute((const void*)gemmF<false>,
                              hipFuncAttributeMaxDynamicSharedMemorySize, 147456);
    (void)hipFuncSetAttribute((const void*)gemmF<true>,
                              hipFuncAttributeMaxDynamicSharedMemorySize, 147456);

    transpose_w3<<<21, 256, 0, stream>>>(pqw, pkw, pvw, wt);
    bound_kernel<<<1, 64, 0, stream>>>(gq, bq, gk, bk, Mb);
    cast_f32_bf16<<<4096, 256, 0, stream>>>(x, xb, MX * CC, MXP * CC);
    cast_f32_bf16<<<576, 256, 0, stream>>>(Wq, wqkv,            WSZ, WSZ);
    cast_f32_bf16<<<576, 256, 0, stream>>>(Wk, wqkv + WSZ,      WSZ, WSZ);
    cast_f32_bf16<<<576, 256, 0, stream>>>(Wv, wqkv + 2 * WSZ,  WSZ, WSZ);
    cast_f32_bf16<<<576, 256, 0, stream>>>(Wproj, wpb,          WSZ, WSZ);

    // fused QKV projection: [50304][768] @ [2304][768]^T -> [50304][2304]
    gemmF<false><<<197 * 18, 512, 147456, stream>>>(xb, wqkv, tmp3, nullptr, 18, MXP, MXP, 2304);

    // pools read fused output at column offsets 0/768/1536 (stride 2304)
    pool_norm2<2, 14, 14, 2, NQ, NQP, 2304><<<5400, 256, 0, stream>>>(tmp3,        wt,        gq, bq, qn,  0.125f);
    pool_norm2<4, 7, 7, 1, NK, NKP, 2304><<<1368, 256, 0, stream>>>(tmp3 + 768,  wt + 1728, gk, bk, kn,  1.0f);
    pool_norm2<4, 7, 7, 1, NK, NKP, 2304><<<1368, 256, 0, stream>>>(tmp3 + 1536, wt + 3456, gv, bv, vnb, 1.0f);

    attn_kernel<<<dim3(25, 96), 256, 0, stream>>>(qn, kn, vnb, ob, Mb);

    gemmF<true><<<50 * 6, 512, 147456, stream>>>(ob, wpb, d_out, bproj, 6, MO, MOP, 768);
}

// Round 7
// 449.816 us; speedup vs baseline: 1.7558x; 1.0176x over previous
//
#include <hip/hip_runtime.h>

using bf16   = __bf16;
using bf16x4 = __attribute__((ext_vector_type(4))) __bf16;
using bf16x8 = __attribute__((ext_vector_type(8))) __bf16;
using f32x4  = __attribute__((ext_vector_type(4))) float;
using u32x4  = __attribute__((ext_vector_type(4))) unsigned int;

#define MFMA16(a,b,c) __builtin_amdgcn_mfma_f32_16x16x32_bf16((a),(b),(c),0,0,0)

__device__ inline void glds16(const void* g, void* l) {
    __builtin_amdgcn_global_load_lds(
        (__attribute__((address_space(1))) void*)(const_cast<void*>(g)),
        (__attribute__((address_space(3))) void*)(l), 16, 0, 0);
}

// ---------------- constants (problem-instance fixed) ----------------
constexpr int CB   = 8;
constexpr int NH   = 12;
constexpr int CC   = 768;
constexpr int HD   = 64;
constexpr int TT   = 8, HH = 28, WW = 28;
constexpr int NTOK = TT*HH*WW + 1;      // 6273
constexpr int MX   = CB*NTOK;           // 50184
constexpr int MXP  = 50304;             // padded M rows in xb/tmp3
constexpr int NQ   = 1569, NQP = 1600;
constexpr int NK   = 393,  NKP = 416;
constexpr int MO   = CB*NQ;             // 12552
constexpr int MOP  = 12672;

// ---------------- f32 -> bf16 cast (with zero tail pad) ----------------
__global__ __launch_bounds__(256) void cast_f32_bf16(const float* __restrict__ src,
                                                     bf16* __restrict__ dst,
                                                     int nvalid, int ntotal) {
    int i = (blockIdx.x * 256 + threadIdx.x) * 4;
    int stride = gridDim.x * 256 * 4;
    for (; i < ntotal; i += stride) {
        bf16x4 o;
        if (i + 3 < nvalid) {
            f32x4 v = *(const f32x4*)(src + i);
            #pragma unroll
            for (int e = 0; e < 4; ++e) o[e] = (bf16)v[e];
        } else {
            #pragma unroll
            for (int e = 0; e < 4; ++e) {
                int k = i + e;
                o[e] = (bf16)((k < nvalid) ? src[k] : 0.f);
            }
        }
        *(bf16x4*)(dst + i) = o;
    }
}

// ---------------- weight transpose: (64,27) -> [27][64], 3 sets ----------------
__global__ __launch_bounds__(256) void transpose_w3(const float* __restrict__ w0,
                                                    const float* __restrict__ w1,
                                                    const float* __restrict__ w2,
                                                    float* __restrict__ wt) {
    int i = blockIdx.x * 256 + threadIdx.x;
    if (i >= 3 * 1728) return;
    int setn = i / 1728, j = i % 1728;
    const float* src = (setn == 0) ? w0 : (setn == 1) ? w1 : w2;
    int tap = j / 64, c = j % 64;
    wt[i] = src[c * 27 + tap];
}

// ---------------- score-bound kernel: M = 0.125 * Bq * Bk ----------------
__global__ void bound_kernel(const float* __restrict__ gq, const float* __restrict__ bq,
                             const float* __restrict__ gk, const float* __restrict__ bk,
                             float* __restrict__ out) {
    const int c = threadIdx.x;   // 64 threads
    float mgq = fabsf(gq[c]), sbq = bq[c] * bq[c];
    float mgk = fabsf(gk[c]), sbk = bk[c] * bk[c];
    #pragma unroll
    for (int m = 1; m < 64; m <<= 1) {
        mgq = fmaxf(mgq, __shfl_xor(mgq, m)); sbq += __shfl_xor(sbq, m);
        mgk = fmaxf(mgk, __shfl_xor(mgk, m)); sbk += __shfl_xor(sbk, m);
    }
    if (c == 0) {
        const float Bq = 8.f * mgq + sqrtf(sbq);
        const float Bk = 8.f * mgk + sqrtf(sbk);
        out[0] = 0.125f * Bq * Bk;
    }
}

// ---------------- 256x128 bf16 GEMM, BK=32, 3-deep, 2 blocks/CU ----------------
// A: [*][768] bf16 row-major.  Bw: [Ncols][768] bf16 (W[out][in], B^T layout).
// C = A @ Bw^T, row stride ldc.  K = 768 (24 K-tiles of 32).
// 512 thr = 8 waves (4M x 2N); wave tile 64x64; acc 4x4 f32x4 (64 VGPR).
// LDS: 3 x (A 256x32 | B 128x32) bf16 = 73728 B -> 2 blocks/CU (TLP hides stalls).
// Tile T stages T+2 (disjoint buffer): 2-tile latency lead, counted vmcnt(3).
// Swizzle: slot ^= (row&3) within each 64B row (optimal 8-cyc/KB LDS throughput);
// inverse applied on the global source, LDS dest linear (rule #21).
template<bool FINAL>
__global__ __launch_bounds__(512, 4) void gemmF(const bf16* __restrict__ A,
                                                const bf16* __restrict__ Bw,
                                                void* __restrict__ Cptr,
                                                const float* __restrict__ bias,
                                                int nbn, int Mvalid, int Aclamp, int ldc) {
    extern __shared__ char lds[];
    // T1: bijective XCD-chunked remap (m204)
    const int nwg = gridDim.x;
    const int xcd = blockIdx.x & 7, loc = blockIdx.x >> 3;
    const int q8 = nwg >> 3, r8 = nwg & 7;
    const int wgid = (xcd < r8 ? xcd * (q8 + 1) : r8 * (q8 + 1) + (xcd - r8) * q8) + loc;
    const int bm = wgid / nbn, bn = wgid % nbn;

    const int tid = threadIdx.x, lane = tid & 63, w = tid >> 6;
    const int li = lane & 15, lg = lane >> 4;
    const int wr = w >> 1, wc = w & 1;

    // staging: lane l writes LDS row (l>>2), slot (l&3); source k-chunk = (l&3)^((l>>2)&3)
    const int lr  = lane >> 2;                              // row within 16-row group
    const int lsw = (((lane & 3) ^ ((lane >> 2) & 3)) << 3); // src col offset (elements)
    const bf16* Agp = A  + (size_t)bm * 256 * 768;
    const bf16* Bgp = Bw + (size_t)bn * 128 * 768;
    const int clampA = Aclamp - bm * 256;

    // read-side swizzled byte offset within 64B row: slot = lg ^ (row&3), row&3 == li&3
    const int rsw = ((lg ^ (li & 3)) << 4);

#define STAGE_T(Tt, buf) do {                                                        \
        char* d_ = lds + (buf) * 24576;                                              \
        _Pragma("unroll")                                                            \
        for (int h_ = 0; h_ < 2; ++h_) {                                             \
            const int r0_ = h_ * 128 + w * 16;                                       \
            int gr_ = r0_ + lr; if (gr_ >= clampA) gr_ = clampA - 1;                 \
            glds16(Agp + (size_t)gr_ * 768 + (Tt) * 32 + lsw, d_ + r0_ * 64);        \
        }                                                                            \
        {                                                                            \
            const int r0_ = w * 16;                                                  \
            glds16(Bgp + (size_t)(r0_ + lr) * 768 + (Tt) * 32 + lsw,                 \
                   d_ + 16384 + r0_ * 64);                                           \
        } } while (0)

    f32x4 acc[4][4] = {};
    bf16x8 aF[4], bF[4];

#define READ_ALL()                                                                   \
    _Pragma("unroll") for (int mf = 0; mf < 4; ++mf)                                 \
        aF[mf] = *(const bf16x8*)(bufA + (size_t)(wr * 64 + mf * 16 + li) * 64 + rsw); \
    _Pragma("unroll") for (int nf = 0; nf < 4; ++nf)                                 \
        bF[nf] = *(const bf16x8*)(bufB + (size_t)(wc * 64 + nf * 16 + li) * 64 + rsw);

#define MFMA_ALL()                                                                   \
    _Pragma("unroll") for (int mf = 0; mf < 4; ++mf)                                 \
    _Pragma("unroll") for (int nf = 0; nf < 4; ++nf)                                 \
        acc[mf][nf] = MFMA16(aF[mf], bF[nf], acc[mf][nf]);

    // prologue: stage tiles 0,1 (3 loads each); wait tile 0, publish
    STAGE_T(0, 0);
    STAGE_T(1, 1);
    asm volatile("s_waitcnt vmcnt(3)" ::: "memory");
    __builtin_amdgcn_s_barrier();
    __builtin_amdgcn_sched_barrier(0);

    #pragma unroll
    for (int T = 0; T < 24; ++T) {
        const char* bufA = lds + (T % 3) * 24576;
        const char* bufB = bufA + 16384;
        if (T < 22) STAGE_T(T + 2, (T + 2) % 3);   // 2-tile latency lead
        READ_ALL();
        __builtin_amdgcn_s_setprio(1);
        MFMA_ALL();                                 // compiler-scheduled lgkm waits
        __builtin_amdgcn_s_setprio(0);
        asm volatile("s_waitcnt lgkmcnt(0)" ::: "memory");
        if (T < 22)       asm volatile("s_waitcnt vmcnt(3)" ::: "memory");
        else if (T == 22) asm volatile("s_waitcnt vmcnt(0)" ::: "memory");
        __builtin_amdgcn_s_barrier();               // publish buf[T+1]; protect buf[(T+2)%3]
        __builtin_amdgcn_sched_barrier(0);
    }
#undef STAGE_T
#undef READ_ALL
#undef MFMA_ALL

    // epilogue
    #pragma unroll
    for (int mf = 0; mf < 4; ++mf) {
        const int row0 = bm * 256 + wr * 64 + mf * 16 + lg * 4;
        #pragma unroll
        for (int nf = 0; nf < 4; ++nf) {
            const int col = bn * 128 + wc * 64 + nf * 16 + li;
            #pragma unroll
            for (int r = 0; r < 4; ++r) {
                const int row = row0 + r;
                if (row < Mvalid) {
                    if constexpr (FINAL)
                        ((float*)Cptr)[(size_t)row * ldc + col] = acc[mf][nf][r] + bias[col];
                    else
                        ((bf16*)Cptr)[(size_t)row * ldc + col] = (bf16)acc[mf][nf][r];
                }
            }
        }
    }
}

// ---------------- depthwise 3x3x3 pool + LayerNorm(hd), vectorized ----------------
template<int S, int OH, int OW, int CH, int NP, int NPpad, int SRCSTRIDE>
__global__ __launch_bounds__(256) void pool_norm2(const bf16* __restrict__ P,
                                                  const float* __restrict__ wt,
                                                  const float* __restrict__ gamma,
                                                  const float* __restrict__ beta,
                                                  bf16* __restrict__ outp,
                                                  float outScale) {
    constexpr int TASKS = TT * OH * CH + 1;
    const int w = threadIdx.x >> 6, lane = threadIdx.x & 63;
    const int gw = blockIdx.x * 4 + w;
    const int bh = gw / TASKS, task = gw % TASKS;
    const int b = bh / NH, head = bh % NH;
    const int owg = lane >> 3, cg = lane & 7, c = cg * 8;
    const size_t pbase = (size_t)b * NTOK * SRCSTRIDE + head * HD + c;

    if (task == TASKS - 1) {
        if (owg == 0) {
            bf16x8 v = *(const bf16x8*)(P + pbase);
            float a[8];
            #pragma unroll
            for (int e = 0; e < 8; ++e) a[e] = (float)v[e];
            float s = 0;
            #pragma unroll
            for (int e = 0; e < 8; ++e) s += a[e];
            s += __shfl_xor(s, 1); s += __shfl_xor(s, 2); s += __shfl_xor(s, 4);
            const float mu = s * 0.015625f;
            float v2 = 0;
            #pragma unroll
            for (int e = 0; e < 8; ++e) { float d = a[e] - mu; v2 += d * d; }
            v2 += __shfl_xor(v2, 1); v2 += __shfl_xor(v2, 2); v2 += __shfl_xor(v2, 4);
            const float rs = rsqrtf(v2 * 0.015625f + 1e-5f);
            f32x4 g0 = *(const f32x4*)(gamma + c), g1 = *(const f32x4*)(gamma + c + 4);
            f32x4 b0 = *(const f32x4*)(beta + c),  b1 = *(const f32x4*)(beta + c + 4);
            bf16x8 o;
            #pragma unroll
            for (int e = 0; e < 4; ++e) {
                o[e]     = (bf16)(((a[e]     - mu) * rs * g0[e] + b0[e]) * outScale);
                o[4 + e] = (bf16)(((a[4 + e] - mu) * rs * g1[e] + b1[e]) * outScale);
            }
            *(bf16x8*)(outp + ((size_t)bh * NPpad) * HD + c) = o;
        } else {
            bf16x8 z = {};
            for (int p = NP + owg - 1; p < NPpad; p += 7)
                *(bf16x8*)(outp + ((size_t)bh * NPpad + p) * HD + c) = z;
        }
        return;
    }

    const int t  = task / (OH * CH);
    const int r2 = task % (OH * CH);
    const int oh = r2 / CH;
    const int ow = (r2 % CH) * 8 + owg;
    const bool active = (ow < OW);

    float acc[8] = {0, 0, 0, 0, 0, 0, 0, 0};
    #pragma unroll
    for (int dt = 0; dt < 3; ++dt) {
        const int it = t + dt - 1;
        if (it < 0 || it >= TT) continue;
        #pragma unroll
        for (int dh = 0; dh < 3; ++dh) {
            const int ih = oh * S + dh - 1;
            if (ih < 0 || ih >= HH) continue;
            const int tokrow = 1 + (it * HH + ih) * WW;
            #pragma unroll
            for (int dw = 0; dw < 3; ++dw) {
                const int iw = ow * S + dw - 1;
                if (active && iw >= 0) {
                    bf16x8 v = *(const bf16x8*)(P + pbase + (size_t)(tokrow + iw) * SRCSTRIDE);
                    const float* wp = wt + ((dt * 3 + dh) * 3 + dw) * 64 + c;
                    f32x4 w0 = *(const f32x4*)wp, w1 = *(const f32x4*)(wp + 4);
                    #pragma unroll
                    for (int e = 0; e < 4; ++e) {
                        acc[e]     += w0[e] * (float)v[e];
                        acc[4 + e] += w1[e] * (float)v[4 + e];
                    }
                }
            }
        }
    }
    float s = 0;
    #pragma unroll
    for (int e = 0; e < 8; ++e) s += acc[e];
    s += __shfl_xor(s, 1); s += __shfl_xor(s, 2); s += __shfl_xor(s, 4);
    const float mu = s * 0.015625f;
    float v2 = 0;
    #pragma unroll
    for (int e = 0; e < 8; ++e) { float d = acc[e] - mu; v2 += d * d; }
    v2 += __shfl_xor(v2, 1); v2 += __shfl_xor(v2, 2); v2 += __shfl_xor(v2, 4);
    const float rs = rsqrtf(v2 * 0.015625f + 1e-5f);
    if (active) {
        f32x4 g0 = *(const f32x4*)(gamma + c), g1 = *(const f32x4*)(gamma + c + 4);
        f32x4 b0 = *(const f32x4*)(beta + c),  b1 = *(const f32x4*)(beta + c + 4);
        bf16x8 o;
        #pragma unroll
        for (int e = 0; e < 4; ++e) {
            o[e]     = (bf16)(((acc[e]     - mu) * rs * g0[e] + b0[e]) * outScale);
            o[4 + e] = (bf16)(((acc[4 + e] - mu) * rs * g1[e] + b1[e]) * outScale);
        }
        const int p = 1 + (t * OH + oh) * OW + ow;
        *(bf16x8*)(outp + ((size_t)bh * NPpad + p) * HD + c) = o;
    }
}

// ---------------- flash attention, fixed-max softmax ----------------
__global__ __launch_bounds__(256) void attn_kernel(const bf16* __restrict__ qn,
                                                   const bf16* __restrict__ kn,
                                                   const bf16* __restrict__ vn,
                                                   bf16* __restrict__ ob,
                                                   const float* __restrict__ Mptr) {
    __shared__ bf16 Kl[2][32][72];
    __shared__ bf16 Vt[2][64][40];
    __shared__ bf16 Pl[4][16][40];

    const int tid = threadIdx.x, l = tid & 63, w = tid >> 6;
    const int li = l & 15, lg = l >> 4;
    const int bh = blockIdx.y;
    const int b = bh / NH, head = bh % NH;
    const int qbase = blockIdx.x * 64 + w * 16;
    const float M = Mptr[0];

    const bf16* qp = qn + ((size_t)bh * NQP + qbase + li) * HD + lg * 8;
    const bf16x8 aq0 = *(const bf16x8*)qp;
    const bf16x8 aq1 = *(const bf16x8*)(qp + 32);

    const int srow = tid >> 3, scol = (tid & 7) * 8;
    const int sj = tid & 31, sd8 = tid >> 5;
    const bf16* kbase = kn + (size_t)bh * NKP * HD;
    const bf16* vbase = vn + (size_t)bh * NKP * HD;

    u32x4 kv = *(const u32x4*)(kbase + srow * HD + scol);
    u32x4 vv = *(const u32x4*)(vbase + sj * HD + sd8 * 8);
    *(u32x4*)&Kl[0][srow][scol] = kv;
    {
        bf16x8 t = __builtin_bit_cast(bf16x8, vv);
        #pragma unroll
        for (int e = 0; e < 8; ++e) Vt[0][sd8 * 8 + e][sj] = t[e];
    }

    f32x4 oacc[4] = {};
    float lpart[4] = {0.f, 0.f, 0.f, 0.f};

    for (int kt = 0; kt < 13; ++kt) {
        const int cur = kt & 1;
        if (kt < 12) {
            kv = *(const u32x4*)(kbase + (kt + 1) * 32 * HD + srow * HD + scol);
            vv = *(const u32x4*)(vbase + (kt + 1) * 32 * HD + sj * HD + sd8 * 8);
        }
        __syncthreads();

        f32x4 c0 = {}, c1 = {};
        const bf16x8 b00 = *(const bf16x8*)&Kl[cur][li][lg * 8];
        const bf16x8 b01 = *(const bf16x8*)&Kl[cur][li][32 + lg * 8];
        const bf16x8 b10 = *(const bf16x8*)&Kl[cur][16 + li][lg * 8];
        const bf16x8 b11 = *(const bf16x8*)&Kl[cur][16 + li][32 + lg * 8];
        __builtin_amdgcn_s_setprio(1);
        c0 = MFMA16(aq0, b00, c0); c0 = MFMA16(aq1, b01, c0);
        c1 = MFMA16(aq0, b10, c1); c1 = MFMA16(aq1, b11, c1);
        __builtin_amdgcn_s_setprio(0);

        float p0[4], p1[4];
        #pragma unroll
        for (int r = 0; r < 4; ++r) {
            p0[r] = __expf(c0[r] - M);
            p1[r] = __expf(c1[r] - M);
        }
        if (kt == 12) {
            const bool m0 = (384 + li) >= NK;
            #pragma unroll
            for (int r = 0; r < 4; ++r) { if (m0) p0[r] = 0.f; p1[r] = 0.f; }
        }
        #pragma unroll
        for (int r = 0; r < 4; ++r) {
            lpart[r] += p0[r] + p1[r];
            Pl[w][lg * 4 + r][li]      = (bf16)p0[r];
            Pl[w][lg * 4 + r][16 + li] = (bf16)p1[r];
        }
        const bf16x8 ap = *(const bf16x8*)&Pl[w][li][lg * 8];
        __builtin_amdgcn_s_setprio(1);
        #pragma unroll
        for (int dg = 0; dg < 4; ++dg) {
            const bf16x8 bv = *(const bf16x8*)&Vt[cur][dg * 16 + li][lg * 8];
            oacc[dg] = MFMA16(ap, bv, oacc[dg]);
        }
        __builtin_amdgcn_s_setprio(0);

        if (kt < 12) {
            const int nxt = cur ^ 1;
            *(u32x4*)&Kl[nxt][srow][scol] = kv;
            bf16x8 t = __builtin_bit_cast(bf16x8, vv);
            #pragma unroll
            for (int e = 0; e < 8; ++e) Vt[nxt][sd8 * 8 + e][sj] = t[e];
        }
    }
    #pragma unroll
    for (int r = 0; r < 4; ++r) {
        float lsum = lpart[r];
        lsum += __shfl_xor(lsum, 1);
        lsum += __shfl_xor(lsum, 2);
        lsum += __shfl_xor(lsum, 4);
        lsum += __shfl_xor(lsum, 8);
        const int q = qbase + lg * 4 + r;
        if (q < NQ) {
            const float inv = 1.f / lsum;
            const size_t off = ((size_t)(b * NQ + q)) * CC + head * HD;
            #pragma unroll
            for (int dg = 0; dg < 4; ++dg)
                ob[off + dg * 16 + li] = (bf16)(oacc[dg][r] * inv);
        }
    }
}

// ---------------- launcher ----------------
extern "C" void kernel_launch(void* const* d_in, const int* in_sizes, int n_in,
                              void* d_out, int out_size, void* d_ws, size_t ws_size,
                              hipStream_t stream) {
    const float* x     = (const float*)d_in[0];
    const float* Wq    = (const float*)d_in[1];
    const float* Wk    = (const float*)d_in[2];
    const float* Wv    = (const float*)d_in[3];
    const float* Wproj = (const float*)d_in[4];
    const float* bproj = (const float*)d_in[5];
    const float* pqw   = (const float*)d_in[6];
    const float* pkw   = (const float*)d_in[7];
    const float* pvw   = (const float*)d_in[8];
    const float* gq    = (const float*)d_in[9];
    const float* bq    = (const float*)d_in[10];
    const float* gk    = (const float*)d_in[11];
    const float* bk    = (const float*)d_in[12];
    const float* gv    = (const float*)d_in[13];
    const float* bv    = (const float*)d_in[14];

    if (ws_size < 364000000ULL) return;
    char* ws = (char*)d_ws;
    bf16* xb   = (bf16*)(ws);               // [50304][768]   77,266,944
    bf16* wqkv = (bf16*)(ws + 77266944);    // [2304][768]     3,538,944
    bf16* wpb  = (bf16*)(ws + 80805888);    // [768][768]      1,179,648
    bf16* tmp3 = (bf16*)(ws + 81985536);    // [50304][2304] 231,800,832
    bf16* qn   = (bf16*)(ws + 313786368);   // [96][1600][64] 19,660,800
    bf16* kn   = (bf16*)(ws + 333447168);   // [96][416][64]   5,111,808
    bf16* vnb  = (bf16*)(ws + 338558976);   // [96][416][64]   5,111,808
    bf16* ob   = (bf16*)(ws + 343670784);   // [12672][768]   19,464,192
    float* wt  = (float*)(ws + 363134976);  // [3][27][64] f32    20,736
    float* Mb  = (float*)(ws + 363155712);  // [1]

    const int WSZ = 589824;  // 768*768

    (void)hipFuncSetAttribute((const void*)gemmF<false>,
                              hipFuncAttributeMaxDynamicSharedMemorySize, 73728);
    (void)hipFuncSetAttribute((const void*)gemmF<true>,
                              hipFuncAttributeMaxDynamicSharedMemorySize, 73728);

    transpose_w3<<<21, 256, 0, stream>>>(pqw, pkw, pvw, wt);
    bound_kernel<<<1, 64, 0, stream>>>(gq, bq, gk, bk, Mb);
    cast_f32_bf16<<<4096, 256, 0, stream>>>(x, xb, MX * CC, MXP * CC);
    cast_f32_bf16<<<576, 256, 0, stream>>>(Wq, wqkv,            WSZ, WSZ);
    cast_f32_bf16<<<576, 256, 0, stream>>>(Wk, wqkv + WSZ,      WSZ, WSZ);
    cast_f32_bf16<<<576, 256, 0, stream>>>(Wv, wqkv + 2 * WSZ,  WSZ, WSZ);
    cast_f32_bf16<<<576, 256, 0, stream>>>(Wproj, wpb,          WSZ, WSZ);

    // fused QKV projection: [50304][768] @ [2304][768]^T -> [50304][2304]
    gemmF<false><<<197 * 18, 512, 73728, stream>>>(xb, wqkv, tmp3, nullptr, 18, MXP, MXP, 2304);

    // pools read fused output at column offsets 0/768/1536 (stride 2304)
    pool_norm2<2, 14, 14, 2, NQ, NQP, 2304><<<5400, 256, 0, stream>>>(tmp3,        wt,        gq, bq, qn,  0.125f);
    pool_norm2<4, 7, 7, 1, NK, NKP, 2304><<<1368, 256, 0, stream>>>(tmp3 + 768,  wt + 1728, gk, bk, kn,  1.0f);
    pool_norm2<4, 7, 7, 1, NK, NKP, 2304><<<1368, 256, 0, stream>>>(tmp3 + 1536, wt + 3456, gv, bv, vnb, 1.0f);

    attn_kernel<<<dim3(25, 96), 256, 0, stream>>>(qn, kn, vnb, ob, Mb);

    gemmF<true><<<50 * 6, 512, 73728, stream>>>(ob, wpb, d_out, bproj, 6, MO, MOP, 768);
}

// Round 8
// 430.279 us; speedup vs baseline: 1.8355x; 1.0454x over previous
//
#include <hip/hip_runtime.h>

using bf16   = __bf16;
using bf16x4 = __attribute__((ext_vector_type(4))) __bf16;
using bf16x8 = __attribute__((ext_vector_type(8))) __bf16;
using f32x4  = __attribute__((ext_vector_type(4))) float;
using u32x4  = __attribute__((ext_vector_type(4))) unsigned int;

#define MFMA16(a,b,c) __builtin_amdgcn_mfma_f32_16x16x32_bf16((a),(b),(c),0,0,0)

__device__ inline void glds16(const void* g, void* l) {
    __builtin_amdgcn_global_load_lds(
        (__attribute__((address_space(1))) void*)(const_cast<void*>(g)),
        (__attribute__((address_space(3))) void*)(l), 16, 0, 0);
}

// ---------------- constants (problem-instance fixed) ----------------
constexpr int CB   = 8;
constexpr int NH   = 12;
constexpr int CC   = 768;
constexpr int HD   = 64;
constexpr int TT   = 8, HH = 28, WW = 28;
constexpr int NTOK = TT*HH*WW + 1;      // 6273
constexpr int MX   = CB*NTOK;           // 50184
constexpr int MXP  = 50304;             // padded M rows in xb/tmp3
constexpr int NQ   = 1569, NQP = 1600;
constexpr int NK   = 393,  NKP = 416;
constexpr int MO   = CB*NQ;             // 12552
constexpr int MOP  = 12672;

// ---------------- f32 -> bf16 cast (with zero tail pad) ----------------
__global__ __launch_bounds__(256) void cast_f32_bf16(const float* __restrict__ src,
                                                     bf16* __restrict__ dst,
                                                     int nvalid, int ntotal) {
    int i = (blockIdx.x * 256 + threadIdx.x) * 4;
    int stride = gridDim.x * 256 * 4;
    for (; i < ntotal; i += stride) {
        bf16x4 o;
        if (i + 3 < nvalid) {
            f32x4 v = *(const f32x4*)(src + i);
            #pragma unroll
            for (int e = 0; e < 4; ++e) o[e] = (bf16)v[e];
        } else {
            #pragma unroll
            for (int e = 0; e < 4; ++e) {
                int k = i + e;
                o[e] = (bf16)((k < nvalid) ? src[k] : 0.f);
            }
        }
        *(bf16x4*)(dst + i) = o;
    }
}

// ---------------- weight transpose: (64,27) -> [27][64], 3 sets ----------------
__global__ __launch_bounds__(256) void transpose_w3(const float* __restrict__ w0,
                                                    const float* __restrict__ w1,
                                                    const float* __restrict__ w2,
                                                    float* __restrict__ wt) {
    int i = blockIdx.x * 256 + threadIdx.x;
    if (i >= 3 * 1728) return;
    int setn = i / 1728, j = i % 1728;
    const float* src = (setn == 0) ? w0 : (setn == 1) ? w1 : w2;
    int tap = j / 64, c = j % 64;
    wt[i] = src[c * 27 + tap];
}

// ---------------- score-bound kernel: M = 0.125 * Bq * Bk ----------------
__global__ void bound_kernel(const float* __restrict__ gq, const float* __restrict__ bq,
                             const float* __restrict__ gk, const float* __restrict__ bk,
                             float* __restrict__ out) {
    const int c = threadIdx.x;   // 64 threads
    float mgq = fabsf(gq[c]), sbq = bq[c] * bq[c];
    float mgk = fabsf(gk[c]), sbk = bk[c] * bk[c];
    #pragma unroll
    for (int m = 1; m < 64; m <<= 1) {
        mgq = fmaxf(mgq, __shfl_xor(mgq, m)); sbq += __shfl_xor(sbq, m);
        mgk = fmaxf(mgk, __shfl_xor(mgk, m)); sbk += __shfl_xor(sbk, m);
    }
    if (c == 0) {
        const float Bq = 8.f * mgq + sqrtf(sbq);
        const float Bk = 8.f * mgk + sqrtf(sbk);
        out[0] = 0.125f * Bq * Bk;
    }
}

// ---------------- 256x256 bf16 GEMM, BK=64, dbuf, one barrier/tile ----------------
// A: [*][768] bf16 row-major.  Bw: [Ncols][768] bf16 (W[out][in], B^T layout).
// C = A @ Bw^T, row stride ldc.  K = 768 (12 K-tiles of 64).
// 512 thr = 8 waves (2M x 4N); wave tile 128x64; acc 8x4 f32x4 (128 VGPR).
// LDS: 2 x (A 256x64 | B 256x64) = 131072 B. FLOP/staged-byte = 128 (1.5x r7):
// the staging-throughput cap (~9 TB/s, observed r4-r7) then bounds at ~1150 TF.
// Tile T stages T+1 at its top (full-tile latency lead); end-of-tile vmcnt(0)
// is latency-free since tile time >> HBM/L2 latency. r6-verified 0-conflict
// swizzle (slot ^= row&7 within 128B rows; inverse on global src, rule #21).
template<bool FINAL>
__global__ __launch_bounds__(512, 2) void gemmF(const bf16* __restrict__ A,
                                                const bf16* __restrict__ Bw,
                                                void* __restrict__ Cptr,
                                                const float* __restrict__ bias,
                                                int nbn, int Mvalid, int Aclamp, int ldc) {
    extern __shared__ char lds[];
    // T1: bijective XCD-chunked remap (m204)
    const int nwg = gridDim.x;
    const int xcd = blockIdx.x & 7, loc = blockIdx.x >> 3;
    const int q8 = nwg >> 3, r8 = nwg & 7;
    const int wgid = (xcd < r8 ? xcd * (q8 + 1) : r8 * (q8 + 1) + (xcd - r8) * q8) + loc;
    const int bm = wgid / nbn, bn = wgid % nbn;

    const int tid = threadIdx.x, lane = tid & 63, w = tid >> 6;
    const int li = lane & 15, lg = lane >> 4;
    const int wr = w >> 2, wc = w & 3;

    // staging source swizzle (inverse of read-side; LDS dest linear)
    const int lr  = lane >> 3;                      // row within 8-row group
    const int lsw = ((lane & 7) ^ lr) << 3;         // src col offset (elements)
    const bf16* Agp = A  + (size_t)bm * 256 * 768;
    const bf16* Bgp = Bw + (size_t)bn * 256 * 768;
    const int clampA = Aclamp - bm * 256;

    // read-side swizzled byte offsets for k-slice 0/1 (row&7 == li&7)
    const int sw_  = (li & 7) << 4;
    const int swc0 = (lg * 16) ^ sw_;
    const int swc1 = (64 | (lg * 16)) ^ sw_;

#define STAGE_T(Tt, buf) do {                                                        \
        char* d_ = lds + (buf) * 65536;                                              \
        _Pragma("unroll")                                                            \
        for (int h_ = 0; h_ < 4; ++h_) {                                             \
            const int r0_ = h_ * 64 + w * 8;                                         \
            int gr_ = r0_ + lr; if (gr_ >= clampA) gr_ = clampA - 1;                 \
            glds16(Agp + (size_t)gr_ * 768 + (Tt) * 64 + lsw, d_ + r0_ * 128);       \
        }                                                                            \
        _Pragma("unroll")                                                            \
        for (int h_ = 0; h_ < 4; ++h_) {                                             \
            const int r0_ = h_ * 64 + w * 8;                                         \
            glds16(Bgp + (size_t)(r0_ + lr) * 768 + (Tt) * 64 + lsw,                 \
                   d_ + 32768 + r0_ * 128);                                          \
        } } while (0)

    f32x4 acc[8][4] = {};
    bf16x8 aF[8], bF[4];

#define READ_K(sw)                                                                   \
    _Pragma("unroll") for (int mf = 0; mf < 8; ++mf)                                 \
        aF[mf] = *(const bf16x8*)(bufA + (size_t)(wr * 128 + mf * 16 + li) * 128 + (sw)); \
    _Pragma("unroll") for (int nf = 0; nf < 4; ++nf)                                 \
        bF[nf] = *(const bf16x8*)(bufB + (size_t)(wc * 64 + nf * 16 + li) * 128 + (sw));

#define MFMA_K()                                                                     \
    _Pragma("unroll") for (int mf = 0; mf < 8; ++mf)                                 \
    _Pragma("unroll") for (int nf = 0; nf < 4; ++nf)                                 \
        acc[mf][nf] = MFMA16(aF[mf], bF[nf], acc[mf][nf]);

    // prologue: stage tiles 0 and 1; wait tile 0 (8 of 16 outstanding), publish
    STAGE_T(0, 0);
    STAGE_T(1, 1);
    asm volatile("s_waitcnt vmcnt(8)" ::: "memory");
    __builtin_amdgcn_s_barrier();
    __builtin_amdgcn_sched_barrier(0);

    #pragma unroll
    for (int T = 0; T < 12; ++T) {
        const char* bufA = lds + (T & 1) * 65536;
        const char* bufB = bufA + 32768;
        if (T >= 1 && T < 11) STAGE_T(T + 1, (T + 1) & 1);  // full-tile latency lead
        READ_K(swc0);
        __builtin_amdgcn_s_setprio(1);
        MFMA_K();                                   // compiler-scheduled lgkm waits
        __builtin_amdgcn_s_setprio(0);
        READ_K(swc1);
        __builtin_amdgcn_s_setprio(1);
        MFMA_K();
        __builtin_amdgcn_s_setprio(0);
        asm volatile("s_waitcnt lgkmcnt(0)" ::: "memory");
        if (T < 11) asm volatile("s_waitcnt vmcnt(0)" ::: "memory");  // next buf ready (latency already hidden)
        __builtin_amdgcn_s_barrier();               // publish buf[T+1]; protect buf[T&1] for restage
        __builtin_amdgcn_sched_barrier(0);
    }
#undef STAGE_T
#undef READ_K
#undef MFMA_K

    // epilogue
    #pragma unroll
    for (int mf = 0; mf < 8; ++mf) {
        const int row0 = bm * 256 + wr * 128 + mf * 16 + lg * 4;
        #pragma unroll
        for (int nf = 0; nf < 4; ++nf) {
            const int col = bn * 256 + wc * 64 + nf * 16 + li;
            #pragma unroll
            for (int r = 0; r < 4; ++r) {
                const int row = row0 + r;
                if (row < Mvalid) {
                    if constexpr (FINAL)
                        ((float*)Cptr)[(size_t)row * ldc + col] = acc[mf][nf][r] + bias[col];
                    else
                        ((bf16*)Cptr)[(size_t)row * ldc + col] = (bf16)acc[mf][nf][r];
                }
            }
        }
    }
}

// ---------------- depthwise 3x3x3 pool + LayerNorm(hd), vectorized ----------------
template<int S, int OH, int OW, int CH, int NP, int NPpad, int SRCSTRIDE>
__global__ __launch_bounds__(256) void pool_norm2(const bf16* __restrict__ P,
                                                  const float* __restrict__ wt,
                                                  const float* __restrict__ gamma,
                                                  const float* __restrict__ beta,
                                                  bf16* __restrict__ outp,
                                                  float outScale) {
    constexpr int TASKS = TT * OH * CH + 1;
    const int w = threadIdx.x >> 6, lane = threadIdx.x & 63;
    const int gw = blockIdx.x * 4 + w;
    const int bh = gw / TASKS, task = gw % TASKS;
    const int b = bh / NH, head = bh % NH;
    const int owg = lane >> 3, cg = lane & 7, c = cg * 8;
    const size_t pbase = (size_t)b * NTOK * SRCSTRIDE + head * HD + c;

    if (task == TASKS - 1) {
        if (owg == 0) {
            bf16x8 v = *(const bf16x8*)(P + pbase);
            float a[8];
            #pragma unroll
            for (int e = 0; e < 8; ++e) a[e] = (float)v[e];
            float s = 0;
            #pragma unroll
            for (int e = 0; e < 8; ++e) s += a[e];
            s += __shfl_xor(s, 1); s += __shfl_xor(s, 2); s += __shfl_xor(s, 4);
            const float mu = s * 0.015625f;
            float v2 = 0;
            #pragma unroll
            for (int e = 0; e < 8; ++e) { float d = a[e] - mu; v2 += d * d; }
            v2 += __shfl_xor(v2, 1); v2 += __shfl_xor(v2, 2); v2 += __shfl_xor(v2, 4);
            const float rs = rsqrtf(v2 * 0.015625f + 1e-5f);
            f32x4 g0 = *(const f32x4*)(gamma + c), g1 = *(const f32x4*)(gamma + c + 4);
            f32x4 b0 = *(const f32x4*)(beta + c),  b1 = *(const f32x4*)(beta + c + 4);
            bf16x8 o;
            #pragma unroll
            for (int e = 0; e < 4; ++e) {
                o[e]     = (bf16)(((a[e]     - mu) * rs * g0[e] + b0[e]) * outScale);
                o[4 + e] = (bf16)(((a[4 + e] - mu) * rs * g1[e] + b1[e]) * outScale);
            }
            *(bf16x8*)(outp + ((size_t)bh * NPpad) * HD + c) = o;
        } else {
            bf16x8 z = {};
            for (int p = NP + owg - 1; p < NPpad; p += 7)
                *(bf16x8*)(outp + ((size_t)bh * NPpad + p) * HD + c) = z;
        }
        return;
    }

    const int t  = task / (OH * CH);
    const int r2 = task % (OH * CH);
    const int oh = r2 / CH;
    const int ow = (r2 % CH) * 8 + owg;
    const bool active = (ow < OW);

    float acc[8] = {0, 0, 0, 0, 0, 0, 0, 0};
    #pragma unroll
    for (int dt = 0; dt < 3; ++dt) {
        const int it = t + dt - 1;
        if (it < 0 || it >= TT) continue;
        #pragma unroll
        for (int dh = 0; dh < 3; ++dh) {
            const int ih = oh * S + dh - 1;
            if (ih < 0 || ih >= HH) continue;
            const int tokrow = 1 + (it * HH + ih) * WW;
            #pragma unroll
            for (int dw = 0; dw < 3; ++dw) {
                const int iw = ow * S + dw - 1;
                if (active && iw >= 0) {
                    bf16x8 v = *(const bf16x8*)(P + pbase + (size_t)(tokrow + iw) * SRCSTRIDE);
                    const float* wp = wt + ((dt * 3 + dh) * 3 + dw) * 64 + c;
                    f32x4 w0 = *(const f32x4*)wp, w1 = *(const f32x4*)(wp + 4);
                    #pragma unroll
                    for (int e = 0; e < 4; ++e) {
                        acc[e]     += w0[e] * (float)v[e];
                        acc[4 + e] += w1[e] * (float)v[4 + e];
                    }
                }
            }
        }
    }
    float s = 0;
    #pragma unroll
    for (int e = 0; e < 8; ++e) s += acc[e];
    s += __shfl_xor(s, 1); s += __shfl_xor(s, 2); s += __shfl_xor(s, 4);
    const float mu = s * 0.015625f;
    float v2 = 0;
    #pragma unroll
    for (int e = 0; e < 8; ++e) { float d = acc[e] - mu; v2 += d * d; }
    v2 += __shfl_xor(v2, 1); v2 += __shfl_xor(v2, 2); v2 += __shfl_xor(v2, 4);
    const float rs = rsqrtf(v2 * 0.015625f + 1e-5f);
    if (active) {
        f32x4 g0 = *(const f32x4*)(gamma + c), g1 = *(const f32x4*)(gamma + c + 4);
        f32x4 b0 = *(const f32x4*)(beta + c),  b1 = *(const f32x4*)(beta + c + 4);
        bf16x8 o;
        #pragma unroll
        for (int e = 0; e < 4; ++e) {
            o[e]     = (bf16)(((acc[e]     - mu) * rs * g0[e] + b0[e]) * outScale);
            o[4 + e] = (bf16)(((acc[4 + e] - mu) * rs * g1[e] + b1[e]) * outScale);
        }
        const int p = 1 + (t * OH + oh) * OW + ow;
        *(bf16x8*)(outp + ((size_t)bh * NPpad + p) * HD + c) = o;
    }
}

// ---------------- flash attention, fixed-max softmax ----------------
__global__ __launch_bounds__(256) void attn_kernel(const bf16* __restrict__ qn,
                                                   const bf16* __restrict__ kn,
                                                   const bf16* __restrict__ vn,
                                                   bf16* __restrict__ ob,
                                                   const float* __restrict__ Mptr) {
    __shared__ bf16 Kl[2][32][72];
    __shared__ bf16 Vt[2][64][40];
    __shared__ bf16 Pl[4][16][40];

    const int tid = threadIdx.x, l = tid & 63, w = tid >> 6;
    const int li = l & 15, lg = l >> 4;
    const int bh = blockIdx.y;
    const int b = bh / NH, head = bh % NH;
    const int qbase = blockIdx.x * 64 + w * 16;
    const float M = Mptr[0];

    const bf16* qp = qn + ((size_t)bh * NQP + qbase + li) * HD + lg * 8;
    const bf16x8 aq0 = *(const bf16x8*)qp;
    const bf16x8 aq1 = *(const bf16x8*)(qp + 32);

    const int srow = tid >> 3, scol = (tid & 7) * 8;
    const int sj = tid & 31, sd8 = tid >> 5;
    const bf16* kbase = kn + (size_t)bh * NKP * HD;
    const bf16* vbase = vn + (size_t)bh * NKP * HD;

    u32x4 kv = *(const u32x4*)(kbase + srow * HD + scol);
    u32x4 vv = *(const u32x4*)(vbase + sj * HD + sd8 * 8);
    *(u32x4*)&Kl[0][srow][scol] = kv;
    {
        bf16x8 t = __builtin_bit_cast(bf16x8, vv);
        #pragma unroll
        for (int e = 0; e < 8; ++e) Vt[0][sd8 * 8 + e][sj] = t[e];
    }

    f32x4 oacc[4] = {};
    float lpart[4] = {0.f, 0.f, 0.f, 0.f};

    for (int kt = 0; kt < 13; ++kt) {
        const int cur = kt & 1;
        if (kt < 12) {
            kv = *(const u32x4*)(kbase + (kt + 1) * 32 * HD + srow * HD + scol);
            vv = *(const u32x4*)(vbase + (kt + 1) * 32 * HD + sj * HD + sd8 * 8);
        }
        __syncthreads();

        f32x4 c0 = {}, c1 = {};
        const bf16x8 b00 = *(const bf16x8*)&Kl[cur][li][lg * 8];
        const bf16x8 b01 = *(const bf16x8*)&Kl[cur][li][32 + lg * 8];
        const bf16x8 b10 = *(const bf16x8*)&Kl[cur][16 + li][lg * 8];
        const bf16x8 b11 = *(const bf16x8*)&Kl[cur][16 + li][32 + lg * 8];
        __builtin_amdgcn_s_setprio(1);
        c0 = MFMA16(aq0, b00, c0); c0 = MFMA16(aq1, b01, c0);
        c1 = MFMA16(aq0, b10, c1); c1 = MFMA16(aq1, b11, c1);
        __builtin_amdgcn_s_setprio(0);

        float p0[4], p1[4];
        #pragma unroll
        for (int r = 0; r < 4; ++r) {
            p0[r] = __expf(c0[r] - M);
            p1[r] = __expf(c1[r] - M);
        }
        if (kt == 12) {
            const bool m0 = (384 + li) >= NK;
            #pragma unroll
            for (int r = 0; r < 4; ++r) { if (m0) p0[r] = 0.f; p1[r] = 0.f; }
        }
        #pragma unroll
        for (int r = 0; r < 4; ++r) {
            lpart[r] += p0[r] + p1[r];
            Pl[w][lg * 4 + r][li]      = (bf16)p0[r];
            Pl[w][lg * 4 + r][16 + li] = (bf16)p1[r];
        }
        const bf16x8 ap = *(const bf16x8*)&Pl[w][li][lg * 8];
        __builtin_amdgcn_s_setprio(1);
        #pragma unroll
        for (int dg = 0; dg < 4; ++dg) {
            const bf16x8 bv = *(const bf16x8*)&Vt[cur][dg * 16 + li][lg * 8];
            oacc[dg] = MFMA16(ap, bv, oacc[dg]);
        }
        __builtin_amdgcn_s_setprio(0);

        if (kt < 12) {
            const int nxt = cur ^ 1;
            *(u32x4*)&Kl[nxt][srow][scol] = kv;
            bf16x8 t = __builtin_bit_cast(bf16x8, vv);
            #pragma unroll
            for (int e = 0; e < 8; ++e) Vt[nxt][sd8 * 8 + e][sj] = t[e];
        }
    }
    #pragma unroll
    for (int r = 0; r < 4; ++r) {
        float lsum = lpart[r];
        lsum += __shfl_xor(lsum, 1);
        lsum += __shfl_xor(lsum, 2);
        lsum += __shfl_xor(lsum, 4);
        lsum += __shfl_xor(lsum, 8);
        const int q = qbase + lg * 4 + r;
        if (q < NQ) {
            const float inv = 1.f / lsum;
            const size_t off = ((size_t)(b * NQ + q)) * CC + head * HD;
            #pragma unroll
            for (int dg = 0; dg < 4; ++dg)
                ob[off + dg * 16 + li] = (bf16)(oacc[dg][r] * inv);
        }
    }
}

// ---------------- launcher ----------------
extern "C" void kernel_launch(void* const* d_in, const int* in_sizes, int n_in,
                              void* d_out, int out_size, void* d_ws, size_t ws_size,
                              hipStream_t stream) {
    const float* x     = (const float*)d_in[0];
    const float* Wq    = (const float*)d_in[1];
    const float* Wk    = (const float*)d_in[2];
    const float* Wv    = (const float*)d_in[3];
    const float* Wproj = (const float*)d_in[4];
    const float* bproj = (const float*)d_in[5];
    const float* pqw   = (const float*)d_in[6];
    const float* pkw   = (const float*)d_in[7];
    const float* pvw   = (const float*)d_in[8];
    const float* gq    = (const float*)d_in[9];
    const float* bq    = (const float*)d_in[10];
    const float* gk    = (const float*)d_in[11];
    const float* bk    = (const float*)d_in[12];
    const float* gv    = (const float*)d_in[13];
    const float* bv    = (const float*)d_in[14];

    if (ws_size < 364000000ULL) return;
    char* ws = (char*)d_ws;
    bf16* xb   = (bf16*)(ws);               // [50304][768]   77,266,944
    bf16* wqkv = (bf16*)(ws + 77266944);    // [2304][768]     3,538,944
    bf16* wpb  = (bf16*)(ws + 80805888);    // [768][768]      1,179,648
    bf16* tmp3 = (bf16*)(ws + 81985536);    // [50304][2304] 231,800,832
    bf16* qn   = (bf16*)(ws + 313786368);   // [96][1600][64] 19,660,800
    bf16* kn   = (bf16*)(ws + 333447168);   // [96][416][64]   5,111,808
    bf16* vnb  = (bf16*)(ws + 338558976);   // [96][416][64]   5,111,808
    bf16* ob   = (bf16*)(ws + 343670784);   // [12672][768]   19,464,192
    float* wt  = (float*)(ws + 363134976);  // [3][27][64] f32    20,736
    float* Mb  = (float*)(ws + 363155712);  // [1]

    const int WSZ = 589824;  // 768*768

    (void)hipFuncSetAttribute((const void*)gemmF<false>,
                              hipFuncAttributeMaxDynamicSharedMemorySize, 131072);
    (void)hipFuncSetAttribute((const void*)gemmF<true>,
                              hipFuncAttributeMaxDynamicSharedMemorySize, 131072);

    transpose_w3<<<21, 256, 0, stream>>>(pqw, pkw, pvw, wt);
    bound_kernel<<<1, 64, 0, stream>>>(gq, bq, gk, bk, Mb);
    cast_f32_bf16<<<4096, 256, 0, stream>>>(x, xb, MX * CC, MXP * CC);
    cast_f32_bf16<<<576, 256, 0, stream>>>(Wq, wqkv,            WSZ, WSZ);
    cast_f32_bf16<<<576, 256, 0, stream>>>(Wk, wqkv + WSZ,      WSZ, WSZ);
    cast_f32_bf16<<<576, 256, 0, stream>>>(Wv, wqkv + 2 * WSZ,  WSZ, WSZ);
    cast_f32_bf16<<<576, 256, 0, stream>>>(Wproj, wpb,          WSZ, WSZ);

    // fused QKV projection: [50304][768] @ [2304][768]^T -> [50304][2304]
    // 197 M-tiles x 9 N-tiles of 256x256
    gemmF<false><<<197 * 9, 512, 131072, stream>>>(xb, wqkv, tmp3, nullptr, 9, MXP, MXP, 2304);

    // pools read fused output at column offsets 0/768/1536 (stride 2304)
    pool_norm2<2, 14, 14, 2, NQ, NQP, 2304><<<5400, 256, 0, stream>>>(tmp3,        wt,        gq, bq, qn,  0.125f);
    pool_norm2<4, 7, 7, 1, NK, NKP, 2304><<<1368, 256, 0, stream>>>(tmp3 + 768,  wt + 1728, gk, bk, kn,  1.0f);
    pool_norm2<4, 7, 7, 1, NK, NKP, 2304><<<1368, 256, 0, stream>>>(tmp3 + 1536, wt + 3456, gv, bv, vnb, 1.0f);

    attn_kernel<<<dim3(25, 96), 256, 0, stream>>>(qn, kn, vnb, ob, Mb);

    // final projection: [12672][768] @ [768][768]^T -> f32 + bias (50 x 3 tiles)
    gemmF<true><<<50 * 3, 512, 131072, stream>>>(ob, wpb, d_out, bproj, 3, MO, MOP, 768);
}

// Round 9
// 360.184 us; speedup vs baseline: 2.1927x; 1.1946x over previous
//
#include <hip/hip_runtime.h>

using bf16   = __bf16;
using bf16x4 = __attribute__((ext_vector_type(4))) __bf16;
using bf16x8 = __attribute__((ext_vector_type(8))) __bf16;
using f32x4  = __attribute__((ext_vector_type(4))) float;
using u32x4  = __attribute__((ext_vector_type(4))) unsigned int;

#define MFMA16(a,b,c) __builtin_amdgcn_mfma_f32_16x16x32_bf16((a),(b),(c),0,0,0)

__device__ inline void glds16(const void* g, void* l) {
    __builtin_amdgcn_global_load_lds(
        (__attribute__((address_space(1))) void*)(const_cast<void*>(g)),
        (__attribute__((address_space(3))) void*)(l), 16, 0, 0);
}

// ---------------- constants (problem-instance fixed) ----------------
constexpr int CB   = 8;
constexpr int NH   = 12;
constexpr int CC   = 768;
constexpr int HD   = 64;
constexpr int TT   = 8, HH = 28, WW = 28;
constexpr int NTOK = TT*HH*WW + 1;      // 6273
constexpr int MX   = CB*NTOK;           // 50184
constexpr int MXP  = 50304;             // padded M rows in xb/tmpq
constexpr int NQ   = 1569, NQP = 1600;
constexpr int NK   = 393,  NKP = 416;
constexpr int MO   = CB*NQ;             // 12552
constexpr int MOP  = 12672;
// compact KV token set: rows ih in {4a-1,4a,4a+1} -> 20 of 28 per dim
constexpr int CTOK = 1 + TT*20*20;      // 3201 per batch
constexpr int MKV  = CB*CTOK;           // 25608
constexpr int MKVP = 25856;             // 101*256

// ---------------- f32 -> bf16 cast (with zero tail pad) ----------------
__global__ __launch_bounds__(256) void cast_f32_bf16(const float* __restrict__ src,
                                                     bf16* __restrict__ dst,
                                                     int nvalid, int ntotal) {
    int i = (blockIdx.x * 256 + threadIdx.x) * 4;
    int stride = gridDim.x * 256 * 4;
    for (; i < ntotal; i += stride) {
        bf16x4 o;
        if (i + 3 < nvalid) {
            f32x4 v = *(const f32x4*)(src + i);
            #pragma unroll
            for (int e = 0; e < 4; ++e) o[e] = (bf16)v[e];
        } else {
            #pragma unroll
            for (int e = 0; e < 4; ++e) {
                int k = i + e;
                o[e] = (bf16)((k < nvalid) ? src[k] : 0.f);
            }
        }
        *(bf16x4*)(dst + i) = o;
    }
}

// ---------------- weight transpose: (64,27) -> [27][64], 3 sets ----------------
__global__ __launch_bounds__(256) void transpose_w3(const float* __restrict__ w0,
                                                    const float* __restrict__ w1,
                                                    const float* __restrict__ w2,
                                                    float* __restrict__ wt) {
    int i = blockIdx.x * 256 + threadIdx.x;
    if (i >= 3 * 1728) return;
    int setn = i / 1728, j = i % 1728;
    const float* src = (setn == 0) ? w0 : (setn == 1) ? w1 : w2;
    int tap = j / 64, c = j % 64;
    wt[i] = src[c * 27 + tap];
}

// ---------------- score-bound kernel: M = 0.125 * Bq * Bk ----------------
__global__ void bound_kernel(const float* __restrict__ gq, const float* __restrict__ bq,
                             const float* __restrict__ gk, const float* __restrict__ bk,
                             float* __restrict__ out) {
    const int c = threadIdx.x;   // 64 threads
    float mgq = fabsf(gq[c]), sbq = bq[c] * bq[c];
    float mgk = fabsf(gk[c]), sbk = bk[c] * bk[c];
    #pragma unroll
    for (int m = 1; m < 64; m <<= 1) {
        mgq = fmaxf(mgq, __shfl_xor(mgq, m)); sbq += __shfl_xor(sbq, m);
        mgk = fmaxf(mgk, __shfl_xor(mgk, m)); sbk += __shfl_xor(sbk, m);
    }
    if (c == 0) {
        const float Bq = 8.f * mgq + sqrtf(sbq);
        const float Bk = 8.f * mgk + sqrtf(sbk);
        out[0] = 0.125f * Bq * Bk;
    }
}

// ---------------- unified Q + gathered-KV projection GEMM ----------------
// r8 structure (256x256, BK=64, dbuf, one barrier/tile, 0-conflict swizzle).
// Blocks [0,591): Q = xb(all rows) @ Wq^T -> tmpq [50304][768].
// Blocks [591,1197): KV = gather(xb) @ Wkv^T -> tmpkv [25856][1536], where the
// gather keeps only the 3201 tokens/batch the stride-4 pools read. Per-lane
// A-row pointers precomputed once (global src of global_load_lds is per-lane).
__global__ __launch_bounds__(512, 2) void gemmU(const bf16* __restrict__ xb,
                                                const bf16* __restrict__ wqkv,
                                                bf16* __restrict__ tmpq,
                                                bf16* __restrict__ tmpkv) {
    extern __shared__ char lds[];
    const int nwg = gridDim.x;   // 1197
    const int xcd = blockIdx.x & 7, loc = blockIdx.x >> 3;
    const int q8 = nwg >> 3, r8 = nwg & 7;
    const int wgid = (xcd < r8 ? xcd * (q8 + 1) : r8 * (q8 + 1) + (xcd - r8) * q8) + loc;

    const int tid = threadIdx.x, lane = tid & 63, w = tid >> 6;
    const int li = lane & 15, lg = lane >> 4;
    const int wr = w >> 2, wc = w & 3;
    const int lr  = lane >> 3;
    const int lsw = ((lane & 7) ^ lr) << 3;

    const bool isQ = wgid < 591;
    int bm, bn, Mv, ldc;
    const bf16* Bb;
    bf16* C;
    if (isQ) { bm = wgid / 3;        bn = wgid % 3;        Mv = MXP;  ldc = 768;
               Bb = wqkv + (size_t)bn * 256 * 768;               C = tmpq; }
    else     { int t = wgid - 591;   bm = t / 6; bn = t % 6; Mv = MKVP; ldc = 1536;
               Bb = wqkv + (size_t)(768 + bn * 256) * 768;       C = tmpkv; }

    // per-lane A/B row base pointers (fixed across K-tiles)
    const bf16* abase[4];
    const bf16* bbase[4];
    #pragma unroll
    for (int h_ = 0; h_ < 4; ++h_) {
        int gr = bm * 256 + h_ * 64 + w * 8 + lr;
        size_t orig;
        if (isQ) {
            if (gr > MXP - 1) gr = MXP - 1;
            orig = (size_t)gr;
        } else {
            if (gr > MKV - 1) gr = MKV - 1;
            const unsigned b = (unsigned)gr / 3201u;
            const unsigned p = (unsigned)gr % 3201u;
            if (p == 0) orig = (size_t)b * NTOK;
            else {
                const unsigned q  = p - 1;
                const unsigned t2 = q / 400u, rem = q % 400u;
                const unsigned hi = rem / 20u, wi = rem % 20u;
                const int ih = 4 * (int)((hi + 1) / 3) + (int)((hi + 1) % 3) - 1;
                const int iw = 4 * (int)((wi + 1) / 3) + (int)((wi + 1) % 3) - 1;
                orig = (size_t)b * NTOK + 1 + ((size_t)t2 * HH + ih) * WW + iw;
            }
        }
        abase[h_] = xb + orig * 768 + lsw;
        bbase[h_] = Bb + (size_t)(h_ * 64 + w * 8 + lr) * 768 + lsw;
    }

    const int sw_  = (li & 7) << 4;
    const int swc0 = (lg * 16) ^ sw_;
    const int swc1 = (64 | (lg * 16)) ^ sw_;

#define STAGE_T(Tt, buf) do {                                                        \
        char* d_ = lds + (buf) * 65536;                                              \
        _Pragma("unroll")                                                            \
        for (int h_ = 0; h_ < 4; ++h_)                                               \
            glds16(abase[h_] + (Tt) * 64, d_ + (h_ * 64 + w * 8) * 128);             \
        _Pragma("unroll")                                                            \
        for (int h_ = 0; h_ < 4; ++h_)                                               \
            glds16(bbase[h_] + (Tt) * 64, d_ + 32768 + (h_ * 64 + w * 8) * 128);     \
    } while (0)

    f32x4 acc[8][4] = {};
    bf16x8 aF[8], bF[4];

#define READ_K(sw)                                                                   \
    _Pragma("unroll") for (int mf = 0; mf < 8; ++mf)                                 \
        aF[mf] = *(const bf16x8*)(bufA + (size_t)(wr * 128 + mf * 16 + li) * 128 + (sw)); \
    _Pragma("unroll") for (int nf = 0; nf < 4; ++nf)                                 \
        bF[nf] = *(const bf16x8*)(bufB + (size_t)(wc * 64 + nf * 16 + li) * 128 + (sw));

#define MFMA_K()                                                                     \
    _Pragma("unroll") for (int mf = 0; mf < 8; ++mf)                                 \
    _Pragma("unroll") for (int nf = 0; nf < 4; ++nf)                                 \
        acc[mf][nf] = MFMA16(aF[mf], bF[nf], acc[mf][nf]);

    STAGE_T(0, 0);
    STAGE_T(1, 1);
    asm volatile("s_waitcnt vmcnt(8)" ::: "memory");
    __builtin_amdgcn_s_barrier();
    __builtin_amdgcn_sched_barrier(0);

    #pragma unroll
    for (int T = 0; T < 12; ++T) {
        const char* bufA = lds + (T & 1) * 65536;
        const char* bufB = bufA + 32768;
        if (T >= 1 && T < 11) STAGE_T(T + 1, (T + 1) & 1);
        READ_K(swc0);
        __builtin_amdgcn_s_setprio(1);
        MFMA_K();
        __builtin_amdgcn_s_setprio(0);
        READ_K(swc1);
        __builtin_amdgcn_s_setprio(1);
        MFMA_K();
        __builtin_amdgcn_s_setprio(0);
        asm volatile("s_waitcnt lgkmcnt(0)" ::: "memory");
        if (T < 11) asm volatile("s_waitcnt vmcnt(0)" ::: "memory");
        __builtin_amdgcn_s_barrier();
        __builtin_amdgcn_sched_barrier(0);
    }
#undef STAGE_T
#undef READ_K
#undef MFMA_K

    #pragma unroll
    for (int mf = 0; mf < 8; ++mf) {
        const int row0 = bm * 256 + wr * 128 + mf * 16 + lg * 4;
        #pragma unroll
        for (int nf = 0; nf < 4; ++nf) {
            const int col = bn * 256 + wc * 64 + nf * 16 + li;
            #pragma unroll
            for (int r = 0; r < 4; ++r) {
                const int row = row0 + r;
                if (row < Mv)
                    C[(size_t)row * ldc + col] = (bf16)acc[mf][nf][r];
            }
        }
    }
}

// ---------------- final projection GEMM (r8 structure, f32 + bias out) ----------------
__global__ __launch_bounds__(512, 2) void gemmF(const bf16* __restrict__ A,
                                                const bf16* __restrict__ Bw,
                                                float* __restrict__ Cptr,
                                                const float* __restrict__ bias,
                                                int nbn, int Mvalid, int Aclamp) {
    extern __shared__ char lds[];
    const int nwg = gridDim.x;
    const int xcd = blockIdx.x & 7, loc = blockIdx.x >> 3;
    const int q8 = nwg >> 3, r8 = nwg & 7;
    const int wgid = (xcd < r8 ? xcd * (q8 + 1) : r8 * (q8 + 1) + (xcd - r8) * q8) + loc;
    const int bm = wgid / nbn, bn = wgid % nbn;

    const int tid = threadIdx.x, lane = tid & 63, w = tid >> 6;
    const int li = lane & 15, lg = lane >> 4;
    const int wr = w >> 2, wc = w & 3;
    const int lr  = lane >> 3;
    const int lsw = ((lane & 7) ^ lr) << 3;
    const bf16* Agp = A  + (size_t)bm * 256 * 768;
    const bf16* Bgp = Bw + (size_t)bn * 256 * 768;
    const int clampA = Aclamp - bm * 256;

    const int sw_  = (li & 7) << 4;
    const int swc0 = (lg * 16) ^ sw_;
    const int swc1 = (64 | (lg * 16)) ^ sw_;

#define STAGE_T(Tt, buf) do {                                                        \
        char* d_ = lds + (buf) * 65536;                                              \
        _Pragma("unroll")                                                            \
        for (int h_ = 0; h_ < 4; ++h_) {                                             \
            const int r0_ = h_ * 64 + w * 8;                                         \
            int gr_ = r0_ + lr; if (gr_ >= clampA) gr_ = clampA - 1;                 \
            glds16(Agp + (size_t)gr_ * 768 + (Tt) * 64 + lsw, d_ + r0_ * 128);       \
        }                                                                            \
        _Pragma("unroll")                                                            \
        for (int h_ = 0; h_ < 4; ++h_) {                                             \
            const int r0_ = h_ * 64 + w * 8;                                         \
            glds16(Bgp + (size_t)(r0_ + lr) * 768 + (Tt) * 64 + lsw,                 \
                   d_ + 32768 + r0_ * 128);                                          \
        } } while (0)

    f32x4 acc[8][4] = {};
    bf16x8 aF[8], bF[4];

#define READ_K(sw)                                                                   \
    _Pragma("unroll") for (int mf = 0; mf < 8; ++mf)                                 \
        aF[mf] = *(const bf16x8*)(bufA + (size_t)(wr * 128 + mf * 16 + li) * 128 + (sw)); \
    _Pragma("unroll") for (int nf = 0; nf < 4; ++nf)                                 \
        bF[nf] = *(const bf16x8*)(bufB + (size_t)(wc * 64 + nf * 16 + li) * 128 + (sw));

#define MFMA_K()                                                                     \
    _Pragma("unroll") for (int mf = 0; mf < 8; ++mf)                                 \
    _Pragma("unroll") for (int nf = 0; nf < 4; ++nf)                                 \
        acc[mf][nf] = MFMA16(aF[mf], bF[nf], acc[mf][nf]);

    STAGE_T(0, 0);
    STAGE_T(1, 1);
    asm volatile("s_waitcnt vmcnt(8)" ::: "memory");
    __builtin_amdgcn_s_barrier();
    __builtin_amdgcn_sched_barrier(0);

    #pragma unroll
    for (int T = 0; T < 12; ++T) {
        const char* bufA = lds + (T & 1) * 65536;
        const char* bufB = bufA + 32768;
        if (T >= 1 && T < 11) STAGE_T(T + 1, (T + 1) & 1);
        READ_K(swc0);
        __builtin_amdgcn_s_setprio(1);
        MFMA_K();
        __builtin_amdgcn_s_setprio(0);
        READ_K(swc1);
        __builtin_amdgcn_s_setprio(1);
        MFMA_K();
        __builtin_amdgcn_s_setprio(0);
        asm volatile("s_waitcnt lgkmcnt(0)" ::: "memory");
        if (T < 11) asm volatile("s_waitcnt vmcnt(0)" ::: "memory");
        __builtin_amdgcn_s_barrier();
        __builtin_amdgcn_sched_barrier(0);
    }
#undef STAGE_T
#undef READ_K
#undef MFMA_K

    #pragma unroll
    for (int mf = 0; mf < 8; ++mf) {
        const int row0 = bm * 256 + wr * 128 + mf * 16 + lg * 4;
        #pragma unroll
        for (int nf = 0; nf < 4; ++nf) {
            const int col = bn * 256 + wc * 64 + nf * 16 + li;
            #pragma unroll
            for (int r = 0; r < 4; ++r) {
                const int row = row0 + r;
                if (row < Mvalid)
                    Cptr[(size_t)row * 768 + col] = acc[mf][nf][r] + bias[col];
            }
        }
    }
}

// ---------------- depthwise 3x3x3 pool + LayerNorm(hd), vectorized ----------------
// COMPACT: source is the gathered-KV layout [CB*3201][SRCSTRIDE] where per-batch
// token (t, ih=4a+dh-1, iw=4b+dw-1) lives at row b*3201 + 1 + t*400 + hi*20 + wi,
// hi = 3*oh+dh-1, wi = 3*ow+dw-1 (cls at row b*3201).
template<int S, int OH, int OW, int CH, int NP, int NPpad, int SRCSTRIDE, bool COMPACT>
__global__ __launch_bounds__(256) void pool_norm2(const bf16* __restrict__ P,
                                                  const float* __restrict__ wt,
                                                  const float* __restrict__ gamma,
                                                  const float* __restrict__ beta,
                                                  bf16* __restrict__ outp,
                                                  float outScale) {
    constexpr int TASKS = TT * OH * CH + 1;
    const int w = threadIdx.x >> 6, lane = threadIdx.x & 63;
    const int gw = blockIdx.x * 4 + w;
    const int bh = gw / TASKS, task = gw % TASKS;
    const int b = bh / NH, head = bh % NH;
    const int owg = lane >> 3, cg = lane & 7, c = cg * 8;
    const size_t rowbase = COMPACT ? (size_t)b * CTOK : (size_t)b * NTOK;
    const size_t pbase = rowbase * SRCSTRIDE + head * HD + c;

    if (task == TASKS - 1) {
        if (owg == 0) {
            bf16x8 v = *(const bf16x8*)(P + pbase);
            float a[8];
            #pragma unroll
            for (int e = 0; e < 8; ++e) a[e] = (float)v[e];
            float s = 0;
            #pragma unroll
            for (int e = 0; e < 8; ++e) s += a[e];
            s += __shfl_xor(s, 1); s += __shfl_xor(s, 2); s += __shfl_xor(s, 4);
            const float mu = s * 0.015625f;
            float v2 = 0;
            #pragma unroll
            for (int e = 0; e < 8; ++e) { float d = a[e] - mu; v2 += d * d; }
            v2 += __shfl_xor(v2, 1); v2 += __shfl_xor(v2, 2); v2 += __shfl_xor(v2, 4);
            const float rs = rsqrtf(v2 * 0.015625f + 1e-5f);
            f32x4 g0 = *(const f32x4*)(gamma + c), g1 = *(const f32x4*)(gamma + c + 4);
            f32x4 b0 = *(const f32x4*)(beta + c),  b1 = *(const f32x4*)(beta + c + 4);
            bf16x8 o;
            #pragma unroll
            for (int e = 0; e < 4; ++e) {
                o[e]     = (bf16)(((a[e]     - mu) * rs * g0[e] + b0[e]) * outScale);
                o[4 + e] = (bf16)(((a[4 + e] - mu) * rs * g1[e] + b1[e]) * outScale);
            }
            *(bf16x8*)(outp + ((size_t)bh * NPpad) * HD + c) = o;
        } else {
            bf16x8 z = {};
            for (int p = NP + owg - 1; p < NPpad; p += 7)
                *(bf16x8*)(outp + ((size_t)bh * NPpad + p) * HD + c) = z;
        }
        return;
    }

    const int t  = task / (OH * CH);
    const int r2 = task % (OH * CH);
    const int oh = r2 / CH;
    const int ow = (r2 % CH) * 8 + owg;
    const bool active = (ow < OW);

    float acc[8] = {0, 0, 0, 0, 0, 0, 0, 0};
    #pragma unroll
    for (int dt = 0; dt < 3; ++dt) {
        const int it = t + dt - 1;
        if (it < 0 || it >= TT) continue;
        #pragma unroll
        for (int dh = 0; dh < 3; ++dh) {
            int rowh;
            if constexpr (COMPACT) {
                const int hi = 3 * oh + dh - 1;
                if (hi < 0) continue;
                rowh = 1 + it * 400 + hi * 20;
            } else {
                const int ih = oh * S + dh - 1;
                if (ih < 0 || ih >= HH) continue;
                rowh = 1 + (it * HH + ih) * WW;
            }
            #pragma unroll
            for (int dw = 0; dw < 3; ++dw) {
                int rowoff;
                bool ok;
                if constexpr (COMPACT) {
                    const int wi = 3 * ow + dw - 1;
                    ok = active && (wi >= 0);
                    rowoff = rowh + wi;
                } else {
                    const int iw = ow * S + dw - 1;
                    ok = active && (iw >= 0);
                    rowoff = rowh + iw;
                }
                if (ok) {
                    bf16x8 v = *(const bf16x8*)(P + pbase + (size_t)rowoff * SRCSTRIDE);
                    const float* wp = wt + ((dt * 3 + dh) * 3 + dw) * 64 + c;
                    f32x4 w0 = *(const f32x4*)wp, w1 = *(const f32x4*)(wp + 4);
                    #pragma unroll
                    for (int e = 0; e < 4; ++e) {
                        acc[e]     += w0[e] * (float)v[e];
                        acc[4 + e] += w1[e] * (float)v[4 + e];
                    }
                }
            }
        }
    }
    float s = 0;
    #pragma unroll
    for (int e = 0; e < 8; ++e) s += acc[e];
    s += __shfl_xor(s, 1); s += __shfl_xor(s, 2); s += __shfl_xor(s, 4);
    const float mu = s * 0.015625f;
    float v2 = 0;
    #pragma unroll
    for (int e = 0; e < 8; ++e) { float d = acc[e] - mu; v2 += d * d; }
    v2 += __shfl_xor(v2, 1); v2 += __shfl_xor(v2, 2); v2 += __shfl_xor(v2, 4);
    const float rs = rsqrtf(v2 * 0.015625f + 1e-5f);
    if (active) {
        f32x4 g0 = *(const f32x4*)(gamma + c), g1 = *(const f32x4*)(gamma + c + 4);
        f32x4 b0 = *(const f32x4*)(beta + c),  b1 = *(const f32x4*)(beta + c + 4);
        bf16x8 o;
        #pragma unroll
        for (int e = 0; e < 4; ++e) {
            o[e]     = (bf16)(((acc[e]     - mu) * rs * g0[e] + b0[e]) * outScale);
            o[4 + e] = (bf16)(((acc[4 + e] - mu) * rs * g1[e] + b1[e]) * outScale);
        }
        const int p = 1 + (t * OH + oh) * OW + ow;
        *(bf16x8*)(outp + ((size_t)bh * NPpad + p) * HD + c) = o;
    }
}

// ---------------- flash attention, fixed-max softmax ----------------
__global__ __launch_bounds__(256) void attn_kernel(const bf16* __restrict__ qn,
                                                   const bf16* __restrict__ kn,
                                                   const bf16* __restrict__ vn,
                                                   bf16* __restrict__ ob,
                                                   const float* __restrict__ Mptr) {
    __shared__ bf16 Kl[2][32][72];
    __shared__ bf16 Vt[2][64][40];
    __shared__ bf16 Pl[4][16][40];

    const int tid = threadIdx.x, l = tid & 63, w = tid >> 6;
    const int li = l & 15, lg = l >> 4;
    const int bh = blockIdx.y;
    const int b = bh / NH, head = bh % NH;
    const int qbase = blockIdx.x * 64 + w * 16;
    const float M = Mptr[0];

    const bf16* qp = qn + ((size_t)bh * NQP + qbase + li) * HD + lg * 8;
    const bf16x8 aq0 = *(const bf16x8*)qp;
    const bf16x8 aq1 = *(const bf16x8*)(qp + 32);

    const int srow = tid >> 3, scol = (tid & 7) * 8;
    const int sj = tid & 31, sd8 = tid >> 5;
    const bf16* kbase = kn + (size_t)bh * NKP * HD;
    const bf16* vbase = vn + (size_t)bh * NKP * HD;

    u32x4 kv = *(const u32x4*)(kbase + srow * HD + scol);
    u32x4 vv = *(const u32x4*)(vbase + sj * HD + sd8 * 8);
    *(u32x4*)&Kl[0][srow][scol] = kv;
    {
        bf16x8 t = __builtin_bit_cast(bf16x8, vv);
        #pragma unroll
        for (int e = 0; e < 8; ++e) Vt[0][sd8 * 8 + e][sj] = t[e];
    }

    f32x4 oacc[4] = {};
    float lpart[4] = {0.f, 0.f, 0.f, 0.f};

    for (int kt = 0; kt < 13; ++kt) {
        const int cur = kt & 1;
        if (kt < 12) {
            kv = *(const u32x4*)(kbase + (kt + 1) * 32 * HD + srow * HD + scol);
            vv = *(const u32x4*)(vbase + (kt + 1) * 32 * HD + sj * HD + sd8 * 8);
        }
        __syncthreads();

        f32x4 c0 = {}, c1 = {};
        const bf16x8 b00 = *(const bf16x8*)&Kl[cur][li][lg * 8];
        const bf16x8 b01 = *(const bf16x8*)&Kl[cur][li][32 + lg * 8];
        const bf16x8 b10 = *(const bf16x8*)&Kl[cur][16 + li][lg * 8];
        const bf16x8 b11 = *(const bf16x8*)&Kl[cur][16 + li][32 + lg * 8];
        __builtin_amdgcn_s_setprio(1);
        c0 = MFMA16(aq0, b00, c0); c0 = MFMA16(aq1, b01, c0);
        c1 = MFMA16(aq0, b10, c1); c1 = MFMA16(aq1, b11, c1);
        __builtin_amdgcn_s_setprio(0);

        float p0[4], p1[4];
        #pragma unroll
        for (int r = 0; r < 4; ++r) {
            p0[r] = __expf(c0[r] - M);
            p1[r] = __expf(c1[r] - M);
        }
        if (kt == 12) {
            const bool m0 = (384 + li) >= NK;
            #pragma unroll
            for (int r = 0; r < 4; ++r) { if (m0) p0[r] = 0.f; p1[r] = 0.f; }
        }
        #pragma unroll
        for (int r = 0; r < 4; ++r) {
            lpart[r] += p0[r] + p1[r];
            Pl[w][lg * 4 + r][li]      = (bf16)p0[r];
            Pl[w][lg * 4 + r][16 + li] = (bf16)p1[r];
        }
        const bf16x8 ap = *(const bf16x8*)&Pl[w][li][lg * 8];
        __builtin_amdgcn_s_setprio(1);
        #pragma unroll
        for (int dg = 0; dg < 4; ++dg) {
            const bf16x8 bv = *(const bf16x8*)&Vt[cur][dg * 16 + li][lg * 8];
            oacc[dg] = MFMA16(ap, bv, oacc[dg]);
        }
        __builtin_amdgcn_s_setprio(0);

        if (kt < 12) {
            const int nxt = cur ^ 1;
            *(u32x4*)&Kl[nxt][srow][scol] = kv;
            bf16x8 t = __builtin_bit_cast(bf16x8, vv);
            #pragma unroll
            for (int e = 0; e < 8; ++e) Vt[nxt][sd8 * 8 + e][sj] = t[e];
        }
    }
    #pragma unroll
    for (int r = 0; r < 4; ++r) {
        float lsum = lpart[r];
        lsum += __shfl_xor(lsum, 1);
        lsum += __shfl_xor(lsum, 2);
        lsum += __shfl_xor(lsum, 4);
        lsum += __shfl_xor(lsum, 8);
        const int q = qbase + lg * 4 + r;
        if (q < NQ) {
            const float inv = 1.f / lsum;
            const size_t off = ((size_t)(b * NQ + q)) * CC + head * HD;
            #pragma unroll
            for (int dg = 0; dg < 4; ++dg)
                ob[off + dg * 16 + li] = (bf16)(oacc[dg][r] * inv);
        }
    }
}

// ---------------- launcher ----------------
extern "C" void kernel_launch(void* const* d_in, const int* in_sizes, int n_in,
                              void* d_out, int out_size, void* d_ws, size_t ws_size,
                              hipStream_t stream) {
    const float* x     = (const float*)d_in[0];
    const float* Wq    = (const float*)d_in[1];
    const float* Wk    = (const float*)d_in[2];
    const float* Wv    = (const float*)d_in[3];
    const float* Wproj = (const float*)d_in[4];
    const float* bproj = (const float*)d_in[5];
    const float* pqw   = (const float*)d_in[6];
    const float* pkw   = (const float*)d_in[7];
    const float* pvw   = (const float*)d_in[8];
    const float* gq    = (const float*)d_in[9];
    const float* bq    = (const float*)d_in[10];
    const float* gk    = (const float*)d_in[11];
    const float* bk    = (const float*)d_in[12];
    const float* gv    = (const float*)d_in[13];
    const float* bv    = (const float*)d_in[14];

    if (ws_size < 364000000ULL) return;
    char* ws = (char*)d_ws;
    bf16* xb    = (bf16*)(ws);               // [50304][768]    77,266,944
    bf16* wqkv  = (bf16*)(ws + 77266944);    // [2304][768]      3,538,944
    bf16* wpb   = (bf16*)(ws + 80805888);    // [768][768]       1,179,648
    bf16* tmpq  = (bf16*)(ws + 81985536);    // [50304][768]    77,266,944
    bf16* tmpkv = (bf16*)(ws + 159252480);   // [25856][1536]   79,429,632
    bf16* qn    = (bf16*)(ws + 238682112);   // [96][1600][64]  19,660,800
    bf16* kn    = (bf16*)(ws + 258342912);   // [96][416][64]    5,111,808
    bf16* vnb   = (bf16*)(ws + 263454720);   // [96][416][64]    5,111,808
    bf16* ob    = (bf16*)(ws + 268566528);   // [12672][768]    19,464,192
    float* wt   = (float*)(ws + 288030720);  // [3][27][64] f32     20,736
    float* Mb   = (float*)(ws + 288051456);  // [1]

    const int WSZ = 589824;  // 768*768

    (void)hipFuncSetAttribute((const void*)gemmU,
                              hipFuncAttributeMaxDynamicSharedMemorySize, 131072);
    (void)hipFuncSetAttribute((const void*)gemmF,
                              hipFuncAttributeMaxDynamicSharedMemorySize, 131072);

    transpose_w3<<<21, 256, 0, stream>>>(pqw, pkw, pvw, wt);
    bound_kernel<<<1, 64, 0, stream>>>(gq, bq, gk, bk, Mb);
    cast_f32_bf16<<<4096, 256, 0, stream>>>(x, xb, MX * CC, MXP * CC);
    cast_f32_bf16<<<576, 256, 0, stream>>>(Wq, wqkv,            WSZ, WSZ);
    cast_f32_bf16<<<576, 256, 0, stream>>>(Wk, wqkv + WSZ,      WSZ, WSZ);
    cast_f32_bf16<<<576, 256, 0, stream>>>(Wv, wqkv + 2 * WSZ,  WSZ, WSZ);
    cast_f32_bf16<<<576, 256, 0, stream>>>(Wproj, wpb,          WSZ, WSZ);

    // unified projection: Q (591 blocks, all tokens) + KV (606 blocks, gathered)
    gemmU<<<1197, 512, 131072, stream>>>(xb, wqkv, tmpq, tmpkv);

    // pools: q from tmpq (full layout), k/v from compact tmpkv
    pool_norm2<2, 14, 14, 2, NQ, NQP, 768,  false><<<5400, 256, 0, stream>>>(tmpq,        wt,        gq, bq, qn,  0.125f);
    pool_norm2<4, 7, 7, 1, NK, NKP, 1536, true ><<<1368, 256, 0, stream>>>(tmpkv,       wt + 1728, gk, bk, kn,  1.0f);
    pool_norm2<4, 7, 7, 1, NK, NKP, 1536, true ><<<1368, 256, 0, stream>>>(tmpkv + 768, wt + 3456, gv, bv, vnb, 1.0f);

    attn_kernel<<<dim3(25, 96), 256, 0, stream>>>(qn, kn, vnb, ob, Mb);

    gemmF<<<50 * 3, 512, 131072, stream>>>(ob, wpb, (float*)d_out, bproj, 3, MO, MOP);
}

// Round 10
// 352.897 us; speedup vs baseline: 2.2380x; 1.0206x over previous
//
#include <hip/hip_runtime.h>

using bf16   = __bf16;
using bf16x4 = __attribute__((ext_vector_type(4))) __bf16;
using bf16x8 = __attribute__((ext_vector_type(8))) __bf16;
using f32x4  = __attribute__((ext_vector_type(4))) float;
using u32x4  = __attribute__((ext_vector_type(4))) unsigned int;

#define MFMA16(a,b,c) __builtin_amdgcn_mfma_f32_16x16x32_bf16((a),(b),(c),0,0,0)

__device__ inline void glds16(const void* g, void* l) {
    __builtin_amdgcn_global_load_lds(
        (__attribute__((address_space(1))) void*)(const_cast<void*>(g)),
        (__attribute__((address_space(3))) void*)(l), 16, 0, 0);
}

// bijective XCD-chunked remap (m204): contiguous chunk of blocks per XCD
__device__ inline int xcd_remap(int bid, int nwg) {
    const int xcd = bid & 7, loc = bid >> 3;
    const int q8 = nwg >> 3, r8 = nwg & 7;
    return (xcd < r8 ? xcd * (q8 + 1) : r8 * (q8 + 1) + (xcd - r8) * q8) + loc;
}

// ---------------- constants (problem-instance fixed) ----------------
constexpr int CB   = 8;
constexpr int NH   = 12;
constexpr int CC   = 768;
constexpr int HD   = 64;
constexpr int TT   = 8, HH = 28, WW = 28;
constexpr int NTOK = TT*HH*WW + 1;      // 6273
constexpr int MX   = CB*NTOK;           // 50184
constexpr int MXP  = 50304;
constexpr int NQ   = 1569, NQP = 1600;
constexpr int NK   = 393,  NKP = 416;
constexpr int MO   = CB*NQ;             // 12552
constexpr int MOP  = 12672;
constexpr int CTOK = 1 + TT*20*20;      // 3201 per batch (compact KV tokens)
constexpr int MKV  = CB*CTOK;           // 25608
constexpr int MKVP = 25856;

// ---------------- f32 -> bf16 cast (with zero tail pad) ----------------
__global__ __launch_bounds__(256) void cast_f32_bf16(const float* __restrict__ src,
                                                     bf16* __restrict__ dst,
                                                     int nvalid, int ntotal) {
    int i = (blockIdx.x * 256 + threadIdx.x) * 4;
    int stride = gridDim.x * 256 * 4;
    for (; i < ntotal; i += stride) {
        bf16x4 o;
        if (i + 3 < nvalid) {
            f32x4 v = *(const f32x4*)(src + i);
            #pragma unroll
            for (int e = 0; e < 4; ++e) o[e] = (bf16)v[e];
        } else {
            #pragma unroll
            for (int e = 0; e < 4; ++e) {
                int k = i + e;
                o[e] = (bf16)((k < nvalid) ? src[k] : 0.f);
            }
        }
        *(bf16x4*)(dst + i) = o;
    }
}

// ---------------- merged weight cast: Wq|Wk|Wv|Wproj -> contiguous bf16 ----------------
__global__ __launch_bounds__(256) void cast_w4(const float* __restrict__ w0,
                                               const float* __restrict__ w1,
                                               const float* __restrict__ w2,
                                               const float* __restrict__ w3,
                                               bf16* __restrict__ dst) {
    constexpr int WSZ = 589824;
    int i = (blockIdx.x * 256 + threadIdx.x) * 4;
    if (i >= 4 * WSZ) return;
    const int setn = i / WSZ, j = i % WSZ;
    const float* src = (setn == 0) ? w0 : (setn == 1) ? w1 : (setn == 2) ? w2 : w3;
    f32x4 v = *(const f32x4*)(src + j);
    bf16x4 o;
    #pragma unroll
    for (int e = 0; e < 4; ++e) o[e] = (bf16)v[e];
    *(bf16x4*)(dst + i) = o;
}

// ---------------- weight transpose: (64,27) -> [27][64], 3 sets ----------------
__global__ __launch_bounds__(256) void transpose_w3(const float* __restrict__ w0,
                                                    const float* __restrict__ w1,
                                                    const float* __restrict__ w2,
                                                    float* __restrict__ wt) {
    int i = blockIdx.x * 256 + threadIdx.x;
    if (i >= 3 * 1728) return;
    int setn = i / 1728, j = i % 1728;
    const float* src = (setn == 0) ? w0 : (setn == 1) ? w1 : w2;
    int tap = j / 64, c = j % 64;
    wt[i] = src[c * 27 + tap];
}

// ---------------- score-bound kernel: M = 0.125 * Bq * Bk ----------------
__global__ void bound_kernel(const float* __restrict__ gq, const float* __restrict__ bq,
                             const float* __restrict__ gk, const float* __restrict__ bk,
                             float* __restrict__ out) {
    const int c = threadIdx.x;   // 64 threads
    float mgq = fabsf(gq[c]), sbq = bq[c] * bq[c];
    float mgk = fabsf(gk[c]), sbk = bk[c] * bk[c];
    #pragma unroll
    for (int m = 1; m < 64; m <<= 1) {
        mgq = fmaxf(mgq, __shfl_xor(mgq, m)); sbq += __shfl_xor(sbq, m);
        mgk = fmaxf(mgk, __shfl_xor(mgk, m)); sbk += __shfl_xor(sbk, m);
    }
    if (c == 0) {
        const float Bq = 8.f * mgq + sqrtf(sbq);
        const float Bk = 8.f * mgk + sqrtf(sbk);
        out[0] = 0.125f * Bq * Bk;
    }
}

// ---------------- unified Q + gathered-KV projection GEMM (r9, unchanged) ----------------
__global__ __launch_bounds__(512, 2) void gemmU(const bf16* __restrict__ xb,
                                                const bf16* __restrict__ wqkv,
                                                bf16* __restrict__ tmpq,
                                                bf16* __restrict__ tmpkv) {
    extern __shared__ char lds[];
    const int wgid = xcd_remap(blockIdx.x, gridDim.x);   // 1197

    const int tid = threadIdx.x, lane = tid & 63, w = tid >> 6;
    const int li = lane & 15, lg = lane >> 4;
    const int wr = w >> 2, wc = w & 3;
    const int lr  = lane >> 3;
    const int lsw = ((lane & 7) ^ lr) << 3;

    const bool isQ = wgid < 591;
    int bm, bn, Mv, ldc;
    const bf16* Bb;
    bf16* C;
    if (isQ) { bm = wgid / 3;        bn = wgid % 3;        Mv = MXP;  ldc = 768;
               Bb = wqkv + (size_t)bn * 256 * 768;               C = tmpq; }
    else     { int t = wgid - 591;   bm = t / 6; bn = t % 6; Mv = MKVP; ldc = 1536;
               Bb = wqkv + (size_t)(768 + bn * 256) * 768;       C = tmpkv; }

    const bf16* abase[4];
    const bf16* bbase[4];
    #pragma unroll
    for (int h_ = 0; h_ < 4; ++h_) {
        int gr = bm * 256 + h_ * 64 + w * 8 + lr;
        size_t orig;
        if (isQ) {
            if (gr > MXP - 1) gr = MXP - 1;
            orig = (size_t)gr;
        } else {
            if (gr > MKV - 1) gr = MKV - 1;
            const unsigned b = (unsigned)gr / 3201u;
            const unsigned p = (unsigned)gr % 3201u;
            if (p == 0) orig = (size_t)b * NTOK;
            else {
                const unsigned q  = p - 1;
                const unsigned t2 = q / 400u, rem = q % 400u;
                const unsigned hi = rem / 20u, wi = rem % 20u;
                const int ih = 4 * (int)((hi + 1) / 3) + (int)((hi + 1) % 3) - 1;
                const int iw = 4 * (int)((wi + 1) / 3) + (int)((wi + 1) % 3) - 1;
                orig = (size_t)b * NTOK + 1 + ((size_t)t2 * HH + ih) * WW + iw;
            }
        }
        abase[h_] = xb + orig * 768 + lsw;
        bbase[h_] = Bb + (size_t)(h_ * 64 + w * 8 + lr) * 768 + lsw;
    }

    const int sw_  = (li & 7) << 4;
    const int swc0 = (lg * 16) ^ sw_;
    const int swc1 = (64 | (lg * 16)) ^ sw_;

#define STAGE_T(Tt, buf) do {                                                        \
        char* d_ = lds + (buf) * 65536;                                              \
        _Pragma("unroll")                                                            \
        for (int h_ = 0; h_ < 4; ++h_)                                               \
            glds16(abase[h_] + (Tt) * 64, d_ + (h_ * 64 + w * 8) * 128);             \
        _Pragma("unroll")                                                            \
        for (int h_ = 0; h_ < 4; ++h_)                                               \
            glds16(bbase[h_] + (Tt) * 64, d_ + 32768 + (h_ * 64 + w * 8) * 128);     \
    } while (0)

    f32x4 acc[8][4] = {};
    bf16x8 aF[8], bF[4];

#define READ_K(sw)                                                                   \
    _Pragma("unroll") for (int mf = 0; mf < 8; ++mf)                                 \
        aF[mf] = *(const bf16x8*)(bufA + (size_t)(wr * 128 + mf * 16 + li) * 128 + (sw)); \
    _Pragma("unroll") for (int nf = 0; nf < 4; ++nf)                                 \
        bF[nf] = *(const bf16x8*)(bufB + (size_t)(wc * 64 + nf * 16 + li) * 128 + (sw));

#define MFMA_K()                                                                     \
    _Pragma("unroll") for (int mf = 0; mf < 8; ++mf)                                 \
    _Pragma("unroll") for (int nf = 0; nf < 4; ++nf)                                 \
        acc[mf][nf] = MFMA16(aF[mf], bF[nf], acc[mf][nf]);

    STAGE_T(0, 0);
    STAGE_T(1, 1);
    asm volatile("s_waitcnt vmcnt(8)" ::: "memory");
    __builtin_amdgcn_s_barrier();
    __builtin_amdgcn_sched_barrier(0);

    #pragma unroll
    for (int T = 0; T < 12; ++T) {
        const char* bufA = lds + (T & 1) * 65536;
        const char* bufB = bufA + 32768;
        if (T >= 1 && T < 11) STAGE_T(T + 1, (T + 1) & 1);
        READ_K(swc0);
        __builtin_amdgcn_s_setprio(1);
        MFMA_K();
        __builtin_amdgcn_s_setprio(0);
        READ_K(swc1);
        __builtin_amdgcn_s_setprio(1);
        MFMA_K();
        __builtin_amdgcn_s_setprio(0);
        asm volatile("s_waitcnt lgkmcnt(0)" ::: "memory");
        if (T < 11) asm volatile("s_waitcnt vmcnt(0)" ::: "memory");
        __builtin_amdgcn_s_barrier();
        __builtin_amdgcn_sched_barrier(0);
    }
#undef STAGE_T
#undef READ_K
#undef MFMA_K

    #pragma unroll
    for (int mf = 0; mf < 8; ++mf) {
        const int row0 = bm * 256 + wr * 128 + mf * 16 + lg * 4;
        #pragma unroll
        for (int nf = 0; nf < 4; ++nf) {
            const int col = bn * 256 + wc * 64 + nf * 16 + li;
            #pragma unroll
            for (int r = 0; r < 4; ++r) {
                const int row = row0 + r;
                if (row < Mv)
                    C[(size_t)row * ldc + col] = (bf16)acc[mf][nf][r];
            }
        }
    }
}

// ---------------- final projection GEMM: 256x128 tile (300 blocks, f32+bias) ----------------
__global__ __launch_bounds__(512, 2) void gemmF(const bf16* __restrict__ A,
                                                const bf16* __restrict__ Bw,
                                                float* __restrict__ Cptr,
                                                const float* __restrict__ bias,
                                                int nbn, int Mvalid, int Aclamp) {
    extern __shared__ char lds[];
    const int wgid = xcd_remap(blockIdx.x, gridDim.x);
    const int bm = wgid / nbn, bn = wgid % nbn;

    const int tid = threadIdx.x, lane = tid & 63, w = tid >> 6;
    const int li = lane & 15, lg = lane >> 4;
    const int wr = w >> 2, wc = w & 3;
    const int lr  = lane >> 3;
    const int lsw = ((lane & 7) ^ lr) << 3;
    const bf16* Agp = A  + (size_t)bm * 256 * 768;
    const bf16* Bgp = Bw + (size_t)bn * 128 * 768;
    const int clampA = Aclamp - bm * 256;

    const int sw_  = (li & 7) << 4;
    const int swc0 = (lg * 16) ^ sw_;
    const int swc1 = (64 | (lg * 16)) ^ sw_;

#define STAGE_T(Tt, buf) do {                                                        \
        char* d_ = lds + (buf) * 49152;                                              \
        _Pragma("unroll")                                                            \
        for (int h_ = 0; h_ < 4; ++h_) {                                             \
            const int r0_ = h_ * 64 + w * 8;                                         \
            int gr_ = r0_ + lr; if (gr_ >= clampA) gr_ = clampA - 1;                 \
            glds16(Agp + (size_t)gr_ * 768 + (Tt) * 64 + lsw, d_ + r0_ * 128);       \
        }                                                                            \
        _Pragma("unroll")                                                            \
        for (int h_ = 0; h_ < 2; ++h_) {                                             \
            const int r0_ = h_ * 64 + w * 8;                                         \
            glds16(Bgp + (size_t)(r0_ + lr) * 768 + (Tt) * 64 + lsw,                 \
                   d_ + 32768 + r0_ * 128);                                          \
        } } while (0)

    f32x4 acc[8][2] = {};
    bf16x8 aF[8], bF[2];

#define READ_K(sw)                                                                   \
    _Pragma("unroll") for (int mf = 0; mf < 8; ++mf)                                 \
        aF[mf] = *(const bf16x8*)(bufA + (size_t)(wr * 128 + mf * 16 + li) * 128 + (sw)); \
    _Pragma("unroll") for (int nf = 0; nf < 2; ++nf)                                 \
        bF[nf] = *(const bf16x8*)(bufB + (size_t)(wc * 32 + nf * 16 + li) * 128 + (sw));

#define MFMA_K()                                                                     \
    _Pragma("unroll") for (int mf = 0; mf < 8; ++mf)                                 \
    _Pragma("unroll") for (int nf = 0; nf < 2; ++nf)                                 \
        acc[mf][nf] = MFMA16(aF[mf], bF[nf], acc[mf][nf]);

    STAGE_T(0, 0);
    STAGE_T(1, 1);
    asm volatile("s_waitcnt vmcnt(6)" ::: "memory");
    __builtin_amdgcn_s_barrier();
    __builtin_amdgcn_sched_barrier(0);

    #pragma unroll
    for (int T = 0; T < 12; ++T) {
        const char* bufA = lds + (T & 1) * 49152;
        const char* bufB = bufA + 32768;
        if (T >= 1 && T < 11) STAGE_T(T + 1, (T + 1) & 1);
        READ_K(swc0);
        __builtin_amdgcn_s_setprio(1);
        MFMA_K();
        __builtin_amdgcn_s_setprio(0);
        READ_K(swc1);
        __builtin_amdgcn_s_setprio(1);
        MFMA_K();
        __builtin_amdgcn_s_setprio(0);
        asm volatile("s_waitcnt lgkmcnt(0)" ::: "memory");
        if (T < 11) asm volatile("s_waitcnt vmcnt(0)" ::: "memory");
        __builtin_amdgcn_s_barrier();
        __builtin_amdgcn_sched_barrier(0);
    }
#undef STAGE_T
#undef READ_K
#undef MFMA_K

    #pragma unroll
    for (int mf = 0; mf < 8; ++mf) {
        const int row0 = bm * 256 + wr * 128 + mf * 16 + lg * 4;
        #pragma unroll
        for (int nf = 0; nf < 2; ++nf) {
            const int col = bn * 128 + wc * 32 + nf * 16 + li;
            #pragma unroll
            for (int r = 0; r < 4; ++r) {
                const int row = row0 + r;
                if (row < Mvalid)
                    Cptr[(size_t)row * 768 + col] = acc[mf][nf][r] + bias[col];
            }
        }
    }
}

// ---------------- depthwise 3x3x3 pool + LayerNorm(hd), XCD-chunked ----------------
template<int S, int OH, int OW, int CH, int NP, int NPpad, int SRCSTRIDE, bool COMPACT>
__global__ __launch_bounds__(256) void pool_norm2(const bf16* __restrict__ P,
                                                  const float* __restrict__ wt,
                                                  const float* __restrict__ gamma,
                                                  const float* __restrict__ beta,
                                                  bf16* __restrict__ outp,
                                                  float outScale) {
    constexpr int TASKS = TT * OH * CH + 1;
    const int w = threadIdx.x >> 6, lane = threadIdx.x & 63;
    const int gw = xcd_remap(blockIdx.x, gridDim.x) * 4 + w;  // T1: same-bh blocks on one XCD
    const int bh = gw / TASKS, task = gw % TASKS;
    const int b = bh / NH, head = bh % NH;
    const int owg = lane >> 3, cg = lane & 7, c = cg * 8;
    const size_t rowbase = COMPACT ? (size_t)b * CTOK : (size_t)b * NTOK;
    const size_t pbase = rowbase * SRCSTRIDE + head * HD + c;

    if (task == TASKS - 1) {
        if (owg == 0) {
            bf16x8 v = *(const bf16x8*)(P + pbase);
            float a[8];
            #pragma unroll
            for (int e = 0; e < 8; ++e) a[e] = (float)v[e];
            float s = 0;
            #pragma unroll
            for (int e = 0; e < 8; ++e) s += a[e];
            s += __shfl_xor(s, 1); s += __shfl_xor(s, 2); s += __shfl_xor(s, 4);
            const float mu = s * 0.015625f;
            float v2 = 0;
            #pragma unroll
            for (int e = 0; e < 8; ++e) { float d = a[e] - mu; v2 += d * d; }
            v2 += __shfl_xor(v2, 1); v2 += __shfl_xor(v2, 2); v2 += __shfl_xor(v2, 4);
            const float rs = rsqrtf(v2 * 0.015625f + 1e-5f);
            f32x4 g0 = *(const f32x4*)(gamma + c), g1 = *(const f32x4*)(gamma + c + 4);
            f32x4 b0 = *(const f32x4*)(beta + c),  b1 = *(const f32x4*)(beta + c + 4);
            bf16x8 o;
            #pragma unroll
            for (int e = 0; e < 4; ++e) {
                o[e]     = (bf16)(((a[e]     - mu) * rs * g0[e] + b0[e]) * outScale);
                o[4 + e] = (bf16)(((a[4 + e] - mu) * rs * g1[e] + b1[e]) * outScale);
            }
            *(bf16x8*)(outp + ((size_t)bh * NPpad) * HD + c) = o;
        } else {
            bf16x8 z = {};
            for (int p = NP + owg - 1; p < NPpad; p += 7)
                *(bf16x8*)(outp + ((size_t)bh * NPpad + p) * HD + c) = z;
        }
        return;
    }

    const int t  = task / (OH * CH);
    const int r2 = task % (OH * CH);
    const int oh = r2 / CH;
    const int ow = (r2 % CH) * 8 + owg;
    const bool active = (ow < OW);

    float acc[8] = {0, 0, 0, 0, 0, 0, 0, 0};
    #pragma unroll
    for (int dt = 0; dt < 3; ++dt) {
        const int it = t + dt - 1;
        if (it < 0 || it >= TT) continue;
        #pragma unroll
        for (int dh = 0; dh < 3; ++dh) {
            int rowh;
            if constexpr (COMPACT) {
                const int hi = 3 * oh + dh - 1;
                if (hi < 0) continue;
                rowh = 1 + it * 400 + hi * 20;
            } else {
                const int ih = oh * S + dh - 1;
                if (ih < 0 || ih >= HH) continue;
                rowh = 1 + (it * HH + ih) * WW;
            }
            #pragma unroll
            for (int dw = 0; dw < 3; ++dw) {
                int rowoff;
                bool ok;
                if constexpr (COMPACT) {
                    const int wi = 3 * ow + dw - 1;
                    ok = active && (wi >= 0);
                    rowoff = rowh + wi;
                } else {
                    const int iw = ow * S + dw - 1;
                    ok = active && (iw >= 0);
                    rowoff = rowh + iw;
                }
                if (ok) {
                    bf16x8 v = *(const bf16x8*)(P + pbase + (size_t)rowoff * SRCSTRIDE);
                    const float* wp = wt + ((dt * 3 + dh) * 3 + dw) * 64 + c;
                    f32x4 w0 = *(const f32x4*)wp, w1 = *(const f32x4*)(wp + 4);
                    #pragma unroll
                    for (int e = 0; e < 4; ++e) {
                        acc[e]     += w0[e] * (float)v[e];
                        acc[4 + e] += w1[e] * (float)v[4 + e];
                    }
                }
            }
        }
    }
    float s = 0;
    #pragma unroll
    for (int e = 0; e < 8; ++e) s += acc[e];
    s += __shfl_xor(s, 1); s += __shfl_xor(s, 2); s += __shfl_xor(s, 4);
    const float mu = s * 0.015625f;
    float v2 = 0;
    #pragma unroll
    for (int e = 0; e < 8; ++e) { float d = acc[e] - mu; v2 += d * d; }
    v2 += __shfl_xor(v2, 1); v2 += __shfl_xor(v2, 2); v2 += __shfl_xor(v2, 4);
    const float rs = rsqrtf(v2 * 0.015625f + 1e-5f);
    if (active) {
        f32x4 g0 = *(const f32x4*)(gamma + c), g1 = *(const f32x4*)(gamma + c + 4);
        f32x4 b0 = *(const f32x4*)(beta + c),  b1 = *(const f32x4*)(beta + c + 4);
        bf16x8 o;
        #pragma unroll
        for (int e = 0; e < 4; ++e) {
            o[e]     = (bf16)(((acc[e]     - mu) * rs * g0[e] + b0[e]) * outScale);
            o[4 + e] = (bf16)(((acc[4 + e] - mu) * rs * g1[e] + b1[e]) * outScale);
        }
        const int p = 1 + (t * OH + oh) * OW + ow;
        *(bf16x8*)(outp + ((size_t)bh * NPpad + p) * HD + c) = o;
    }
}

// ---------------- flash attention, fixed-max softmax, XCD-chunked ----------------
__global__ __launch_bounds__(256) void attn_kernel(const bf16* __restrict__ qn,
                                                   const bf16* __restrict__ kn,
                                                   const bf16* __restrict__ vn,
                                                   bf16* __restrict__ ob,
                                                   const float* __restrict__ Mptr) {
    __shared__ bf16 Kl[2][32][72];
    __shared__ bf16 Vt[2][64][40];
    __shared__ bf16 Pl[4][16][40];

    const int tid = threadIdx.x, l = tid & 63, w = tid >> 6;
    const int li = l & 15, lg = l >> 4;
    const int wgid = xcd_remap(blockIdx.x, gridDim.x);   // 2400: 12 bh per XCD chunk
    const int bh = wgid / 25;
    const int b = bh / NH, head = bh % NH;
    const int qbase = (wgid % 25) * 64 + w * 16;
    const float M = Mptr[0];

    const bf16* qp = qn + ((size_t)bh * NQP + qbase + li) * HD + lg * 8;
    const bf16x8 aq0 = *(const bf16x8*)qp;
    const bf16x8 aq1 = *(const bf16x8*)(qp + 32);

    const int srow = tid >> 3, scol = (tid & 7) * 8;
    const int sj = tid & 31, sd8 = tid >> 5;
    const bf16* kbase = kn + (size_t)bh * NKP * HD;
    const bf16* vbase = vn + (size_t)bh * NKP * HD;

    u32x4 kv = *(const u32x4*)(kbase + srow * HD + scol);
    u32x4 vv = *(const u32x4*)(vbase + sj * HD + sd8 * 8);
    *(u32x4*)&Kl[0][srow][scol] = kv;
    {
        bf16x8 t = __builtin_bit_cast(bf16x8, vv);
        #pragma unroll
        for (int e = 0; e < 8; ++e) Vt[0][sd8 * 8 + e][sj] = t[e];
    }

    f32x4 oacc[4] = {};
    float lpart[4] = {0.f, 0.f, 0.f, 0.f};

    for (int kt = 0; kt < 13; ++kt) {
        const int cur = kt & 1;
        if (kt < 12) {
            kv = *(const u32x4*)(kbase + (kt + 1) * 32 * HD + srow * HD + scol);
            vv = *(const u32x4*)(vbase + (kt + 1) * 32 * HD + sj * HD + sd8 * 8);
        }
        __syncthreads();

        f32x4 c0 = {}, c1 = {};
        const bf16x8 b00 = *(const bf16x8*)&Kl[cur][li][lg * 8];
        const bf16x8 b01 = *(const bf16x8*)&Kl[cur][li][32 + lg * 8];
        const bf16x8 b10 = *(const bf16x8*)&Kl[cur][16 + li][lg * 8];
        const bf16x8 b11 = *(const bf16x8*)&Kl[cur][16 + li][32 + lg * 8];
        __builtin_amdgcn_s_setprio(1);
        c0 = MFMA16(aq0, b00, c0); c0 = MFMA16(aq1, b01, c0);
        c1 = MFMA16(aq0, b10, c1); c1 = MFMA16(aq1, b11, c1);
        __builtin_amdgcn_s_setprio(0);

        float p0[4], p1[4];
        #pragma unroll
        for (int r = 0; r < 4; ++r) {
            p0[r] = __expf(c0[r] - M);
            p1[r] = __expf(c1[r] - M);
        }
        if (kt == 12) {
            const bool m0 = (384 + li) >= NK;
            #pragma unroll
            for (int r = 0; r < 4; ++r) { if (m0) p0[r] = 0.f; p1[r] = 0.f; }
        }
        #pragma unroll
        for (int r = 0; r < 4; ++r) {
            lpart[r] += p0[r] + p1[r];
            Pl[w][lg * 4 + r][li]      = (bf16)p0[r];
            Pl[w][lg * 4 + r][16 + li] = (bf16)p1[r];
        }
        const bf16x8 ap = *(const bf16x8*)&Pl[w][li][lg * 8];
        __builtin_amdgcn_s_setprio(1);
        #pragma unroll
        for (int dg = 0; dg < 4; ++dg) {
            const bf16x8 bv = *(const bf16x8*)&Vt[cur][dg * 16 + li][lg * 8];
            oacc[dg] = MFMA16(ap, bv, oacc[dg]);
        }
        __builtin_amdgcn_s_setprio(0);

        if (kt < 12) {
            const int nxt = cur ^ 1;
            *(u32x4*)&Kl[nxt][srow][scol] = kv;
            bf16x8 t = __builtin_bit_cast(bf16x8, vv);
            #pragma unroll
            for (int e = 0; e < 8; ++e) Vt[nxt][sd8 * 8 + e][sj] = t[e];
        }
    }
    #pragma unroll
    for (int r = 0; r < 4; ++r) {
        float lsum = lpart[r];
        lsum += __shfl_xor(lsum, 1);
        lsum += __shfl_xor(lsum, 2);
        lsum += __shfl_xor(lsum, 4);
        lsum += __shfl_xor(lsum, 8);
        const int q = qbase + lg * 4 + r;
        if (q < NQ) {
            const float inv = 1.f / lsum;
            const size_t off = ((size_t)(b * NQ + q)) * CC + head * HD;
            #pragma unroll
            for (int dg = 0; dg < 4; ++dg)
                ob[off + dg * 16 + li] = (bf16)(oacc[dg][r] * inv);
        }
    }
}

// ---------------- launcher ----------------
extern "C" void kernel_launch(void* const* d_in, const int* in_sizes, int n_in,
                              void* d_out, int out_size, void* d_ws, size_t ws_size,
                              hipStream_t stream) {
    const float* x     = (const float*)d_in[0];
    const float* Wq    = (const float*)d_in[1];
    const float* Wk    = (const float*)d_in[2];
    const float* Wv    = (const float*)d_in[3];
    const float* Wproj = (const float*)d_in[4];
    const float* bproj = (const float*)d_in[5];
    const float* pqw   = (const float*)d_in[6];
    const float* pkw   = (const float*)d_in[7];
    const float* pvw   = (const float*)d_in[8];
    const float* gq    = (const float*)d_in[9];
    const float* bq    = (const float*)d_in[10];
    const float* gk    = (const float*)d_in[11];
    const float* bk    = (const float*)d_in[12];
    const float* gv    = (const float*)d_in[13];
    const float* bv    = (const float*)d_in[14];

    if (ws_size < 364000000ULL) return;
    char* ws = (char*)d_ws;
    bf16* xb    = (bf16*)(ws);               // [50304][768]
    bf16* wqkv  = (bf16*)(ws + 77266944);    // [2304][768] (+wpb contiguous after)
    bf16* wpb   = (bf16*)(ws + 80805888);    // [768][768]
    bf16* tmpq  = (bf16*)(ws + 81985536);    // [50304][768]
    bf16* tmpkv = (bf16*)(ws + 159252480);   // [25856][1536]
    bf16* qn    = (bf16*)(ws + 238682112);   // [96][1600][64]
    bf16* kn    = (bf16*)(ws + 258342912);   // [96][416][64]
    bf16* vnb   = (bf16*)(ws + 263454720);   // [96][416][64]
    bf16* ob    = (bf16*)(ws + 268566528);   // [12672][768]
    float* wt   = (float*)(ws + 288030720);  // [3][27][64] f32
    float* Mb   = (float*)(ws + 288051456);  // [1]

    (void)hipFuncSetAttribute((const void*)gemmU,
                              hipFuncAttributeMaxDynamicSharedMemorySize, 131072);
    (void)hipFuncSetAttribute((const void*)gemmF,
                              hipFuncAttributeMaxDynamicSharedMemorySize, 98304);

    transpose_w3<<<21, 256, 0, stream>>>(pqw, pkw, pvw, wt);
    bound_kernel<<<1, 64, 0, stream>>>(gq, bq, gk, bk, Mb);
    cast_f32_bf16<<<4096, 256, 0, stream>>>(x, xb, MX * CC, MXP * CC);
    cast_w4<<<2304, 256, 0, stream>>>(Wq, Wk, Wv, Wproj, wqkv);  // 4*589824/1024

    // unified projection: Q (591 blocks, all tokens) + KV (606 blocks, gathered)
    gemmU<<<1197, 512, 131072, stream>>>(xb, wqkv, tmpq, tmpkv);

    // pools: q from tmpq (full layout), k/v from compact tmpkv — all XCD-chunked
    pool_norm2<2, 14, 14, 2, NQ, NQP, 768,  false><<<5400, 256, 0, stream>>>(tmpq,        wt,        gq, bq, qn,  0.125f);
    pool_norm2<4, 7, 7, 1, NK, NKP, 1536, true ><<<1368, 256, 0, stream>>>(tmpkv,       wt + 1728, gk, bk, kn,  1.0f);
    pool_norm2<4, 7, 7, 1, NK, NKP, 1536, true ><<<1368, 256, 0, stream>>>(tmpkv + 768, wt + 3456, gv, bv, vnb, 1.0f);

    attn_kernel<<<2400, 256, 0, stream>>>(qn, kn, vnb, ob, Mb);

    // final projection: 256x128 tiles, 300 blocks
    gemmF<<<50 * 6, 512, 98304, stream>>>(ob, wpb, (float*)d_out, bproj, 6, MO, MOP);
}

// Round 11
// 349.644 us; speedup vs baseline: 2.2588x; 1.0093x over previous
//
#include <hip/hip_runtime.h>

using bf16   = __bf16;
using bf16x4 = __attribute__((ext_vector_type(4))) __bf16;
using bf16x8 = __attribute__((ext_vector_type(8))) __bf16;
using f32x4  = __attribute__((ext_vector_type(4))) float;
using u32x4  = __attribute__((ext_vector_type(4))) unsigned int;

#define MFMA16(a,b,c) __builtin_amdgcn_mfma_f32_16x16x32_bf16((a),(b),(c),0,0,0)

__device__ inline void glds16(const void* g, void* l) {
    __builtin_amdgcn_global_load_lds(
        (__attribute__((address_space(1))) void*)(const_cast<void*>(g)),
        (__attribute__((address_space(3))) void*)(l), 16, 0, 0);
}

// bijective XCD-chunked remap (m204)
__device__ inline int xcd_remap(int bid, int nwg) {
    const int xcd = bid & 7, loc = bid >> 3;
    const int q8 = nwg >> 3, r8 = nwg & 7;
    return (xcd < r8 ? xcd * (q8 + 1) : r8 * (q8 + 1) + (xcd - r8) * q8) + loc;
}

// ---------------- constants (problem-instance fixed) ----------------
constexpr int CB   = 8;
constexpr int NH   = 12;
constexpr int CC   = 768;
constexpr int HD   = 64;
constexpr int TT   = 8, HH = 28, WW = 28;
constexpr int NTOK = TT*HH*WW + 1;      // 6273
constexpr int MX   = CB*NTOK;           // 50184
constexpr int MXP  = 50304;
constexpr int NQ   = 1569, NQP = 1600;
constexpr int NK   = 393,  NKP = 416;
constexpr int MO   = CB*NQ;             // 12552
constexpr int MOP  = 12672;
constexpr int CTOK = 1 + TT*20*20;      // 3201 per batch (compact KV tokens)
constexpr int MKV  = CB*CTOK;           // 25608
constexpr int MKVP = 25856;

// ---------------- f32 -> bf16 cast (with zero tail pad) ----------------
__global__ __launch_bounds__(256) void cast_f32_bf16(const float* __restrict__ src,
                                                     bf16* __restrict__ dst,
                                                     int nvalid, int ntotal) {
    int i = (blockIdx.x * 256 + threadIdx.x) * 4;
    int stride = gridDim.x * 256 * 4;
    for (; i < ntotal; i += stride) {
        bf16x4 o;
        if (i + 3 < nvalid) {
            f32x4 v = *(const f32x4*)(src + i);
            #pragma unroll
            for (int e = 0; e < 4; ++e) o[e] = (bf16)v[e];
        } else {
            #pragma unroll
            for (int e = 0; e < 4; ++e) {
                int k = i + e;
                o[e] = (bf16)((k < nvalid) ? src[k] : 0.f);
            }
        }
        *(bf16x4*)(dst + i) = o;
    }
}

// ---------------- merged weight cast: Wq|Wk|Wv|Wproj -> contiguous bf16 ----------------
__global__ __launch_bounds__(256) void cast_w4(const float* __restrict__ w0,
                                               const float* __restrict__ w1,
                                               const float* __restrict__ w2,
                                               const float* __restrict__ w3,
                                               bf16* __restrict__ dst) {
    constexpr int WSZ = 589824;
    int i = (blockIdx.x * 256 + threadIdx.x) * 4;
    if (i >= 4 * WSZ) return;
    const int setn = i / WSZ, j = i % WSZ;
    const float* src = (setn == 0) ? w0 : (setn == 1) ? w1 : (setn == 2) ? w2 : w3;
    f32x4 v = *(const f32x4*)(src + j);
    bf16x4 o;
    #pragma unroll
    for (int e = 0; e < 4; ++e) o[e] = (bf16)v[e];
    *(bf16x4*)(dst + i) = o;
}

// ---------------- weight transpose: (64,27) -> [27][64], 3 sets ----------------
__global__ __launch_bounds__(256) void transpose_w3(const float* __restrict__ w0,
                                                    const float* __restrict__ w1,
                                                    const float* __restrict__ w2,
                                                    float* __restrict__ wt) {
    int i = blockIdx.x * 256 + threadIdx.x;
    if (i >= 3 * 1728) return;
    int setn = i / 1728, j = i % 1728;
    const float* src = (setn == 0) ? w0 : (setn == 1) ? w1 : w2;
    int tap = j / 64, c = j % 64;
    wt[i] = src[c * 27 + tap];
}

// ---------------- score-bound kernel: M = 0.125 * Bq * Bk ----------------
__global__ void bound_kernel(const float* __restrict__ gq, const float* __restrict__ bq,
                             const float* __restrict__ gk, const float* __restrict__ bk,
                             float* __restrict__ out) {
    const int c = threadIdx.x;   // 64 threads
    float mgq = fabsf(gq[c]), sbq = bq[c] * bq[c];
    float mgk = fabsf(gk[c]), sbk = bk[c] * bk[c];
    #pragma unroll
    for (int m = 1; m < 64; m <<= 1) {
        mgq = fmaxf(mgq, __shfl_xor(mgq, m)); sbq += __shfl_xor(sbq, m);
        mgk = fmaxf(mgk, __shfl_xor(mgk, m)); sbk += __shfl_xor(sbk, m);
    }
    if (c == 0) {
        const float Bq = 8.f * mgq + sqrtf(sbq);
        const float Bk = 8.f * mgk + sqrtf(sbk);
        out[0] = 0.125f * Bq * Bk;
    }
}

// ---------------- unified Q + gathered-KV projection GEMM ----------------
// 256x256, BK=64, 2dbuf. m201-faithful 4-phase/K-tile schedule:
//  q0: read A0-sub(8)+B0-sub(4); stage A1(k+1);        barrier; lgkm0; 16 MFMA (m0,n0); barrier
//  q1: read B1-sub(4);                                  barrier; lgkm0; 16 MFMA (m0,n1); barrier
//  q2: read A1-sub(8); stage B0(k+2)+B1(k+2);           barrier; lgkm0; 16 MFMA (m1,n0); barrier
//  q3: stage A0(k+2);                                   barrier;        16 MFMA (m1,n1); vmcnt(6); barrier
// Counted vmcnt(6) = 3 half-tiles in flight (T4); never 0 in the main loop (k=10: 0).
// Slot safety: each LDS region re-written >=1 phase after its last ds-read
// (A-halves last read q2 -> staged q3/q0; B-halves last read q1 -> staged q2).
__global__ __launch_bounds__(512, 2) void gemmU(const bf16* __restrict__ xb,
                                                const bf16* __restrict__ wqkv,
                                                bf16* __restrict__ tmpq,
                                                bf16* __restrict__ tmpkv) {
    extern __shared__ char lds[];
    const int wgid = xcd_remap(blockIdx.x, gridDim.x);   // 1197

    const int tid = threadIdx.x, lane = tid & 63, w = tid >> 6;
    const int li = lane & 15, lg = lane >> 4;
    const int wr = w >> 2, wc = w & 3;
    const int lr  = lane >> 3;
    const int lsw = ((lane & 7) ^ lr) << 3;

    const bool isQ = wgid < 591;
    int bm, bn, Mv, ldc;
    const bf16* Bb;
    bf16* C;
    if (isQ) { bm = wgid / 3;        bn = wgid % 3;        Mv = MXP;  ldc = 768;
               Bb = wqkv + (size_t)bn * 256 * 768;               C = tmpq; }
    else     { int t = wgid - 591;   bm = t / 6; bn = t % 6; Mv = MKVP; ldc = 1536;
               Bb = wqkv + (size_t)(768 + bn * 256) * 768;       C = tmpkv; }

    // per-lane A/B row base pointers (fixed across K-tiles); KV rows gathered
    const bf16* abase[4];
    const bf16* bbase[4];
    #pragma unroll
    for (int h_ = 0; h_ < 4; ++h_) {
        int gr = bm * 256 + h_ * 64 + w * 8 + lr;
        size_t orig;
        if (isQ) {
            if (gr > MXP - 1) gr = MXP - 1;
            orig = (size_t)gr;
        } else {
            if (gr > MKV - 1) gr = MKV - 1;
            const unsigned b = (unsigned)gr / 3201u;
            const unsigned p = (unsigned)gr % 3201u;
            if (p == 0) orig = (size_t)b * NTOK;
            else {
                const unsigned q  = p - 1;
                const unsigned t2 = q / 400u, rem = q % 400u;
                const unsigned hi = rem / 20u, wi = rem % 20u;
                const int ih = 4 * (int)((hi + 1) / 3) + (int)((hi + 1) % 3) - 1;
                const int iw = 4 * (int)((wi + 1) / 3) + (int)((wi + 1) % 3) - 1;
                orig = (size_t)b * NTOK + 1 + ((size_t)t2 * HH + ih) * WW + iw;
            }
        }
        abase[h_] = xb + orig * 768 + lsw;
        bbase[h_] = Bb + (size_t)(h_ * 64 + w * 8 + lr) * 768 + lsw;
    }

    const int sw_  = (li & 7) << 4;
    const int swc0 = (lg * 16) ^ sw_;
    const int swc1 = (64 | (lg * 16)) ^ sw_;

// half-tile stage: 2 glds16/thread (= 128 rows x 64 cols bf16, 16 KB)
#define STAGE_AH(Tt, a) do {                                                         \
        char* d_ = lds + ((Tt) & 1) * 65536;                                         \
        glds16(abase[2*(a)]   + (size_t)(Tt) * 64, d_ + ((2*(a))   * 64 + w * 8) * 128); \
        glds16(abase[2*(a)+1] + (size_t)(Tt) * 64, d_ + ((2*(a)+1) * 64 + w * 8) * 128); \
    } while (0)
#define STAGE_BH(Tt, b) do {                                                         \
        char* d_ = lds + ((Tt) & 1) * 65536 + 32768;                                 \
        glds16(bbase[2*(b)]   + (size_t)(Tt) * 64, d_ + ((2*(b))   * 64 + w * 8) * 128); \
        glds16(bbase[2*(b)+1] + (size_t)(Tt) * 64, d_ + ((2*(b)+1) * 64 + w * 8) * 128); \
    } while (0)

    f32x4 acc[8][4] = {};
    bf16x8 aF[4][2], bF0[2][2], bF1[2][2];

#define READ_A(mh)                                                                   \
    _Pragma("unroll") for (int mf = 0; mf < 4; ++mf) {                               \
        const char* p_ = bufA + (size_t)(wr * 128 + (mh) * 64 + mf * 16 + li) * 128; \
        aF[mf][0] = *(const bf16x8*)(p_ + swc0);                                     \
        aF[mf][1] = *(const bf16x8*)(p_ + swc1); }
#define READ_B(nh, BF)                                                               \
    _Pragma("unroll") for (int nf = 0; nf < 2; ++nf) {                               \
        const char* p_ = bufB + (size_t)(wc * 64 + (nh) * 32 + nf * 16 + li) * 128;  \
        BF[nf][0] = *(const bf16x8*)(p_ + swc0);                                     \
        BF[nf][1] = *(const bf16x8*)(p_ + swc1); }
#define MFMA_PH(mh, nh, BF)                                                          \
    _Pragma("unroll") for (int mf = 0; mf < 4; ++mf)                                 \
    _Pragma("unroll") for (int nf = 0; nf < 2; ++nf) {                               \
        acc[(mh)*4+mf][(nh)*2+nf] = MFMA16(aF[mf][0], BF[nf][0], acc[(mh)*4+mf][(nh)*2+nf]); \
        acc[(mh)*4+mf][(nh)*2+nf] = MFMA16(aF[mf][1], BF[nf][1], acc[(mh)*4+mf][(nh)*2+nf]); }

    // prologue: 7 half-tiles (tile0 complete + B0,B1(1) + A0(1)); vmcnt(6) lands tile 0
    STAGE_BH(0, 0); STAGE_BH(0, 1); STAGE_AH(0, 0); STAGE_AH(0, 1);
    STAGE_BH(1, 0); STAGE_BH(1, 1); STAGE_AH(1, 0);
    asm volatile("s_waitcnt vmcnt(6)" ::: "memory");
    __builtin_amdgcn_s_barrier();

    #pragma unroll
    for (int k = 0; k < 12; ++k) {
        const char* bufA = lds + (k & 1) * 65536;
        const char* bufB = bufA + 32768;
        // ---- q0: quadrant (m0,n0)
        READ_A(0); READ_B(0, bF0);
        if (k < 11) STAGE_AH(k + 1, 1);
        __builtin_amdgcn_s_barrier();
        asm volatile("s_waitcnt lgkmcnt(0)" ::: "memory");
        __builtin_amdgcn_s_setprio(1);
        MFMA_PH(0, 0, bF0);
        __builtin_amdgcn_s_setprio(0);
        __builtin_amdgcn_s_barrier();
        // ---- q1: quadrant (m0,n1)
        READ_B(1, bF1);
        __builtin_amdgcn_s_barrier();
        asm volatile("s_waitcnt lgkmcnt(0)" ::: "memory");
        __builtin_amdgcn_s_setprio(1);
        MFMA_PH(0, 1, bF1);
        __builtin_amdgcn_s_setprio(0);
        __builtin_amdgcn_s_barrier();
        // ---- q2: quadrant (m1,n0)
        READ_A(1);
        if (k < 10) { STAGE_BH(k + 2, 0); STAGE_BH(k + 2, 1); }
        __builtin_amdgcn_s_barrier();
        asm volatile("s_waitcnt lgkmcnt(0)" ::: "memory");
        __builtin_amdgcn_s_setprio(1);
        MFMA_PH(1, 0, bF0);
        __builtin_amdgcn_s_setprio(0);
        __builtin_amdgcn_s_barrier();
        // ---- q3: quadrant (m1,n1); counted vmcnt (never 0 until epilogue)
        if (k < 10) STAGE_AH(k + 2, 0);
        __builtin_amdgcn_s_barrier();
        __builtin_amdgcn_s_setprio(1);
        MFMA_PH(1, 1, bF1);
        __builtin_amdgcn_s_setprio(0);
        if (k < 10)       asm volatile("s_waitcnt vmcnt(6)" ::: "memory");
        else if (k == 10) asm volatile("s_waitcnt vmcnt(0)" ::: "memory");
        __builtin_amdgcn_s_barrier();
    }
#undef STAGE_AH
#undef STAGE_BH
#undef READ_A
#undef READ_B
#undef MFMA_PH

    #pragma unroll
    for (int mf = 0; mf < 8; ++mf) {
        const int row0 = bm * 256 + wr * 128 + mf * 16 + lg * 4;
        #pragma unroll
        for (int nf = 0; nf < 4; ++nf) {
            const int col = bn * 256 + wc * 64 + nf * 16 + li;
            #pragma unroll
            for (int r = 0; r < 4; ++r) {
                const int row = row0 + r;
                if (row < Mv)
                    C[(size_t)row * ldc + col] = (bf16)acc[mf][nf][r];
            }
        }
    }
}

// ---------------- final projection GEMM: 256x128 tile (300 blocks, f32+bias) ----------------
__global__ __launch_bounds__(512, 2) void gemmF(const bf16* __restrict__ A,
                                                const bf16* __restrict__ Bw,
                                                float* __restrict__ Cptr,
                                                const float* __restrict__ bias,
                                                int nbn, int Mvalid, int Aclamp) {
    extern __shared__ char lds[];
    const int wgid = xcd_remap(blockIdx.x, gridDim.x);
    const int bm = wgid / nbn, bn = wgid % nbn;

    const int tid = threadIdx.x, lane = tid & 63, w = tid >> 6;
    const int li = lane & 15, lg = lane >> 4;
    const int wr = w >> 2, wc = w & 3;
    const int lr  = lane >> 3;
    const int lsw = ((lane & 7) ^ lr) << 3;
    const bf16* Agp = A  + (size_t)bm * 256 * 768;
    const bf16* Bgp = Bw + (size_t)bn * 128 * 768;
    const int clampA = Aclamp - bm * 256;

    const int sw_  = (li & 7) << 4;
    const int swc0 = (lg * 16) ^ sw_;
    const int swc1 = (64 | (lg * 16)) ^ sw_;

#define STAGE_T(Tt, buf) do {                                                        \
        char* d_ = lds + (buf) * 49152;                                              \
        _Pragma("unroll")                                                            \
        for (int h_ = 0; h_ < 4; ++h_) {                                             \
            const int r0_ = h_ * 64 + w * 8;                                         \
            int gr_ = r0_ + lr; if (gr_ >= clampA) gr_ = clampA - 1;                 \
            glds16(Agp + (size_t)gr_ * 768 + (Tt) * 64 + lsw, d_ + r0_ * 128);       \
        }                                                                            \
        _Pragma("unroll")                                                            \
        for (int h_ = 0; h_ < 2; ++h_) {                                             \
            const int r0_ = h_ * 64 + w * 8;                                         \
            glds16(Bgp + (size_t)(r0_ + lr) * 768 + (Tt) * 64 + lsw,                 \
                   d_ + 32768 + r0_ * 128);                                          \
        } } while (0)

    f32x4 acc[8][2] = {};
    bf16x8 aF[8], bF[2];

#define READ_K(sw)                                                                   \
    _Pragma("unroll") for (int mf = 0; mf < 8; ++mf)                                 \
        aF[mf] = *(const bf16x8*)(bufA + (size_t)(wr * 128 + mf * 16 + li) * 128 + (sw)); \
    _Pragma("unroll") for (int nf = 0; nf < 2; ++nf)                                 \
        bF[nf] = *(const bf16x8*)(bufB + (size_t)(wc * 32 + nf * 16 + li) * 128 + (sw));

#define MFMA_K()                                                                     \
    _Pragma("unroll") for (int mf = 0; mf < 8; ++mf)                                 \
    _Pragma("unroll") for (int nf = 0; nf < 2; ++nf)                                 \
        acc[mf][nf] = MFMA16(aF[mf], bF[nf], acc[mf][nf]);

    STAGE_T(0, 0);
    STAGE_T(1, 1);
    asm volatile("s_waitcnt vmcnt(6)" ::: "memory");
    __builtin_amdgcn_s_barrier();
    __builtin_amdgcn_sched_barrier(0);

    #pragma unroll
    for (int T = 0; T < 12; ++T) {
        const char* bufA = lds + (T & 1) * 49152;
        const char* bufB = bufA + 32768;
        if (T >= 1 && T < 11) STAGE_T(T + 1, (T + 1) & 1);
        READ_K(swc0);
        __builtin_amdgcn_s_setprio(1);
        MFMA_K();
        __builtin_amdgcn_s_setprio(0);
        READ_K(swc1);
        __builtin_amdgcn_s_setprio(1);
        MFMA_K();
        __builtin_amdgcn_s_setprio(0);
        asm volatile("s_waitcnt lgkmcnt(0)" ::: "memory");
        if (T < 11) asm volatile("s_waitcnt vmcnt(0)" ::: "memory");
        __builtin_amdgcn_s_barrier();
        __builtin_amdgcn_sched_barrier(0);
    }
#undef STAGE_T
#undef READ_K
#undef MFMA_K

    #pragma unroll
    for (int mf = 0; mf < 8; ++mf) {
        const int row0 = bm * 256 + wr * 128 + mf * 16 + lg * 4;
        #pragma unroll
        for (int nf = 0; nf < 2; ++nf) {
            const int col = bn * 128 + wc * 32 + nf * 16 + li;
            #pragma unroll
            for (int r = 0; r < 4; ++r) {
                const int row = row0 + r;
                if (row < Mvalid)
                    Cptr[(size_t)row * 768 + col] = acc[mf][nf][r] + bias[col];
            }
        }
    }
}

// ---------------- depthwise 3x3x3 pool + LayerNorm(hd), XCD-chunked ----------------
template<int S, int OH, int OW, int CH, int NP, int NPpad, int SRCSTRIDE, bool COMPACT>
__global__ __launch_bounds__(256) void pool_norm2(const bf16* __restrict__ P,
                                                  const float* __restrict__ wt,
                                                  const float* __restrict__ gamma,
                                                  const float* __restrict__ beta,
                                                  bf16* __restrict__ outp,
                                                  float outScale) {
    constexpr int TASKS = TT * OH * CH + 1;
    const int w = threadIdx.x >> 6, lane = threadIdx.x & 63;
    const int gw = xcd_remap(blockIdx.x, gridDim.x) * 4 + w;
    const int bh = gw / TASKS, task = gw % TASKS;
    const int b = bh / NH, head = bh % NH;
    const int owg = lane >> 3, cg = lane & 7, c = cg * 8;
    const size_t rowbase = COMPACT ? (size_t)b * CTOK : (size_t)b * NTOK;
    const size_t pbase = rowbase * SRCSTRIDE + head * HD + c;

    if (task == TASKS - 1) {
        if (owg == 0) {
            bf16x8 v = *(const bf16x8*)(P + pbase);
            float a[8];
            #pragma unroll
            for (int e = 0; e < 8; ++e) a[e] = (float)v[e];
            float s = 0;
            #pragma unroll
            for (int e = 0; e < 8; ++e) s += a[e];
            s += __shfl_xor(s, 1); s += __shfl_xor(s, 2); s += __shfl_xor(s, 4);
            const float mu = s * 0.015625f;
            float v2 = 0;
            #pragma unroll
            for (int e = 0; e < 8; ++e) { float d = a[e] - mu; v2 += d * d; }
            v2 += __shfl_xor(v2, 1); v2 += __shfl_xor(v2, 2); v2 += __shfl_xor(v2, 4);
            const float rs = rsqrtf(v2 * 0.015625f + 1e-5f);
            f32x4 g0 = *(const f32x4*)(gamma + c), g1 = *(const f32x4*)(gamma + c + 4);
            f32x4 b0 = *(const f32x4*)(beta + c),  b1 = *(const f32x4*)(beta + c + 4);
            bf16x8 o;
            #pragma unroll
            for (int e = 0; e < 4; ++e) {
                o[e]     = (bf16)(((a[e]     - mu) * rs * g0[e] + b0[e]) * outScale);
                o[4 + e] = (bf16)(((a[4 + e] - mu) * rs * g1[e] + b1[e]) * outScale);
            }
            *(bf16x8*)(outp + ((size_t)bh * NPpad) * HD + c) = o;
        } else {
            bf16x8 z = {};
            for (int p = NP + owg - 1; p < NPpad; p += 7)
                *(bf16x8*)(outp + ((size_t)bh * NPpad + p) * HD + c) = z;
        }
        return;
    }

    const int t  = task / (OH * CH);
    const int r2 = task % (OH * CH);
    const int oh = r2 / CH;
    const int ow = (r2 % CH) * 8 + owg;
    const bool active = (ow < OW);

    float acc[8] = {0, 0, 0, 0, 0, 0, 0, 0};
    #pragma unroll
    for (int dt = 0; dt < 3; ++dt) {
        const int it = t + dt - 1;
        if (it < 0 || it >= TT) continue;
        #pragma unroll
        for (int dh = 0; dh < 3; ++dh) {
            int rowh;
            if constexpr (COMPACT) {
                const int hi = 3 * oh + dh - 1;
                if (hi < 0) continue;
                rowh = 1 + it * 400 + hi * 20;
            } else {
                const int ih = oh * S + dh - 1;
                if (ih < 0 || ih >= HH) continue;
                rowh = 1 + (it * HH + ih) * WW;
            }
            #pragma unroll
            for (int dw = 0; dw < 3; ++dw) {
                int rowoff;
                bool ok;
                if constexpr (COMPACT) {
                    const int wi = 3 * ow + dw - 1;
                    ok = active && (wi >= 0);
                    rowoff = rowh + wi;
                } else {
                    const int iw = ow * S + dw - 1;
                    ok = active && (iw >= 0);
                    rowoff = rowh + iw;
                }
                if (ok) {
                    bf16x8 v = *(const bf16x8*)(P + pbase + (size_t)rowoff * SRCSTRIDE);
                    const float* wp = wt + ((dt * 3 + dh) * 3 + dw) * 64 + c;
                    f32x4 w0 = *(const f32x4*)wp, w1 = *(const f32x4*)(wp + 4);
                    #pragma unroll
                    for (int e = 0; e < 4; ++e) {
                        acc[e]     += w0[e] * (float)v[e];
                        acc[4 + e] += w1[e] * (float)v[4 + e];
                    }
                }
            }
        }
    }
    float s = 0;
    #pragma unroll
    for (int e = 0; e < 8; ++e) s += acc[e];
    s += __shfl_xor(s, 1); s += __shfl_xor(s, 2); s += __shfl_xor(s, 4);
    const float mu = s * 0.015625f;
    float v2 = 0;
    #pragma unroll
    for (int e = 0; e < 8; ++e) { float d = acc[e] - mu; v2 += d * d; }
    v2 += __shfl_xor(v2, 1); v2 += __shfl_xor(v2, 2); v2 += __shfl_xor(v2, 4);
    const float rs = rsqrtf(v2 * 0.015625f + 1e-5f);
    if (active) {
        f32x4 g0 = *(const f32x4*)(gamma + c), g1 = *(const f32x4*)(gamma + c + 4);
        f32x4 b0 = *(const f32x4*)(beta + c),  b1 = *(const f32x4*)(beta + c + 4);
        bf16x8 o;
        #pragma unroll
        for (int e = 0; e < 4; ++e) {
            o[e]     = (bf16)(((acc[e]     - mu) * rs * g0[e] + b0[e]) * outScale);
            o[4 + e] = (bf16)(((acc[4 + e] - mu) * rs * g1[e] + b1[e]) * outScale);
        }
        const int p = 1 + (t * OH + oh) * OW + ow;
        *(bf16x8*)(outp + ((size_t)bh * NPpad + p) * HD + c) = o;
    }
}

// ---------------- flash attention, fixed-max softmax, XCD-chunked ----------------
__global__ __launch_bounds__(256) void attn_kernel(const bf16* __restrict__ qn,
                                                   const bf16* __restrict__ kn,
                                                   const bf16* __restrict__ vn,
                                                   bf16* __restrict__ ob,
                                                   const float* __restrict__ Mptr) {
    __shared__ bf16 Kl[2][32][72];
    __shared__ bf16 Vt[2][64][40];
    __shared__ bf16 Pl[4][16][40];

    const int tid = threadIdx.x, l = tid & 63, w = tid >> 6;
    const int li = l & 15, lg = l >> 4;
    const int wgid = xcd_remap(blockIdx.x, gridDim.x);
    const int bh = wgid / 25;
    const int b = bh / NH, head = bh % NH;
    const int qbase = (wgid % 25) * 64 + w * 16;
    const float M = Mptr[0];

    const bf16* qp = qn + ((size_t)bh * NQP + qbase + li) * HD + lg * 8;
    const bf16x8 aq0 = *(const bf16x8*)qp;
    const bf16x8 aq1 = *(const bf16x8*)(qp + 32);

    const int srow = tid >> 3, scol = (tid & 7) * 8;
    const int sj = tid & 31, sd8 = tid >> 5;
    const bf16* kbase = kn + (size_t)bh * NKP * HD;
    const bf16* vbase = vn + (size_t)bh * NKP * HD;

    u32x4 kv = *(const u32x4*)(kbase + srow * HD + scol);
    u32x4 vv = *(const u32x4*)(vbase + sj * HD + sd8 * 8);
    *(u32x4*)&Kl[0][srow][scol] = kv;
    {
        bf16x8 t = __builtin_bit_cast(bf16x8, vv);
        #pragma unroll
        for (int e = 0; e < 8; ++e) Vt[0][sd8 * 8 + e][sj] = t[e];
    }

    f32x4 oacc[4] = {};
    float lpart[4] = {0.f, 0.f, 0.f, 0.f};

    for (int kt = 0; kt < 13; ++kt) {
        const int cur = kt & 1;
        if (kt < 12) {
            kv = *(const u32x4*)(kbase + (kt + 1) * 32 * HD + srow * HD + scol);
            vv = *(const u32x4*)(vbase + (kt + 1) * 32 * HD + sj * HD + sd8 * 8);
        }
        __syncthreads();

        f32x4 c0 = {}, c1 = {};
        const bf16x8 b00 = *(const bf16x8*)&Kl[cur][li][lg * 8];
        const bf16x8 b01 = *(const bf16x8*)&Kl[cur][li][32 + lg * 8];
        const bf16x8 b10 = *(const bf16x8*)&Kl[cur][16 + li][lg * 8];
        const bf16x8 b11 = *(const bf16x8*)&Kl[cur][16 + li][32 + lg * 8];
        __builtin_amdgcn_s_setprio(1);
        c0 = MFMA16(aq0, b00, c0); c0 = MFMA16(aq1, b01, c0);
        c1 = MFMA16(aq0, b10, c1); c1 = MFMA16(aq1, b11, c1);
        __builtin_amdgcn_s_setprio(0);

        float p0[4], p1[4];
        #pragma unroll
        for (int r = 0; r < 4; ++r) {
            p0[r] = __expf(c0[r] - M);
            p1[r] = __expf(c1[r] - M);
        }
        if (kt == 12) {
            const bool m0 = (384 + li) >= NK;
            #pragma unroll
            for (int r = 0; r < 4; ++r) { if (m0) p0[r] = 0.f; p1[r] = 0.f; }
        }
        #pragma unroll
        for (int r = 0; r < 4; ++r) {
            lpart[r] += p0[r] + p1[r];
            Pl[w][lg * 4 + r][li]      = (bf16)p0[r];
            Pl[w][lg * 4 + r][16 + li] = (bf16)p1[r];
        }
        const bf16x8 ap = *(const bf16x8*)&Pl[w][li][lg * 8];
        __builtin_amdgcn_s_setprio(1);
        #pragma unroll
        for (int dg = 0; dg < 4; ++dg) {
            const bf16x8 bv = *(const bf16x8*)&Vt[cur][dg * 16 + li][lg * 8];
            oacc[dg] = MFMA16(ap, bv, oacc[dg]);
        }
        __builtin_amdgcn_s_setprio(0);

        if (kt < 12) {
            const int nxt = cur ^ 1;
            *(u32x4*)&Kl[nxt][srow][scol] = kv;
            bf16x8 t = __builtin_bit_cast(bf16x8, vv);
            #pragma unroll
            for (int e = 0; e < 8; ++e) Vt[nxt][sd8 * 8 + e][sj] = t[e];
        }
    }
    #pragma unroll
    for (int r = 0; r < 4; ++r) {
        float lsum = lpart[r];
        lsum += __shfl_xor(lsum, 1);
        lsum += __shfl_xor(lsum, 2);
        lsum += __shfl_xor(lsum, 4);
        lsum += __shfl_xor(lsum, 8);
        const int q = qbase + lg * 4 + r;
        if (q < NQ) {
            const float inv = 1.f / lsum;
            const size_t off = ((size_t)(b * NQ + q)) * CC + head * HD;
            #pragma unroll
            for (int dg = 0; dg < 4; ++dg)
                ob[off + dg * 16 + li] = (bf16)(oacc[dg][r] * inv);
        }
    }
}

// ---------------- launcher ----------------
extern "C" void kernel_launch(void* const* d_in, const int* in_sizes, int n_in,
                              void* d_out, int out_size, void* d_ws, size_t ws_size,
                              hipStream_t stream) {
    const float* x     = (const float*)d_in[0];
    const float* Wq    = (const float*)d_in[1];
    const float* Wk    = (const float*)d_in[2];
    const float* Wv    = (const float*)d_in[3];
    const float* Wproj = (const float*)d_in[4];
    const float* bproj = (const float*)d_in[5];
    const float* pqw   = (const float*)d_in[6];
    const float* pkw   = (const float*)d_in[7];
    const float* pvw   = (const float*)d_in[8];
    const float* gq    = (const float*)d_in[9];
    const float* bq    = (const float*)d_in[10];
    const float* gk    = (const float*)d_in[11];
    const float* bk    = (const float*)d_in[12];
    const float* gv    = (const float*)d_in[13];
    const float* bv    = (const float*)d_in[14];

    if (ws_size < 364000000ULL) return;
    char* ws = (char*)d_ws;
    bf16* xb    = (bf16*)(ws);               // [50304][768]
    bf16* wqkv  = (bf16*)(ws + 77266944);    // [2304][768] (+wpb contiguous after)
    bf16* wpb   = (bf16*)(ws + 80805888);    // [768][768]
    bf16* tmpq  = (bf16*)(ws + 81985536);    // [50304][768]
    bf16* tmpkv = (bf16*)(ws + 159252480);   // [25856][1536]
    bf16* qn    = (bf16*)(ws + 238682112);   // [96][1600][64]
    bf16* kn    = (bf16*)(ws + 258342912);   // [96][416][64]
    bf16* vnb   = (bf16*)(ws + 263454720);   // [96][416][64]
    bf16* ob    = (bf16*)(ws + 268566528);   // [12672][768]
    float* wt   = (float*)(ws + 288030720);  // [3][27][64] f32
    float* Mb   = (float*)(ws + 288051456);  // [1]

    (void)hipFuncSetAttribute((const void*)gemmU,
                              hipFuncAttributeMaxDynamicSharedMemorySize, 131072);
    (void)hipFuncSetAttribute((const void*)gemmF,
                              hipFuncAttributeMaxDynamicSharedMemorySize, 98304);

    transpose_w3<<<21, 256, 0, stream>>>(pqw, pkw, pvw, wt);
    bound_kernel<<<1, 64, 0, stream>>>(gq, bq, gk, bk, Mb);
    cast_f32_bf16<<<4096, 256, 0, stream>>>(x, xb, MX * CC, MXP * CC);
    cast_w4<<<2304, 256, 0, stream>>>(Wq, Wk, Wv, Wproj, wqkv);

    // unified projection: Q (591 blocks, all tokens) + KV (606 blocks, gathered)
    gemmU<<<1197, 512, 131072, stream>>>(xb, wqkv, tmpq, tmpkv);

    // pools: q from tmpq (full layout), k/v from compact tmpkv
    pool_norm2<2, 14, 14, 2, NQ, NQP, 768,  false><<<5400, 256, 0, stream>>>(tmpq,        wt,        gq, bq, qn,  0.125f);
    pool_norm2<4, 7, 7, 1, NK, NKP, 1536, true ><<<1368, 256, 0, stream>>>(tmpkv,       wt + 1728, gk, bk, kn,  1.0f);
    pool_norm2<4, 7, 7, 1, NK, NKP, 1536, true ><<<1368, 256, 0, stream>>>(tmpkv + 768, wt + 3456, gv, bv, vnb, 1.0f);

    attn_kernel<<<2400, 256, 0, stream>>>(qn, kn, vnb, ob, Mb);

    // final projection: 256x128 tiles, 300 blocks
    gemmF<<<50 * 6, 512, 98304, stream>>>(ob, wpb, (float*)d_out, bproj, 6, MO, MOP);
}